// Round 1
// baseline (569.875 us; speedup 1.0000x reference)
//
#include <hip/hip_runtime.h>
#include <hip/hip_bf16.h>
#include <math.h>

// Problem constants
#define BATCH 2
#define DI 192          // D_INNER
#define NST 16          // D_STATE
#define DTR 6           // DT_RANK
#define KK 2
#define LL 4096
#define NCH 64          // scan chunks
#define CHL 64          // chunk length
#define NQ (BATCH*KK*DI*NST)   // 12288 chains

// ---------------- pe table: pe[col][c], col=l%64 ----------------
__global__ void pe_kernel(float* __restrict__ pe) {
    int i = blockIdx.x * 256 + threadIdx.x;
    if (i >= 64 * DI) return;
    int col = i / DI, c = i % DI;
    float gx = (float)col / 63.f;
    int m = (c < 96) ? c : (c - 96);
    float invf = expf(-(float)m * (logf(10000.f) / 96.f));
    float ang = gx * invf;
    pe[i] = (c < 96) ? sinf(ang) : cosf(ang);
}

// ---------------- fuse conv (3x3, 384ch -> 1) raw outputs for both branches ----
// pm layout: [X][b][L]  (raw pre-activation; monotonic map preserves argsort)
__global__ void fusepm_kernel(const float* __restrict__ xT, const float* __restrict__ xR,
                              const float* __restrict__ prox, const float* __restrict__ fw,
                              const float* __restrict__ fb, float* __restrict__ pm) {
    __shared__ float wl[3456];
    __shared__ float red[3][4][64];
    int b = blockIdx.x >> 6;
    int row = blockIdx.x & 63;
    for (int i = threadIdx.x; i < 3456; i += 256) wl[i] = fw[i];
    __syncthreads();
    int px = threadIdx.x & 63, g = threadIdx.x >> 6;
    float aT = 0.f, aR = 0.f, aP = 0.f;
    for (int cc = 0; cc < 48; ++cc) {
        int c = g * 48 + cc;
        const float* xTb = xT + (size_t)(b * DI + c) * 4096;
        const float* xRb = xR + (size_t)(b * DI + c) * 4096;
        const float* pb  = prox + (size_t)(b * DI + c) * 4096;
        const float* wT = wl + c * 9;
        const float* wP = wl + (192 + c) * 9;
        #pragma unroll
        for (int ky = 0; ky < 3; ++ky) {
            int yy = row + ky - 1;
            if (yy < 0 || yy > 63) continue;
            #pragma unroll
            for (int kx = 0; kx < 3; ++kx) {
                int xx = px + kx - 1;
                if (xx < 0 || xx > 63) continue;
                int o = yy * 64 + xx;
                float wTv = wT[ky * 3 + kx], wPv = wP[ky * 3 + kx];
                aT += xTb[o] * wTv;
                aR += xRb[o] * wTv;
                aP += pb[o] * wPv;
            }
        }
    }
    red[0][g][px] = aT; red[1][g][px] = aR; red[2][g][px] = aP;
    __syncthreads();
    if (threadIdx.x < 64) {
        int x = threadIdx.x;
        float sT = red[0][0][x] + red[0][1][x] + red[0][2][x] + red[0][3][x];
        float sR = red[1][0][x] + red[1][1][x] + red[1][2][x] + red[1][3][x];
        float sP = red[2][0][x] + red[2][1][x] + red[2][2][x] + red[2][3][x];
        float bb = fb[0];
        pm[(0 * 2 + b) * LL + row * 64 + x] = sT + sP + bb;
        pm[(1 * 2 + b) * LL + row * 64 + x] = sR + sP + bb;
    }
}

// ---------------- bitonic argsort (stable via index tie-break) ----------------
// grid 4: blockIdx = X*2+b.  X=0 (T): descending pm  -> key = -z ascending
//                            X=1 (R): ascending pm   -> key = z ascending
__global__ void sort_kernel(const float* __restrict__ pm, int* __restrict__ ord,
                            int* __restrict__ inv) {
    __shared__ float key[LL];
    __shared__ int idx[LL];
    int X = blockIdx.x >> 1, b = blockIdx.x & 1;
    const float* z = pm + (X * 2 + b) * LL;
    for (int i = threadIdx.x; i < LL; i += 1024) {
        float v = z[i];
        key[i] = (X == 0) ? -v : v;
        idx[i] = i;
    }
    __syncthreads();
    for (int k = 2; k <= LL; k <<= 1) {
        for (int j = k >> 1; j >= 1; j >>= 1) {
            for (int t = threadIdx.x; t < LL / 2; t += 1024) {
                int i = ((t & ~(j - 1)) << 1) | (t & (j - 1));
                int p = i | j;
                bool asc = ((i & k) == 0);
                float ka = key[i], kb = key[p];
                int ia = idx[i], ib = idx[p];
                bool agt = (ka > kb) || (ka == kb && ia > ib);
                if (agt == asc) { key[i] = kb; key[p] = ka; idx[i] = ib; idx[p] = ia; }
            }
            __syncthreads();
        }
    }
    int* o = ord + (X * 2 + b) * LL;
    int* iv = inv + (X * 2 + b) * LL;
    for (int s = threadIdx.x; s < LL; s += 1024) {
        int j = idx[s];
        o[s] = j;
        iv[j] = s;
    }
}

// ---------------- transpose NCHW (b,c,l) -> (b,l,c), optionally add pe --------
__global__ void transpose_pe_kernel(const float* __restrict__ in, float* __restrict__ out,
                                    const float* __restrict__ pe, int use_pe) {
    __shared__ float tile[32][33];
    int b = blockIdx.z;
    int l0 = blockIdx.x * 32, c0 = blockIdx.y * 32;
    int tx = threadIdx.x, ty = threadIdx.y;
    #pragma unroll
    for (int r = 0; r < 4; ++r) {
        int c = c0 + ty + r * 8;
        tile[ty + r * 8][tx] = in[(size_t)(b * DI + c) * LL + l0 + tx];
    }
    __syncthreads();
    #pragma unroll
    for (int r = 0; r < 4; ++r) {
        int l = l0 + ty + r * 8;
        int c = c0 + tx;
        float v = tile[tx][ty + r * 8];
        if (use_pe) v += pe[(l & 63) * DI + c];
        out[(size_t)(b * LL + l) * DI + c] = v;
    }
}

// ---------------- depth path: df = leaky(Wde@pv+b); dproj = dpw@df; dsig ------
// block: 16 positions; dproj layout [bl][64] (k*32+c2), dsig [bl][16]
__global__ void depth_kernel(const float* __restrict__ proxt, const float* __restrict__ wde,
                             const float* __restrict__ bde, const float* __restrict__ dpw,
                             const float* __restrict__ sgw, const float* __restrict__ sgb,
                             float* __restrict__ dproj, float* __restrict__ dsig) {
    __shared__ float pvs[16][DI];
    __shared__ float dfs[16][DI];
    int bl0 = blockIdx.x * 16;
    int tid = threadIdx.x;
    for (int t = tid; t < 16 * DI; t += 256)
        pvs[t / DI][t % DI] = proxt[(size_t)bl0 * DI + t];
    __syncthreads();
    if (tid < DI) {
        float acc[16];
        #pragma unroll
        for (int l = 0; l < 16; ++l) acc[l] = 0.f;
        for (int i = 0; i < DI; ++i) {
            float w = wde[tid * DI + i];
            #pragma unroll
            for (int l = 0; l < 16; ++l) acc[l] += w * pvs[l][i];
        }
        float bias = bde[tid];
        #pragma unroll
        for (int l = 0; l < 16; ++l) {
            float v = acc[l] + bias;
            dfs[l][tid] = (v > 0.f) ? v : 0.2f * v;
        }
    }
    __syncthreads();
    if (tid < 80) {
        float acc[16];
        #pragma unroll
        for (int l = 0; l < 16; ++l) acc[l] = 0.f;
        const float* wrow = (tid < 64) ? (dpw + tid * DI) : (sgw + (tid - 64) * DI);
        for (int i = 0; i < DI; ++i) {
            float w = wrow[i];
            #pragma unroll
            for (int l = 0; l < 16; ++l) acc[l] += w * dfs[l][i];
        }
        if (tid < 64) {
            #pragma unroll
            for (int l = 0; l < 16; ++l) dproj[(size_t)(bl0 + l) * 64 + tid] = acc[l];
        } else {
            float bias = sgb[tid - 64];
            #pragma unroll
            for (int l = 0; l < 16; ++l) {
                float v = acc[l] + bias;
                v = (v > 0.f) ? v : 0.2f * v;
                dsig[(size_t)(bl0 + l) * NST + (tid - 64)] = 1.f / (1.f + __expf(-v));
            }
        }
    }
}

// ---------------- per-(b,k,s): x_dbl projection, delta(softplus), Bs/Cs -------
// outputs: dtbuf [b][k][s][192], bscs [b][k][s][32] (Bs 0..15, Cs 16..31)
__global__ void project_kernel(const float* __restrict__ xpe, const int* __restrict__ ord,
                               const float* __restrict__ xpw, const float* __restrict__ dtw,
                               const float* __restrict__ dtb, const float* __restrict__ dproj,
                               const float* __restrict__ dsig, float* __restrict__ dtbuf,
                               float* __restrict__ bscs) {
    __shared__ float u[16][193];
    __shared__ float dbl[16][40];
    __shared__ int jarr[16];
    int chunk = blockIdx.x & 255;
    int k = (blockIdx.x >> 8) & 1;
    int b = blockIdx.x >> 9;
    int s0 = chunk * 16;
    int tid = threadIdx.x;
    if (tid < 16) {
        int s = s0 + tid;
        jarr[tid] = ord[b * LL + ((k == 0) ? s : (LL - 1 - s))];
    }
    __syncthreads();
    for (int t = tid; t < 16 * DI; t += 256) {
        int l = t / DI, i = t - l * DI;
        u[l][i] = xpe[(size_t)(b * LL + jarr[l]) * DI + i];
    }
    __syncthreads();
    {
        int og = tid >> 4, sl = tid & 15;
        float a0 = 0.f, a1 = 0.f, a2 = 0.f;
        const float* w0 = xpw + (size_t)(k * 38 + og) * DI;
        const float* w1 = w0 + 16 * DI;
        const float* w2 = w0 + 32 * DI;
        bool has2 = (og < 6);
        for (int i = 0; i < DI; ++i) {
            float uu = u[sl][i];
            a0 += w0[i] * uu;
            a1 += w1[i] * uu;
            if (has2) a2 += w2[i] * uu;
        }
        dbl[sl][og] = a0;
        dbl[sl][og + 16] = a1;
        if (has2) dbl[sl][og + 32] = a2;
    }
    __syncthreads();
    if (tid < DI) {
        int c = tid;
        float w[6];
        #pragma unroll
        for (int r = 0; r < 6; ++r) w[r] = dtw[(k * DI + c) * DTR + r];
        float bias = dtb[k * DI + c];
        for (int sl = 0; sl < 16; ++sl) {
            float d = bias;
            #pragma unroll
            for (int r = 0; r < 6; ++r) d += w[r] * dbl[sl][r];
            float sp = fmaxf(d, 0.f) + log1pf(__expf(-fabsf(d)));
            dtbuf[((size_t)(b * 2 + k) * LL + s0 + sl) * DI + c] = sp;
        }
    }
    {
        int sl = tid >> 4, n = tid & 15;
        int j = jarr[sl];
        float w = dsig[(size_t)(b * LL + j) * NST + n];
        float Bo = dbl[sl][6 + n], Co = dbl[sl][22 + n];
        float Bd = dproj[(size_t)(b * LL + j) * 64 + k * 32 + n];
        float Cd = dproj[(size_t)(b * LL + j) * 64 + k * 32 + 16 + n];
        size_t base = ((size_t)(b * 2 + k) * LL + s0 + sl) * 32;
        bscs[base + n] = (1.f - w) * Bo + w * Bd;
        bscs[base + 16 + n] = (1.f - w) * Co + w * Cd;
    }
}

// ---------------- scan pass1: per-chunk partial state + decay product ---------
__global__ __launch_bounds__(256) void scan1_kernel(const float* __restrict__ dtbuf,
        const float* __restrict__ xpe, const int* __restrict__ ord,
        const float* __restrict__ bscs, const float* __restrict__ Alog,
        float* __restrict__ hp, float* __restrict__ Ap) {
    int wid = (blockIdx.x << 2) | (threadIdx.x >> 6);
    int lane = threadIdx.x & 63;
    int ch = wid & 63;
    int cg = (wid >> 6) % 48;
    int k = (wid / 3072) & 1;
    int b = wid / 6144;
    int c = cg * 4 + (lane >> 4);
    int n = lane & 15;
    float A = -__expf(Alog[(k * DI + c) * NST + n]);
    const float* dtp = dtbuf + (size_t)(b * 2 + k) * LL * DI + c;
    const float* bp = bscs + (size_t)(b * 2 + k) * LL * 32 + n;
    const int* op = ord + b * LL;
    float h = 0.f, cA = 1.f;
    int s0 = ch * CHL;
    for (int t = 0; t < CHL; ++t) {
        int s = s0 + t;
        int j = op[(k == 0) ? s : (LL - 1 - s)];
        float dt = dtp[(size_t)s * DI];
        float uu = xpe[(size_t)(b * LL + j) * DI + c];
        float Bv = bp[(size_t)s * 32];
        float e = __expf(dt * A);
        h = h * e + dt * uu * Bv;
        cA *= e;
    }
    int q = ((b * 2 + k) * DI + c) * NST + n;
    hp[ch * NQ + q] = h;
    Ap[ch * NQ + q] = cA;
}

// ---------------- scan pass2: sequential over chunks (exclusive) --------------
__global__ void scan2_kernel(const float* __restrict__ hp, const float* __restrict__ Ap,
                             float* __restrict__ hin) {
    int q = blockIdx.x * 256 + threadIdx.x;
    float carry = 0.f;
    for (int ch = 0; ch < NCH; ++ch) {
        hin[ch * NQ + q] = carry;
        carry = hp[ch * NQ + q] + Ap[ch * NQ + q] * carry;
    }
}

// ---------------- scan pass3: replay with true h_in, emit y -------------------
__global__ __launch_bounds__(256) void scan3_kernel(const float* __restrict__ dtbuf,
        const float* __restrict__ xpe, const int* __restrict__ ord,
        const float* __restrict__ bscs, const float* __restrict__ Alog,
        const float* __restrict__ hin, float* __restrict__ y) {
    int wid = (blockIdx.x << 2) | (threadIdx.x >> 6);
    int lane = threadIdx.x & 63;
    int ch = wid & 63;
    int cg = (wid >> 6) % 48;
    int k = (wid / 3072) & 1;
    int b = wid / 6144;
    int c = cg * 4 + (lane >> 4);
    int n = lane & 15;
    float A = -__expf(Alog[(k * DI + c) * NST + n]);
    const float* dtp = dtbuf + (size_t)(b * 2 + k) * LL * DI + c;
    const float* bp = bscs + (size_t)(b * 2 + k) * LL * 32 + n;
    const int* op = ord + b * LL;
    int q = ((b * 2 + k) * DI + c) * NST + n;
    float h = hin[ch * NQ + q];
    int s0 = ch * CHL;
    for (int t = 0; t < CHL; ++t) {
        int s = s0 + t;
        int j = op[(k == 0) ? s : (LL - 1 - s)];
        float dt = dtp[(size_t)s * DI];
        float uu = xpe[(size_t)(b * LL + j) * DI + c];
        float Bv = bp[(size_t)s * 32];
        float Cv = bp[(size_t)s * 32 + 16];
        float e = __expf(dt * A);
        h = h * e + dt * uu * Bv;
        float yp = h * Cv;
        yp += __shfl_xor(yp, 1);
        yp += __shfl_xor(yp, 2);
        yp += __shfl_xor(yp, 4);
        yp += __shfl_xor(yp, 8);
        if (n == 0) y[((size_t)(b * 2 + k) * LL + s) * DI + c] = yp;
    }
}

// ---------------- gather (inverse perm) + D*u + layernorm + output ------------
__global__ void ln_kernel(const float* __restrict__ y, const float* __restrict__ xpe,
                          const int* __restrict__ inv, const float* __restrict__ Dvec,
                          const float* __restrict__ g, const float* __restrict__ beta,
                          float* __restrict__ out, int X) {
    int w = threadIdx.x >> 6, lane = threadIdx.x & 63;
    int bl = blockIdx.x * 4 + w;
    int b = bl >> 12, l = bl & 4095;
    int s0 = inv[b * LL + l];
    int s1 = LL - 1 - s0;
    const float* y0 = y + ((size_t)(b * 2 + 0) * LL + s0) * DI;
    const float* y1 = y + ((size_t)(b * 2 + 1) * LL + s1) * DI;
    const float* xr = xpe + (size_t)(b * LL + l) * DI;
    float v[3];
    float sum = 0.f, sq = 0.f;
    #pragma unroll
    for (int r = 0; r < 3; ++r) {
        int c = lane + r * 64;
        float t = y0[c] + y1[c] + (Dvec[c] + Dvec[DI + c]) * xr[c];
        v[r] = t; sum += t; sq += t * t;
    }
    #pragma unroll
    for (int m = 1; m < 64; m <<= 1) {
        sum += __shfl_xor(sum, m);
        sq += __shfl_xor(sq, m);
    }
    float mu = sum * (1.f / 192.f);
    float var = sq * (1.f / 192.f) - mu * mu;
    float rs = rsqrtf(var + 1e-5f);
    float* op = out + ((size_t)(X * 2 + b) * LL + l) * DI;
    #pragma unroll
    for (int r = 0; r < 3; ++r) {
        int c = lane + r * 64;
        op[c] = (v[r] - mu) * rs * g[c] + beta[c];
    }
}

extern "C" void kernel_launch(void* const* d_in, const int* in_sizes, int n_in,
                              void* d_out, int out_size, void* d_ws, size_t ws_size,
                              hipStream_t stream) {
    const float* x_T = (const float*)d_in[0];
    const float* x_R = (const float*)d_in[1];
    const float* prox = (const float*)d_in[2];
    const float* fuse_w = (const float*)d_in[3];
    const float* fuse_b = (const float*)d_in[4];
    const float* x_proj_w = (const float*)d_in[5];
    const float* dt_w = (const float*)d_in[6];
    const float* dt_b = (const float*)d_in[7];
    const float* A_log_T = (const float*)d_in[8];
    const float* A_log_R = (const float*)d_in[9];
    const float* D_T = (const float*)d_in[10];
    const float* D_R = (const float*)d_in[11];
    const float* depth_enc_w = (const float*)d_in[12];
    const float* depth_enc_b = (const float*)d_in[13];
    const float* depth_proj_w = (const float*)d_in[14];
    const float* sig_w = (const float*)d_in[15];
    const float* sig_b = (const float*)d_in[16];
    const float* ln_g = (const float*)d_in[17];
    const float* ln_b = (const float*)d_in[18];
    float* out = (float*)d_out;
    char* ws = (char*)d_ws;

    float* pe    = (float*)(ws + 0);         //   49152
    float* pm    = (float*)(ws + 49152);     //   65536
    int*   ord   = (int*)(ws + 114688);      //   65536
    int*   inv   = (int*)(ws + 180224);      //   65536
    float* proxt = (float*)(ws + 245760);    // 6291456
    float* dproj = (float*)(ws + 6537216);   // 2097152
    float* dsig  = (float*)(ws + 8634368);   //  524288
    float* xpe   = (float*)(ws + 9158656);   // 6291456 (reused per branch)
    float* dtbuf = (float*)(ws + 15450112);  // 12582912
    float* bscs  = (float*)(ws + 28033024);  // 2097152
    float* hp    = (float*)(ws + 30130176);  // 3145728
    float* Ap    = (float*)(ws + 33275904);  // 3145728
    float* hin   = (float*)(ws + 36421632);  // 3145728
    float* ybuf  = (float*)(ws + 39567360);  // 12582912  -> total 52150272

    pe_kernel<<<48, 256, 0, stream>>>(pe);
    fusepm_kernel<<<128, 256, 0, stream>>>(x_T, x_R, prox, fuse_w, fuse_b, pm);
    sort_kernel<<<4, 1024, 0, stream>>>(pm, ord, inv);
    transpose_pe_kernel<<<dim3(128, 6, 2), dim3(32, 8), 0, stream>>>(prox, proxt, pe, 0);
    depth_kernel<<<512, 256, 0, stream>>>(proxt, depth_enc_w, depth_enc_b, depth_proj_w,
                                          sig_w, sig_b, dproj, dsig);
    for (int X = 0; X < 2; ++X) {
        const float* xin = X ? x_R : x_T;
        const float* Alog = X ? A_log_R : A_log_T;
        const float* Dv = X ? D_R : D_T;
        const int* ordX = ord + X * 2 * LL;
        const int* invX = inv + X * 2 * LL;
        transpose_pe_kernel<<<dim3(128, 6, 2), dim3(32, 8), 0, stream>>>(xin, xpe, pe, 1);
        project_kernel<<<1024, 256, 0, stream>>>(xpe, ordX, x_proj_w, dt_w, dt_b,
                                                 dproj, dsig, dtbuf, bscs);
        scan1_kernel<<<3072, 256, 0, stream>>>(dtbuf, xpe, ordX, bscs, Alog, hp, Ap);
        scan2_kernel<<<48, 256, 0, stream>>>(hp, Ap, hin);
        scan3_kernel<<<3072, 256, 0, stream>>>(dtbuf, xpe, ordX, bscs, Alog, hin, ybuf);
        ln_kernel<<<2048, 256, 0, stream>>>(ybuf, xpe, invX, Dv, ln_g, ln_b, out, X);
    }
}

// Round 2
// 480.248 us; speedup vs baseline: 1.1866x; 1.1866x over previous
//
#include <hip/hip_runtime.h>
#include <hip/hip_bf16.h>
#include <math.h>

// Problem constants
#define BATCH 2
#define DI 192          // D_INNER
#define NST 16          // D_STATE
#define DTR 6           // DT_RANK
#define KK 2
#define LL 4096
#define NCH 64          // scan chunks
#define CHL 64          // chunk length
#define NQ (BATCH*KK*DI*NST)   // 12288 chains

// ---------------- pe table: pe[col][c], col=l%64 ----------------
__global__ void pe_kernel(float* __restrict__ pe) {
    int i = blockIdx.x * 256 + threadIdx.x;
    if (i >= 64 * DI) return;
    int col = i / DI, c = i % DI;
    float gx = (float)col / 63.f;
    int m = (c < 96) ? c : (c - 96);
    float invf = expf(-(float)m * (logf(10000.f) / 96.f));
    float ang = gx * invf;
    pe[i] = (c < 96) ? sinf(ang) : cosf(ang);
}

// ---------------- fuse conv partials: grid (12 cgroups, 64 rows, 2 b) --------
// pbuf layout: [(cg*4 + X*2 + b)][L]  (X=0:T, X=1:R), raw pre-activation partial
__global__ void fusepm_part_kernel(const float* __restrict__ xT, const float* __restrict__ xR,
                                   const float* __restrict__ prox, const float* __restrict__ fw,
                                   float* __restrict__ pbuf) {
    __shared__ float wl[288];          // 16ch x 9 (x-half) + 16ch x 9 (prox-half)
    __shared__ float red[2][4][64];
    int cg = blockIdx.x;
    int row = blockIdx.y;
    int b = blockIdx.z;
    int tid = threadIdx.x;
    if (tid < 288) {
        int cl = (tid % 144) / 9, tap = tid % 9;
        int half = tid / 144;                    // 0: x-half, 1: prox-half
        wl[tid] = fw[(half * DI + cg * 16 + cl) * 9 + tap];
    }
    __syncthreads();
    int px = tid & 63, g = tid >> 6;
    float aT = 0.f, aR = 0.f, aP = 0.f;
    #pragma unroll
    for (int cc = 0; cc < 4; ++cc) {
        int cl = g * 4 + cc;
        int c = cg * 16 + cl;
        const float* xTb = xT + (size_t)(b * DI + c) * LL;
        const float* xRb = xR + (size_t)(b * DI + c) * LL;
        const float* pb  = prox + (size_t)(b * DI + c) * LL;
        const float* wT = wl + cl * 9;
        const float* wP = wl + 144 + cl * 9;
        #pragma unroll
        for (int ky = 0; ky < 3; ++ky) {
            int yy = row + ky - 1;
            if (yy < 0 || yy > 63) continue;
            #pragma unroll
            for (int kx = 0; kx < 3; ++kx) {
                int xx = px + kx - 1;
                bool in = (xx >= 0 && xx < 64);
                int o = yy * 64 + (in ? xx : 0);
                float mT = in ? xTb[o] : 0.f;
                float mR = in ? xRb[o] : 0.f;
                float mP = in ? pb[o] : 0.f;
                float wTv = wT[ky * 3 + kx], wPv = wP[ky * 3 + kx];
                aT += mT * wTv;
                aR += mR * wTv;
                aP += mP * wPv;
            }
        }
    }
    red[0][g][px] = aT + aP;
    red[1][g][px] = aR + aP;
    __syncthreads();
    if (tid < 128) {
        int X = tid >> 6, x = tid & 63;
        float s = red[X][0][x] + red[X][1][x] + red[X][2][x] + red[X][3][x];
        pbuf[(size_t)(cg * 4 + X * 2 + b) * LL + row * 64 + x] = s;
    }
}

// ---------------- reduce 12 partials -> pm[X*2+b][L] ----------------
__global__ void fusepm_reduce_kernel(const float* __restrict__ pbuf,
                                     const float* __restrict__ fb,
                                     float* __restrict__ pm) {
    int idx = blockIdx.x * 256 + threadIdx.x;   // idx over 4*LL
    int Xb = idx >> 12;                          // X*2+b
    int l = idx & 4095;
    float s = fb[0];
    #pragma unroll
    for (int cg = 0; cg < 12; ++cg)
        s += pbuf[(size_t)(cg * 4 + Xb) * LL + l];
    pm[(size_t)Xb * LL + l] = s;
}

// ---------------- bitonic argsort (stable via index tie-break) ----------------
// grid 4: blockIdx = X*2+b.  X=0 (T): descending pm  -> key = -z ascending
//                            X=1 (R): ascending pm   -> key = z ascending
__global__ void sort_kernel(const float* __restrict__ pm, int* __restrict__ ord,
                            int* __restrict__ inv) {
    __shared__ float key[LL];
    __shared__ int idx[LL];
    int X = blockIdx.x >> 1, b = blockIdx.x & 1;
    const float* z = pm + (X * 2 + b) * LL;
    for (int i = threadIdx.x; i < LL; i += 1024) {
        float v = z[i];
        key[i] = (X == 0) ? -v : v;
        idx[i] = i;
    }
    __syncthreads();
    for (int k = 2; k <= LL; k <<= 1) {
        for (int j = k >> 1; j >= 1; j >>= 1) {
            for (int t = threadIdx.x; t < LL / 2; t += 1024) {
                int i = ((t & ~(j - 1)) << 1) | (t & (j - 1));
                int p = i | j;
                bool asc = ((i & k) == 0);
                float ka = key[i], kb = key[p];
                int ia = idx[i], ib = idx[p];
                bool agt = (ka > kb) || (ka == kb && ia > ib);
                if (agt == asc) { key[i] = kb; key[p] = ka; idx[i] = ib; idx[p] = ia; }
            }
            __syncthreads();
        }
    }
    int* o = ord + (X * 2 + b) * LL;
    int* iv = inv + (X * 2 + b) * LL;
    for (int s = threadIdx.x; s < LL; s += 1024) {
        int j = idx[s];
        o[s] = j;
        iv[j] = s;
    }
}

// ---------------- transpose NCHW (b,c,l) -> (b,l,c), optionally add pe --------
__global__ void transpose_pe_kernel(const float* __restrict__ in, float* __restrict__ out,
                                    const float* __restrict__ pe, int use_pe) {
    __shared__ float tile[32][33];
    int b = blockIdx.z;
    int l0 = blockIdx.x * 32, c0 = blockIdx.y * 32;
    int tx = threadIdx.x, ty = threadIdx.y;
    #pragma unroll
    for (int r = 0; r < 4; ++r) {
        int c = c0 + ty + r * 8;
        tile[ty + r * 8][tx] = in[(size_t)(b * DI + c) * LL + l0 + tx];
    }
    __syncthreads();
    #pragma unroll
    for (int r = 0; r < 4; ++r) {
        int l = l0 + ty + r * 8;
        int c = c0 + tx;
        float v = tile[tx][ty + r * 8];
        if (use_pe) v += pe[(l & 63) * DI + c];
        out[(size_t)(b * LL + l) * DI + c] = v;
    }
}

// ---------------- depth path: df = leaky(Wde@pv+b); dproj = dpw@df; dsig ------
// block: 16 positions; dproj layout [bl][64] (k*32+c2), dsig [bl][16]
__global__ void depth_kernel(const float* __restrict__ proxt, const float* __restrict__ wde,
                             const float* __restrict__ bde, const float* __restrict__ dpw,
                             const float* __restrict__ sgw, const float* __restrict__ sgb,
                             float* __restrict__ dproj, float* __restrict__ dsig) {
    __shared__ float pvs[16][DI];
    __shared__ float dfs[16][DI];
    int bl0 = blockIdx.x * 16;
    int tid = threadIdx.x;
    for (int t = tid; t < 16 * DI; t += 256)
        pvs[t / DI][t % DI] = proxt[(size_t)bl0 * DI + t];
    __syncthreads();
    if (tid < DI) {
        float acc[16];
        #pragma unroll
        for (int l = 0; l < 16; ++l) acc[l] = 0.f;
        for (int i = 0; i < DI; ++i) {
            float w = wde[tid * DI + i];
            #pragma unroll
            for (int l = 0; l < 16; ++l) acc[l] += w * pvs[l][i];
        }
        float bias = bde[tid];
        #pragma unroll
        for (int l = 0; l < 16; ++l) {
            float v = acc[l] + bias;
            dfs[l][tid] = (v > 0.f) ? v : 0.2f * v;
        }
    }
    __syncthreads();
    if (tid < 80) {
        float acc[16];
        #pragma unroll
        for (int l = 0; l < 16; ++l) acc[l] = 0.f;
        const float* wrow = (tid < 64) ? (dpw + tid * DI) : (sgw + (tid - 64) * DI);
        for (int i = 0; i < DI; ++i) {
            float w = wrow[i];
            #pragma unroll
            for (int l = 0; l < 16; ++l) acc[l] += w * dfs[l][i];
        }
        if (tid < 64) {
            #pragma unroll
            for (int l = 0; l < 16; ++l) dproj[(size_t)(bl0 + l) * 64 + tid] = acc[l];
        } else {
            float bias = sgb[tid - 64];
            #pragma unroll
            for (int l = 0; l < 16; ++l) {
                float v = acc[l] + bias;
                v = (v > 0.f) ? v : 0.2f * v;
                dsig[(size_t)(bl0 + l) * NST + (tid - 64)] = 1.f / (1.f + __expf(-v));
            }
        }
    }
}

// ---------------- per-(b,k,s): x_dbl projection, delta(softplus), Bs/Cs -------
// outputs: dtbuf [b][k][s][192], bscs [b][k][s][32] (Bs 0..15, Cs 16..31)
__global__ void project_kernel(const float* __restrict__ xpe, const int* __restrict__ ord,
                               const float* __restrict__ xpw, const float* __restrict__ dtw,
                               const float* __restrict__ dtb, const float* __restrict__ dproj,
                               const float* __restrict__ dsig, float* __restrict__ dtbuf,
                               float* __restrict__ bscs) {
    __shared__ float u[16][193];
    __shared__ float dbl[16][40];
    __shared__ int jarr[16];
    int chunk = blockIdx.x & 255;
    int k = (blockIdx.x >> 8) & 1;
    int b = blockIdx.x >> 9;
    int s0 = chunk * 16;
    int tid = threadIdx.x;
    if (tid < 16) {
        int s = s0 + tid;
        jarr[tid] = ord[b * LL + ((k == 0) ? s : (LL - 1 - s))];
    }
    __syncthreads();
    for (int t = tid; t < 16 * DI; t += 256) {
        int l = t / DI, i = t - l * DI;
        u[l][i] = xpe[(size_t)(b * LL + jarr[l]) * DI + i];
    }
    __syncthreads();
    {
        int og = tid >> 4, sl = tid & 15;
        float a0 = 0.f, a1 = 0.f, a2 = 0.f;
        const float* w0 = xpw + (size_t)(k * 38 + og) * DI;
        const float* w1 = w0 + 16 * DI;
        const float* w2 = w0 + 32 * DI;
        bool has2 = (og < 6);
        for (int i = 0; i < DI; ++i) {
            float uu = u[sl][i];
            a0 += w0[i] * uu;
            a1 += w1[i] * uu;
            if (has2) a2 += w2[i] * uu;
        }
        dbl[sl][og] = a0;
        dbl[sl][og + 16] = a1;
        if (has2) dbl[sl][og + 32] = a2;
    }
    __syncthreads();
    if (tid < DI) {
        int c = tid;
        float w[6];
        #pragma unroll
        for (int r = 0; r < 6; ++r) w[r] = dtw[(k * DI + c) * DTR + r];
        float bias = dtb[k * DI + c];
        for (int sl = 0; sl < 16; ++sl) {
            float d = bias;
            #pragma unroll
            for (int r = 0; r < 6; ++r) d += w[r] * dbl[sl][r];
            float sp = fmaxf(d, 0.f) + log1pf(__expf(-fabsf(d)));
            dtbuf[((size_t)(b * 2 + k) * LL + s0 + sl) * DI + c] = sp;
        }
    }
    {
        int sl = tid >> 4, n = tid & 15;
        int j = jarr[sl];
        float w = dsig[(size_t)(b * LL + j) * NST + n];
        float Bo = dbl[sl][6 + n], Co = dbl[sl][22 + n];
        float Bd = dproj[(size_t)(b * LL + j) * 64 + k * 32 + n];
        float Cd = dproj[(size_t)(b * LL + j) * 64 + k * 32 + 16 + n];
        size_t base = ((size_t)(b * 2 + k) * LL + s0 + sl) * 32;
        bscs[base + n] = (1.f - w) * Bo + w * Bd;
        bscs[base + 16 + n] = (1.f - w) * Co + w * Cd;
    }
}

// ---------------- scan pass1: per-chunk partial state + decay product ---------
__global__ __launch_bounds__(256) void scan1_kernel(const float* __restrict__ dtbuf,
        const float* __restrict__ xpe, const int* __restrict__ ord,
        const float* __restrict__ bscs, const float* __restrict__ Alog,
        float* __restrict__ hp, float* __restrict__ Ap) {
    int wid = (blockIdx.x << 2) | (threadIdx.x >> 6);
    int lane = threadIdx.x & 63;
    int ch = wid & 63;
    int cg = (wid >> 6) % 48;
    int k = (wid / 3072) & 1;
    int b = wid / 6144;
    int c = cg * 4 + (lane >> 4);
    int n = lane & 15;
    float A = -__expf(Alog[(k * DI + c) * NST + n]);
    const float* dtp = dtbuf + (size_t)(b * 2 + k) * LL * DI + c;
    const float* bp = bscs + (size_t)(b * 2 + k) * LL * 32 + n;
    const int* op = ord + b * LL;
    float h = 0.f, cA = 1.f;
    int s0 = ch * CHL;
    for (int t = 0; t < CHL; ++t) {
        int s = s0 + t;
        int j = op[(k == 0) ? s : (LL - 1 - s)];
        float dt = dtp[(size_t)s * DI];
        float uu = xpe[(size_t)(b * LL + j) * DI + c];
        float Bv = bp[(size_t)s * 32];
        float e = __expf(dt * A);
        h = h * e + dt * uu * Bv;
        cA *= e;
    }
    int q = ((b * 2 + k) * DI + c) * NST + n;
    hp[ch * NQ + q] = h;
    Ap[ch * NQ + q] = cA;
}

// ---------------- scan pass2: sequential over chunks (exclusive) --------------
__global__ void scan2_kernel(const float* __restrict__ hp, const float* __restrict__ Ap,
                             float* __restrict__ hin) {
    int q = blockIdx.x * 256 + threadIdx.x;
    float carry = 0.f;
    for (int ch = 0; ch < NCH; ++ch) {
        hin[ch * NQ + q] = carry;
        carry = hp[ch * NQ + q] + Ap[ch * NQ + q] * carry;
    }
}

// ---------------- scan pass3: replay with true h_in, emit y -------------------
__global__ __launch_bounds__(256) void scan3_kernel(const float* __restrict__ dtbuf,
        const float* __restrict__ xpe, const int* __restrict__ ord,
        const float* __restrict__ bscs, const float* __restrict__ Alog,
        const float* __restrict__ hin, float* __restrict__ y) {
    int wid = (blockIdx.x << 2) | (threadIdx.x >> 6);
    int lane = threadIdx.x & 63;
    int ch = wid & 63;
    int cg = (wid >> 6) % 48;
    int k = (wid / 3072) & 1;
    int b = wid / 6144;
    int c = cg * 4 + (lane >> 4);
    int n = lane & 15;
    float A = -__expf(Alog[(k * DI + c) * NST + n]);
    const float* dtp = dtbuf + (size_t)(b * 2 + k) * LL * DI + c;
    const float* bp = bscs + (size_t)(b * 2 + k) * LL * 32 + n;
    const int* op = ord + b * LL;
    int q = ((b * 2 + k) * DI + c) * NST + n;
    float h = hin[ch * NQ + q];
    int s0 = ch * CHL;
    for (int t = 0; t < CHL; ++t) {
        int s = s0 + t;
        int j = op[(k == 0) ? s : (LL - 1 - s)];
        float dt = dtp[(size_t)s * DI];
        float uu = xpe[(size_t)(b * LL + j) * DI + c];
        float Bv = bp[(size_t)s * 32];
        float Cv = bp[(size_t)s * 32 + 16];
        float e = __expf(dt * A);
        h = h * e + dt * uu * Bv;
        float yp = h * Cv;
        yp += __shfl_xor(yp, 1);
        yp += __shfl_xor(yp, 2);
        yp += __shfl_xor(yp, 4);
        yp += __shfl_xor(yp, 8);
        if (n == 0) y[((size_t)(b * 2 + k) * LL + s) * DI + c] = yp;
    }
}

// ---------------- gather (inverse perm) + D*u + layernorm + output ------------
__global__ void ln_kernel(const float* __restrict__ y, const float* __restrict__ xpe,
                          const int* __restrict__ inv, const float* __restrict__ Dvec,
                          const float* __restrict__ g, const float* __restrict__ beta,
                          float* __restrict__ out, int X) {
    int w = threadIdx.x >> 6, lane = threadIdx.x & 63;
    int bl = blockIdx.x * 4 + w;
    int b = bl >> 12, l = bl & 4095;
    int s0 = inv[b * LL + l];
    int s1 = LL - 1 - s0;
    const float* y0 = y + ((size_t)(b * 2 + 0) * LL + s0) * DI;
    const float* y1 = y + ((size_t)(b * 2 + 1) * LL + s1) * DI;
    const float* xr = xpe + (size_t)(b * LL + l) * DI;
    float v[3];
    float sum = 0.f, sq = 0.f;
    #pragma unroll
    for (int r = 0; r < 3; ++r) {
        int c = lane + r * 64;
        float t = y0[c] + y1[c] + (Dvec[c] + Dvec[DI + c]) * xr[c];
        v[r] = t; sum += t; sq += t * t;
    }
    #pragma unroll
    for (int m = 1; m < 64; m <<= 1) {
        sum += __shfl_xor(sum, m);
        sq += __shfl_xor(sq, m);
    }
    float mu = sum * (1.f / 192.f);
    float var = sq * (1.f / 192.f) - mu * mu;
    float rs = rsqrtf(var + 1e-5f);
    float* op = out + ((size_t)(X * 2 + b) * LL + l) * DI;
    #pragma unroll
    for (int r = 0; r < 3; ++r) {
        int c = lane + r * 64;
        op[c] = (v[r] - mu) * rs * g[c] + beta[c];
    }
}

extern "C" void kernel_launch(void* const* d_in, const int* in_sizes, int n_in,
                              void* d_out, int out_size, void* d_ws, size_t ws_size,
                              hipStream_t stream) {
    const float* x_T = (const float*)d_in[0];
    const float* x_R = (const float*)d_in[1];
    const float* prox = (const float*)d_in[2];
    const float* fuse_w = (const float*)d_in[3];
    const float* fuse_b = (const float*)d_in[4];
    const float* x_proj_w = (const float*)d_in[5];
    const float* dt_w = (const float*)d_in[6];
    const float* dt_b = (const float*)d_in[7];
    const float* A_log_T = (const float*)d_in[8];
    const float* A_log_R = (const float*)d_in[9];
    const float* D_T = (const float*)d_in[10];
    const float* D_R = (const float*)d_in[11];
    const float* depth_enc_w = (const float*)d_in[12];
    const float* depth_enc_b = (const float*)d_in[13];
    const float* depth_proj_w = (const float*)d_in[14];
    const float* sig_w = (const float*)d_in[15];
    const float* sig_b = (const float*)d_in[16];
    const float* ln_g = (const float*)d_in[17];
    const float* ln_b = (const float*)d_in[18];
    float* out = (float*)d_out;
    char* ws = (char*)d_ws;

    float* pe    = (float*)(ws + 0);         //   49152
    float* pm    = (float*)(ws + 49152);     //   65536
    int*   ord   = (int*)(ws + 114688);      //   65536
    int*   inv   = (int*)(ws + 180224);      //   65536
    float* proxt = (float*)(ws + 245760);    // 6291456
    float* dproj = (float*)(ws + 6537216);   // 2097152
    float* dsig  = (float*)(ws + 8634368);   //  524288
    float* xpe   = (float*)(ws + 9158656);   // 6291456 (reused per branch)
    float* dtbuf = (float*)(ws + 15450112);  // 12582912
    float* bscs  = (float*)(ws + 28033024);  // 2097152
    float* hp    = (float*)(ws + 30130176);  // 3145728
    float* Ap    = (float*)(ws + 33275904);  // 3145728
    float* hin   = (float*)(ws + 36421632);  // 3145728
    float* ybuf  = (float*)(ws + 39567360);  // 12582912  -> total 52150272
    float* pbuf  = dtbuf;                    // fuse partials (dead until project)

    pe_kernel<<<48, 256, 0, stream>>>(pe);
    fusepm_part_kernel<<<dim3(12, 64, 2), 256, 0, stream>>>(x_T, x_R, prox, fuse_w, pbuf);
    fusepm_reduce_kernel<<<64, 256, 0, stream>>>(pbuf, fuse_b, pm);
    sort_kernel<<<4, 1024, 0, stream>>>(pm, ord, inv);
    transpose_pe_kernel<<<dim3(128, 6, 2), dim3(32, 8), 0, stream>>>(prox, proxt, pe, 0);
    depth_kernel<<<512, 256, 0, stream>>>(proxt, depth_enc_w, depth_enc_b, depth_proj_w,
                                          sig_w, sig_b, dproj, dsig);
    for (int X = 0; X < 2; ++X) {
        const float* xin = X ? x_R : x_T;
        const float* Alog = X ? A_log_R : A_log_T;
        const float* Dv = X ? D_R : D_T;
        const int* ordX = ord + X * 2 * LL;
        const int* invX = inv + X * 2 * LL;
        transpose_pe_kernel<<<dim3(128, 6, 2), dim3(32, 8), 0, stream>>>(xin, xpe, pe, 1);
        project_kernel<<<1024, 256, 0, stream>>>(xpe, ordX, x_proj_w, dt_w, dt_b,
                                                 dproj, dsig, dtbuf, bscs);
        scan1_kernel<<<3072, 256, 0, stream>>>(dtbuf, xpe, ordX, bscs, Alog, hp, Ap);
        scan2_kernel<<<48, 256, 0, stream>>>(hp, Ap, hin);
        scan3_kernel<<<3072, 256, 0, stream>>>(dtbuf, xpe, ordX, bscs, Alog, hin, ybuf);
        ln_kernel<<<2048, 256, 0, stream>>>(ybuf, xpe, invX, Dv, ln_g, ln_b, out, X);
    }
}

// Round 3
// 431.276 us; speedup vs baseline: 1.3214x; 1.1136x over previous
//
#include <hip/hip_runtime.h>
#include <hip/hip_bf16.h>
#include <math.h>

// Problem constants
#define BATCH 2
#define DI 192          // D_INNER
#define NST 16          // D_STATE
#define DTR 6           // DT_RANK
#define KK 2
#define LL 4096
#define NCH 64          // scan chunks
#define CHL 64          // chunk length
#define NQ (BATCH*KK*DI*NST)   // 12288 chains

// ---------------- pe table: pe[col][c], col=l%64 ----------------
__global__ void pe_kernel(float* __restrict__ pe) {
    int i = blockIdx.x * 256 + threadIdx.x;
    if (i >= 64 * DI) return;
    int col = i / DI, c = i % DI;
    float gx = (float)col / 63.f;
    int m = (c < 96) ? c : (c - 96);
    float invf = expf(-(float)m * (logf(10000.f) / 96.f));
    float ang = gx * invf;
    pe[i] = (c < 96) ? sinf(ang) : cosf(ang);
}

// ---------------- fuse conv partials: grid (12 cgroups, 64 rows, 2 b) --------
// pbuf layout: [(cg*4 + X*2 + b)][L]  (X=0:T, X=1:R), raw pre-activation partial
__global__ void fusepm_part_kernel(const float* __restrict__ xT, const float* __restrict__ xR,
                                   const float* __restrict__ prox, const float* __restrict__ fw,
                                   float* __restrict__ pbuf) {
    __shared__ float wl[288];          // 16ch x 9 (x-half) + 16ch x 9 (prox-half)
    __shared__ float red[2][4][64];
    int cg = blockIdx.x;
    int row = blockIdx.y;
    int b = blockIdx.z;
    int tid = threadIdx.x;
    if (tid < 288) {
        int cl = (tid % 144) / 9, tap = tid % 9;
        int half = tid / 144;                    // 0: x-half, 1: prox-half
        wl[tid] = fw[(half * DI + cg * 16 + cl) * 9 + tap];
    }
    __syncthreads();
    int px = tid & 63, g = tid >> 6;
    float aT = 0.f, aR = 0.f, aP = 0.f;
    #pragma unroll
    for (int cc = 0; cc < 4; ++cc) {
        int cl = g * 4 + cc;
        int c = cg * 16 + cl;
        const float* xTb = xT + (size_t)(b * DI + c) * LL;
        const float* xRb = xR + (size_t)(b * DI + c) * LL;
        const float* pb  = prox + (size_t)(b * DI + c) * LL;
        const float* wT = wl + cl * 9;
        const float* wP = wl + 144 + cl * 9;
        #pragma unroll
        for (int ky = 0; ky < 3; ++ky) {
            int yy = row + ky - 1;
            if (yy < 0 || yy > 63) continue;
            #pragma unroll
            for (int kx = 0; kx < 3; ++kx) {
                int xx = px + kx - 1;
                bool in = (xx >= 0 && xx < 64);
                int o = yy * 64 + (in ? xx : 0);
                float mT = in ? xTb[o] : 0.f;
                float mR = in ? xRb[o] : 0.f;
                float mP = in ? pb[o] : 0.f;
                float wTv = wT[ky * 3 + kx], wPv = wP[ky * 3 + kx];
                aT += mT * wTv;
                aR += mR * wTv;
                aP += mP * wPv;
            }
        }
    }
    red[0][g][px] = aT + aP;
    red[1][g][px] = aR + aP;
    __syncthreads();
    if (tid < 128) {
        int X = tid >> 6, x = tid & 63;
        float s = red[X][0][x] + red[X][1][x] + red[X][2][x] + red[X][3][x];
        pbuf[(size_t)(cg * 4 + X * 2 + b) * LL + row * 64 + x] = s;
    }
}

// ---------------- reduce 12 partials -> pm[X*2+b][L] ----------------
__global__ void fusepm_reduce_kernel(const float* __restrict__ pbuf,
                                     const float* __restrict__ fb,
                                     float* __restrict__ pm) {
    int idx = blockIdx.x * 256 + threadIdx.x;   // idx over 4*LL
    int Xb = idx >> 12;                          // X*2+b
    int l = idx & 4095;
    float s = fb[0];
    #pragma unroll
    for (int cg = 0; cg < 12; ++cg)
        s += pbuf[(size_t)(cg * 4 + Xb) * LL + l];
    pm[(size_t)Xb * LL + l] = s;
}

// ---------------- bitonic argsort (stable via index tie-break) ----------------
__global__ void sort_kernel(const float* __restrict__ pm, int* __restrict__ ord,
                            int* __restrict__ inv) {
    __shared__ float key[LL];
    __shared__ int idx[LL];
    int X = blockIdx.x >> 1, b = blockIdx.x & 1;
    const float* z = pm + (X * 2 + b) * LL;
    for (int i = threadIdx.x; i < LL; i += 1024) {
        float v = z[i];
        key[i] = (X == 0) ? -v : v;
        idx[i] = i;
    }
    __syncthreads();
    for (int k = 2; k <= LL; k <<= 1) {
        for (int j = k >> 1; j >= 1; j >>= 1) {
            for (int t = threadIdx.x; t < LL / 2; t += 1024) {
                int i = ((t & ~(j - 1)) << 1) | (t & (j - 1));
                int p = i | j;
                bool asc = ((i & k) == 0);
                float ka = key[i], kb = key[p];
                int ia = idx[i], ib = idx[p];
                bool agt = (ka > kb) || (ka == kb && ia > ib);
                if (agt == asc) { key[i] = kb; key[p] = ka; idx[i] = ib; idx[p] = ia; }
            }
            __syncthreads();
        }
    }
    int* o = ord + (X * 2 + b) * LL;
    int* iv = inv + (X * 2 + b) * LL;
    for (int s = threadIdx.x; s < LL; s += 1024) {
        int j = idx[s];
        o[s] = j;
        iv[j] = s;
    }
}

// ---------------- transpose NCHW (b,c,l) -> (b,l,c), optionally add pe --------
__global__ void transpose_pe_kernel(const float* __restrict__ in, float* __restrict__ out,
                                    const float* __restrict__ pe, int use_pe) {
    __shared__ float tile[32][33];
    int b = blockIdx.z;
    int l0 = blockIdx.x * 32, c0 = blockIdx.y * 32;
    int tx = threadIdx.x, ty = threadIdx.y;
    #pragma unroll
    for (int r = 0; r < 4; ++r) {
        int c = c0 + ty + r * 8;
        tile[ty + r * 8][tx] = in[(size_t)(b * DI + c) * LL + l0 + tx];
    }
    __syncthreads();
    #pragma unroll
    for (int r = 0; r < 4; ++r) {
        int l = l0 + ty + r * 8;
        int c = c0 + tx;
        float v = tile[tx][ty + r * 8];
        if (use_pe) v += pe[(l & 63) * DI + c];
        out[(size_t)(b * LL + l) * DI + c] = v;
    }
}

// ---------------- depth path: df = leaky(Wde@pv+b); dproj = dpw@df; dsig ------
__global__ void depth_kernel(const float* __restrict__ proxt, const float* __restrict__ wde,
                             const float* __restrict__ bde, const float* __restrict__ dpw,
                             const float* __restrict__ sgw, const float* __restrict__ sgb,
                             float* __restrict__ dproj, float* __restrict__ dsig) {
    __shared__ float pvs[16][DI];
    __shared__ float dfs[16][DI];
    int bl0 = blockIdx.x * 16;
    int tid = threadIdx.x;
    for (int t = tid; t < 16 * DI; t += 256)
        pvs[t / DI][t % DI] = proxt[(size_t)bl0 * DI + t];
    __syncthreads();
    if (tid < DI) {
        float acc[16];
        #pragma unroll
        for (int l = 0; l < 16; ++l) acc[l] = 0.f;
        for (int i = 0; i < DI; ++i) {
            float w = wde[tid * DI + i];
            #pragma unroll
            for (int l = 0; l < 16; ++l) acc[l] += w * pvs[l][i];
        }
        float bias = bde[tid];
        #pragma unroll
        for (int l = 0; l < 16; ++l) {
            float v = acc[l] + bias;
            dfs[l][tid] = (v > 0.f) ? v : 0.2f * v;
        }
    }
    __syncthreads();
    if (tid < 80) {
        float acc[16];
        #pragma unroll
        for (int l = 0; l < 16; ++l) acc[l] = 0.f;
        const float* wrow = (tid < 64) ? (dpw + tid * DI) : (sgw + (tid - 64) * DI);
        for (int i = 0; i < DI; ++i) {
            float w = wrow[i];
            #pragma unroll
            for (int l = 0; l < 16; ++l) acc[l] += w * dfs[l][i];
        }
        if (tid < 64) {
            #pragma unroll
            for (int l = 0; l < 16; ++l) dproj[(size_t)(bl0 + l) * 64 + tid] = acc[l];
        } else {
            float bias = sgb[tid - 64];
            #pragma unroll
            for (int l = 0; l < 16; ++l) {
                float v = acc[l] + bias;
                v = (v > 0.f) ? v : 0.2f * v;
                dsig[(size_t)(bl0 + l) * NST + (tid - 64)] = 1.f / (1.f + __expf(-v));
            }
        }
    }
}

// ---------------- per-(b,k,s): x_dbl proj, delta, Bs/Cs -> s-minor buffers ----
// dtb2/dub2: [bk][c][s] ; bscs2: [bk][n][s] (B rows 0..15, C rows 16..31)
__global__ void project_kernel(const float* __restrict__ xpe, const int* __restrict__ ord,
                               const float* __restrict__ xpw, const float* __restrict__ dtw,
                               const float* __restrict__ dtb, const float* __restrict__ dproj,
                               const float* __restrict__ dsig, float* __restrict__ dtb2,
                               float* __restrict__ dub2, float* __restrict__ bscs2) {
    __shared__ float u[16][193];
    __shared__ float dbl[16][40];
    __shared__ int jarr[16];
    int chunk = blockIdx.x & 255;
    int k = (blockIdx.x >> 8) & 1;
    int b = blockIdx.x >> 9;
    int bk = b * 2 + k;
    int s0 = chunk * 16;
    int tid = threadIdx.x;
    if (tid < 16) {
        int s = s0 + tid;
        jarr[tid] = ord[b * LL + ((k == 0) ? s : (LL - 1 - s))];
    }
    __syncthreads();
    for (int t = tid; t < 16 * DI; t += 256) {
        int l = t / DI, i = t - l * DI;
        u[l][i] = xpe[(size_t)(b * LL + jarr[l]) * DI + i];
    }
    __syncthreads();
    {
        int og = tid >> 4, sl = tid & 15;
        float a0 = 0.f, a1 = 0.f, a2 = 0.f;
        const float* w0 = xpw + (size_t)(k * 38 + og) * DI;
        const float* w1 = w0 + 16 * DI;
        const float* w2 = w0 + 32 * DI;
        bool has2 = (og < 6);
        for (int i = 0; i < DI; ++i) {
            float uu = u[sl][i];
            a0 += w0[i] * uu;
            a1 += w1[i] * uu;
            if (has2) a2 += w2[i] * uu;
        }
        dbl[sl][og] = a0;
        dbl[sl][og + 16] = a1;
        if (has2) dbl[sl][og + 32] = a2;
    }
    __syncthreads();
    if (tid < DI) {
        int c = tid;
        float w[6];
        #pragma unroll
        for (int r = 0; r < 6; ++r) w[r] = dtw[(k * DI + c) * DTR + r];
        float bias = dtb[k * DI + c];
        float dtl[16], dul[16];
        #pragma unroll
        for (int sl = 0; sl < 16; ++sl) {
            float d = bias;
            #pragma unroll
            for (int r = 0; r < 6; ++r) d += w[r] * dbl[sl][r];
            float sp = fmaxf(d, 0.f) + log1pf(__expf(-fabsf(d)));
            dtl[sl] = sp;
            dul[sl] = sp * u[sl][c];
        }
        size_t base = (size_t)(bk * DI + c) * LL + s0;
        #pragma unroll
        for (int g = 0; g < 4; ++g) {
            *(float4*)(dtb2 + base + g * 4) =
                make_float4(dtl[g*4], dtl[g*4+1], dtl[g*4+2], dtl[g*4+3]);
            *(float4*)(dub2 + base + g * 4) =
                make_float4(dul[g*4], dul[g*4+1], dul[g*4+2], dul[g*4+3]);
        }
    }
    {
        int n = tid >> 4, sl = tid & 15;   // consecutive tid -> consecutive sl
        int j = jarr[sl];
        float w = dsig[(size_t)(b * LL + j) * NST + n];
        float Bo = dbl[sl][6 + n], Co = dbl[sl][22 + n];
        float Bd = dproj[(size_t)(b * LL + j) * 64 + k * 32 + n];
        float Cd = dproj[(size_t)(b * LL + j) * 64 + k * 32 + 16 + n];
        size_t sb = (size_t)(bk * 32 + n) * LL + s0 + sl;
        bscs2[sb] = (1.f - w) * Bo + w * Bd;
        bscs2[sb + (size_t)16 * LL] = (1.f - w) * Co + w * Cd;
    }
}

// ---------------- scan pass1: per-chunk partial state + decay product ---------
__global__ __launch_bounds__(256) void scan1_kernel(const float* __restrict__ dtb2,
        const float* __restrict__ dub2, const float* __restrict__ bscs2,
        const float* __restrict__ Alog, float* __restrict__ hp, float* __restrict__ Ap) {
    int wid = (blockIdx.x << 2) | (threadIdx.x >> 6);
    int lane = threadIdx.x & 63;
    int ch = wid & 63;
    int cg = (wid >> 6) % 48;
    int k = (wid / 3072) & 1;
    int b = wid / 6144;
    int c = cg * 4 + (lane >> 4);
    int n = lane & 15;
    int bk = b * 2 + k;
    float A = -__expf(Alog[(k * DI + c) * NST + n]);
    size_t rowc = (size_t)(bk * DI + c) * LL + ch * CHL;
    const float* dtp = dtb2 + rowc;
    const float* dup = dub2 + rowc;
    const float* bp = bscs2 + (size_t)(bk * 32 + n) * LL + ch * CHL;
    float h = 0.f, S = 0.f;
    #pragma unroll 4
    for (int g = 0; g < 16; ++g) {
        float4 d4 = *(const float4*)(dtp + g * 4);
        float4 u4 = *(const float4*)(dup + g * 4);
        float4 b4 = *(const float4*)(bp + g * 4);
        S += d4.x + d4.y + d4.z + d4.w;
        float e0 = __expf(d4.x * A), e1 = __expf(d4.y * A);
        float e2 = __expf(d4.z * A), e3 = __expf(d4.w * A);
        h = h * e0 + u4.x * b4.x;
        h = h * e1 + u4.y * b4.y;
        h = h * e2 + u4.z * b4.z;
        h = h * e3 + u4.w * b4.w;
    }
    int q = (bk * DI + c) * NST + n;
    hp[ch * NQ + q] = h;
    Ap[ch * NQ + q] = __expf(S * A);   // prod of per-step decays = exp(A * sum dt)
}

// ---------------- scan pass2: sequential over chunks, in-place exclusive ------
__global__ void scan2_kernel(float* __restrict__ hp, const float* __restrict__ Ap) {
    int q = blockIdx.x * 256 + threadIdx.x;
    float carry = 0.f;
    for (int ch = 0; ch < NCH; ++ch) {
        float t = hp[ch * NQ + q];
        hp[ch * NQ + q] = carry;              // hp becomes h_in (exclusive)
        carry = t + Ap[ch * NQ + q] * carry;
    }
}

// ---------------- scan pass3: replay with true h_in, emit y -------------------
__global__ __launch_bounds__(256) void scan3_kernel(const float* __restrict__ dtb2,
        const float* __restrict__ dub2, const float* __restrict__ bscs2,
        const float* __restrict__ Alog, const float* __restrict__ hin,
        float* __restrict__ y) {
    int wid = (blockIdx.x << 2) | (threadIdx.x >> 6);
    int lane = threadIdx.x & 63;
    int ch = wid & 63;
    int cg = (wid >> 6) % 48;
    int k = (wid / 3072) & 1;
    int b = wid / 6144;
    int c = cg * 4 + (lane >> 4);
    int n = lane & 15;
    int bk = b * 2 + k;
    float A = -__expf(Alog[(k * DI + c) * NST + n]);
    size_t rowc = (size_t)(bk * DI + c) * LL + ch * CHL;
    const float* dtp = dtb2 + rowc;
    const float* dup = dub2 + rowc;
    const float* bp = bscs2 + (size_t)(bk * 32 + n) * LL + ch * CHL;
    const float* cp = bp + (size_t)16 * LL;
    int q = (bk * DI + c) * NST + n;
    float h = hin[ch * NQ + q];
    float* yb = y + ((size_t)bk * LL + ch * CHL) * DI + c;
    #pragma unroll 2
    for (int g = 0; g < 16; ++g) {
        float4 d4 = *(const float4*)(dtp + g * 4);
        float4 u4 = *(const float4*)(dup + g * 4);
        float4 b4 = *(const float4*)(bp + g * 4);
        float4 c4 = *(const float4*)(cp + g * 4);
        float e;
        e = __expf(d4.x * A); h = h * e + u4.x * b4.x; float y0 = h * c4.x;
        e = __expf(d4.y * A); h = h * e + u4.y * b4.y; float y1 = h * c4.y;
        e = __expf(d4.z * A); h = h * e + u4.z * b4.z; float y2 = h * c4.z;
        e = __expf(d4.w * A); h = h * e + u4.w * b4.w; float y3 = h * c4.w;
        y0 += __shfl_xor(y0, 1); y1 += __shfl_xor(y1, 1);
        y2 += __shfl_xor(y2, 1); y3 += __shfl_xor(y3, 1);
        y0 += __shfl_xor(y0, 2); y1 += __shfl_xor(y1, 2);
        y2 += __shfl_xor(y2, 2); y3 += __shfl_xor(y3, 2);
        y0 += __shfl_xor(y0, 4); y1 += __shfl_xor(y1, 4);
        y2 += __shfl_xor(y2, 4); y3 += __shfl_xor(y3, 4);
        y0 += __shfl_xor(y0, 8); y1 += __shfl_xor(y1, 8);
        y2 += __shfl_xor(y2, 8); y3 += __shfl_xor(y3, 8);
        if (n == 0) {
            yb[(size_t)(g * 4 + 0) * DI] = y0;
            yb[(size_t)(g * 4 + 1) * DI] = y1;
            yb[(size_t)(g * 4 + 2) * DI] = y2;
            yb[(size_t)(g * 4 + 3) * DI] = y3;
        }
    }
}

// ---------------- gather (inverse perm) + D*u + layernorm + output ------------
__global__ void ln_kernel(const float* __restrict__ y, const float* __restrict__ xpe,
                          const int* __restrict__ inv, const float* __restrict__ Dvec,
                          const float* __restrict__ g, const float* __restrict__ beta,
                          float* __restrict__ out, int X) {
    int w = threadIdx.x >> 6, lane = threadIdx.x & 63;
    int bl = blockIdx.x * 4 + w;
    int b = bl >> 12, l = bl & 4095;
    int s0 = inv[b * LL + l];
    int s1 = LL - 1 - s0;
    const float* y0 = y + ((size_t)(b * 2 + 0) * LL + s0) * DI;
    const float* y1 = y + ((size_t)(b * 2 + 1) * LL + s1) * DI;
    const float* xr = xpe + (size_t)(b * LL + l) * DI;
    float v[3];
    float sum = 0.f, sq = 0.f;
    #pragma unroll
    for (int r = 0; r < 3; ++r) {
        int c = lane + r * 64;
        float t = y0[c] + y1[c] + (Dvec[c] + Dvec[DI + c]) * xr[c];
        v[r] = t; sum += t; sq += t * t;
    }
    #pragma unroll
    for (int m = 1; m < 64; m <<= 1) {
        sum += __shfl_xor(sum, m);
        sq += __shfl_xor(sq, m);
    }
    float mu = sum * (1.f / 192.f);
    float var = sq * (1.f / 192.f) - mu * mu;
    float rs = rsqrtf(var + 1e-5f);
    float* op = out + ((size_t)(X * 2 + b) * LL + l) * DI;
    #pragma unroll
    for (int r = 0; r < 3; ++r) {
        int c = lane + r * 64;
        op[c] = (v[r] - mu) * rs * g[c] + beta[c];
    }
}

extern "C" void kernel_launch(void* const* d_in, const int* in_sizes, int n_in,
                              void* d_out, int out_size, void* d_ws, size_t ws_size,
                              hipStream_t stream) {
    const float* x_T = (const float*)d_in[0];
    const float* x_R = (const float*)d_in[1];
    const float* prox = (const float*)d_in[2];
    const float* fuse_w = (const float*)d_in[3];
    const float* fuse_b = (const float*)d_in[4];
    const float* x_proj_w = (const float*)d_in[5];
    const float* dt_w = (const float*)d_in[6];
    const float* dt_b = (const float*)d_in[7];
    const float* A_log_T = (const float*)d_in[8];
    const float* A_log_R = (const float*)d_in[9];
    const float* D_T = (const float*)d_in[10];
    const float* D_R = (const float*)d_in[11];
    const float* depth_enc_w = (const float*)d_in[12];
    const float* depth_enc_b = (const float*)d_in[13];
    const float* depth_proj_w = (const float*)d_in[14];
    const float* sig_w = (const float*)d_in[15];
    const float* sig_b = (const float*)d_in[16];
    const float* ln_g = (const float*)d_in[17];
    const float* ln_b = (const float*)d_in[18];
    float* out = (float*)d_out;
    char* ws = (char*)d_ws;

    float* pe    = (float*)(ws + 0);         //   49152
    float* pm    = (float*)(ws + 49152);     //   65536
    int*   ord   = (int*)(ws + 114688);      //   65536
    int*   inv   = (int*)(ws + 180224);      //   65536
    float* proxt = (float*)(ws + 245760);    // 6291456 (dead after depth_kernel)
    float* hp    = (float*)(ws + 245760);    // 3145728 (aliases proxt)
    float* Ap    = (float*)(ws + 3391488);   // 3145728 (aliases proxt)
    float* dproj = (float*)(ws + 6537216);   // 2097152
    float* dsig  = (float*)(ws + 8634368);   //  524288
    float* xpe   = (float*)(ws + 9158656);   // 6291456 (reused per branch)
    float* dtb2  = (float*)(ws + 15450112);  // 12582912
    float* dub2  = (float*)(ws + 28033024);  // 12582912
    float* bscs2 = (float*)(ws + 40615936);  // 2097152
    float* ybuf  = (float*)(ws + 42713088);  // 12582912  -> total 55296000
    float* pbuf  = dtb2;                     // fuse partials (dead until project)

    pe_kernel<<<48, 256, 0, stream>>>(pe);
    fusepm_part_kernel<<<dim3(12, 64, 2), 256, 0, stream>>>(x_T, x_R, prox, fuse_w, pbuf);
    fusepm_reduce_kernel<<<64, 256, 0, stream>>>(pbuf, fuse_b, pm);
    sort_kernel<<<4, 1024, 0, stream>>>(pm, ord, inv);
    transpose_pe_kernel<<<dim3(128, 6, 2), dim3(32, 8), 0, stream>>>(prox, proxt, pe, 0);
    depth_kernel<<<512, 256, 0, stream>>>(proxt, depth_enc_w, depth_enc_b, depth_proj_w,
                                          sig_w, sig_b, dproj, dsig);
    for (int X = 0; X < 2; ++X) {
        const float* xin = X ? x_R : x_T;
        const float* Alog = X ? A_log_R : A_log_T;
        const float* Dv = X ? D_R : D_T;
        const int* ordX = ord + X * 2 * LL;
        const int* invX = inv + X * 2 * LL;
        transpose_pe_kernel<<<dim3(128, 6, 2), dim3(32, 8), 0, stream>>>(xin, xpe, pe, 1);
        project_kernel<<<1024, 256, 0, stream>>>(xpe, ordX, x_proj_w, dt_w, dt_b,
                                                 dproj, dsig, dtb2, dub2, bscs2);
        scan1_kernel<<<3072, 256, 0, stream>>>(dtb2, dub2, bscs2, Alog, hp, Ap);
        scan2_kernel<<<48, 256, 0, stream>>>(hp, Ap);
        scan3_kernel<<<3072, 256, 0, stream>>>(dtb2, dub2, bscs2, Alog, hp, ybuf);
        ln_kernel<<<2048, 256, 0, stream>>>(ybuf, xpe, invX, Dv, ln_g, ln_b, out, X);
    }
}

// Round 4
// 330.696 us; speedup vs baseline: 1.7233x; 1.3041x over previous
//
#include <hip/hip_runtime.h>
#include <hip/hip_bf16.h>
#include <math.h>

// Problem constants
#define BATCH 2
#define DI 192          // D_INNER
#define NST 16          // D_STATE
#define DTR 6           // DT_RANK
#define KK 2
#define LL 4096
#define CT 256          // timesteps per scan chunk (4 per lane)
#define NCK (LL/CT)     // 16 chunk iterations

// ---------------- pe table: pe[col][c], col=l%64 ----------------
__global__ void pe_kernel(float* __restrict__ pe) {
    int i = blockIdx.x * 256 + threadIdx.x;
    if (i >= 64 * DI) return;
    int col = i / DI, c = i % DI;
    float gx = (float)col / 63.f;
    int m = (c < 96) ? c : (c - 96);
    float invf = expf(-(float)m * (logf(10000.f) / 96.f));
    float ang = gx * invf;
    pe[i] = (c < 96) ? sinf(ang) : cosf(ang);
}

// ---------------- fuse conv partials: grid (12 cgroups, 64 rows, 2 b) --------
// pbuf layout: [(cg*4 + X*2 + b)][L]  (X=0:T, X=1:R), raw pre-activation partial
__global__ void fusepm_part_kernel(const float* __restrict__ xT, const float* __restrict__ xR,
                                   const float* __restrict__ prox, const float* __restrict__ fw,
                                   float* __restrict__ pbuf) {
    __shared__ float wl[288];          // 16ch x 9 (x-half) + 16ch x 9 (prox-half)
    __shared__ float red[2][4][64];
    int cg = blockIdx.x;
    int row = blockIdx.y;
    int b = blockIdx.z;
    int tid = threadIdx.x;
    if (tid < 288) {
        int cl = (tid % 144) / 9, tap = tid % 9;
        int half = tid / 144;                    // 0: x-half, 1: prox-half
        wl[tid] = fw[(half * DI + cg * 16 + cl) * 9 + tap];
    }
    __syncthreads();
    int px = tid & 63, g = tid >> 6;
    float aT = 0.f, aR = 0.f, aP = 0.f;
    #pragma unroll
    for (int cc = 0; cc < 4; ++cc) {
        int cl = g * 4 + cc;
        int c = cg * 16 + cl;
        const float* xTb = xT + (size_t)(b * DI + c) * LL;
        const float* xRb = xR + (size_t)(b * DI + c) * LL;
        const float* pb  = prox + (size_t)(b * DI + c) * LL;
        const float* wT = wl + cl * 9;
        const float* wP = wl + 144 + cl * 9;
        #pragma unroll
        for (int ky = 0; ky < 3; ++ky) {
            int yy = row + ky - 1;
            if (yy < 0 || yy > 63) continue;
            #pragma unroll
            for (int kx = 0; kx < 3; ++kx) {
                int xx = px + kx - 1;
                bool in = (xx >= 0 && xx < 64);
                int o = yy * 64 + (in ? xx : 0);
                float mT = in ? xTb[o] : 0.f;
                float mR = in ? xRb[o] : 0.f;
                float mP = in ? pb[o] : 0.f;
                float wTv = wT[ky * 3 + kx], wPv = wP[ky * 3 + kx];
                aT += mT * wTv;
                aR += mR * wTv;
                aP += mP * wPv;
            }
        }
    }
    red[0][g][px] = aT + aP;
    red[1][g][px] = aR + aP;
    __syncthreads();
    if (tid < 128) {
        int X = tid >> 6, x = tid & 63;
        float s = red[X][0][x] + red[X][1][x] + red[X][2][x] + red[X][3][x];
        pbuf[(size_t)(cg * 4 + X * 2 + b) * LL + row * 64 + x] = s;
    }
}

// ---------------- reduce 12 partials -> pm[X*2+b][L] ----------------
__global__ void fusepm_reduce_kernel(const float* __restrict__ pbuf,
                                     const float* __restrict__ fb,
                                     float* __restrict__ pm) {
    int idx = blockIdx.x * 256 + threadIdx.x;   // idx over 4*LL
    int Xb = idx >> 12;                          // X*2+b
    int l = idx & 4095;
    float s = fb[0];
    #pragma unroll
    for (int cg = 0; cg < 12; ++cg)
        s += pbuf[(size_t)(cg * 4 + Xb) * LL + l];
    pm[(size_t)Xb * LL + l] = s;
}

// ---------------- bitonic argsort (stable via index tie-break) ----------------
__global__ void sort_kernel(const float* __restrict__ pm, int* __restrict__ ord,
                            int* __restrict__ inv) {
    __shared__ float key[LL];
    __shared__ int idx[LL];
    int X = blockIdx.x >> 1, b = blockIdx.x & 1;
    const float* z = pm + (X * 2 + b) * LL;
    for (int i = threadIdx.x; i < LL; i += 1024) {
        float v = z[i];
        key[i] = (X == 0) ? -v : v;
        idx[i] = i;
    }
    __syncthreads();
    for (int k = 2; k <= LL; k <<= 1) {
        for (int j = k >> 1; j >= 1; j >>= 1) {
            for (int t = threadIdx.x; t < LL / 2; t += 1024) {
                int i = ((t & ~(j - 1)) << 1) | (t & (j - 1));
                int p = i | j;
                bool asc = ((i & k) == 0);
                float ka = key[i], kb = key[p];
                int ia = idx[i], ib = idx[p];
                bool agt = (ka > kb) || (ka == kb && ia > ib);
                if (agt == asc) { key[i] = kb; key[p] = ka; idx[i] = ib; idx[p] = ia; }
            }
            __syncthreads();
        }
    }
    int* o = ord + (X * 2 + b) * LL;
    int* iv = inv + (X * 2 + b) * LL;
    for (int s = threadIdx.x; s < LL; s += 1024) {
        int j = idx[s];
        o[s] = j;
        iv[j] = s;
    }
}

// ---------------- transpose NCHW (b,c,l) -> (b,l,c), optionally add pe --------
__global__ void transpose_pe_kernel(const float* __restrict__ in, float* __restrict__ out,
                                    const float* __restrict__ pe, int use_pe) {
    __shared__ float tile[32][33];
    int b = blockIdx.z;
    int l0 = blockIdx.x * 32, c0 = blockIdx.y * 32;
    int tx = threadIdx.x, ty = threadIdx.y;
    #pragma unroll
    for (int r = 0; r < 4; ++r) {
        int c = c0 + ty + r * 8;
        tile[ty + r * 8][tx] = in[(size_t)(b * DI + c) * LL + l0 + tx];
    }
    __syncthreads();
    #pragma unroll
    for (int r = 0; r < 4; ++r) {
        int l = l0 + ty + r * 8;
        int c = c0 + tx;
        float v = tile[tx][ty + r * 8];
        if (use_pe) v += pe[(l & 63) * DI + c];
        out[(size_t)(b * LL + l) * DI + c] = v;
    }
}

// ---------------- depth path: df = leaky(Wde@pv+b); dproj = dpw@df; dsig ------
__global__ void depth_kernel(const float* __restrict__ proxt, const float* __restrict__ wde,
                             const float* __restrict__ bde, const float* __restrict__ dpw,
                             const float* __restrict__ sgw, const float* __restrict__ sgb,
                             float* __restrict__ dproj, float* __restrict__ dsig) {
    __shared__ float pvs[16][DI];
    __shared__ float dfs[16][DI];
    int bl0 = blockIdx.x * 16;
    int tid = threadIdx.x;
    for (int t = tid; t < 16 * DI; t += 256)
        pvs[t / DI][t % DI] = proxt[(size_t)bl0 * DI + t];
    __syncthreads();
    if (tid < DI) {
        float acc[16];
        #pragma unroll
        for (int l = 0; l < 16; ++l) acc[l] = 0.f;
        for (int i = 0; i < DI; ++i) {
            float w = wde[tid * DI + i];
            #pragma unroll
            for (int l = 0; l < 16; ++l) acc[l] += w * pvs[l][i];
        }
        float bias = bde[tid];
        #pragma unroll
        for (int l = 0; l < 16; ++l) {
            float v = acc[l] + bias;
            dfs[l][tid] = (v > 0.f) ? v : 0.2f * v;
        }
    }
    __syncthreads();
    if (tid < 80) {
        float acc[16];
        #pragma unroll
        for (int l = 0; l < 16; ++l) acc[l] = 0.f;
        const float* wrow = (tid < 64) ? (dpw + tid * DI) : (sgw + (tid - 64) * DI);
        for (int i = 0; i < DI; ++i) {
            float w = wrow[i];
            #pragma unroll
            for (int l = 0; l < 16; ++l) acc[l] += w * dfs[l][i];
        }
        if (tid < 64) {
            #pragma unroll
            for (int l = 0; l < 16; ++l) dproj[(size_t)(bl0 + l) * 64 + tid] = acc[l];
        } else {
            float bias = sgb[tid - 64];
            #pragma unroll
            for (int l = 0; l < 16; ++l) {
                float v = acc[l] + bias;
                v = (v > 0.f) ? v : 0.2f * v;
                dsig[(size_t)(bl0 + l) * NST + (tid - 64)] = 1.f / (1.f + __expf(-v));
            }
        }
    }
}

// ---------------- per-(b,k,s): x_dbl proj, delta, Bs/Cs -> s-minor buffers ----
// dtb2/dub2: [bk][c][s] ; bscs2: [bk][n][s] (B rows 0..15, C rows 16..31)
__global__ void project_kernel(const float* __restrict__ xpe, const int* __restrict__ ord,
                               const float* __restrict__ xpw, const float* __restrict__ dtw,
                               const float* __restrict__ dtb, const float* __restrict__ dproj,
                               const float* __restrict__ dsig, float* __restrict__ dtb2,
                               float* __restrict__ dub2, float* __restrict__ bscs2) {
    __shared__ float u[16][193];
    __shared__ float dbl[16][40];
    __shared__ int jarr[16];
    int chunk = blockIdx.x & 255;
    int k = (blockIdx.x >> 8) & 1;
    int b = blockIdx.x >> 9;
    int bk = b * 2 + k;
    int s0 = chunk * 16;
    int tid = threadIdx.x;
    if (tid < 16) {
        int s = s0 + tid;
        jarr[tid] = ord[b * LL + ((k == 0) ? s : (LL - 1 - s))];
    }
    __syncthreads();
    for (int t = tid; t < 16 * DI; t += 256) {
        int l = t / DI, i = t - l * DI;
        u[l][i] = xpe[(size_t)(b * LL + jarr[l]) * DI + i];
    }
    __syncthreads();
    {
        int og = tid >> 4, sl = tid & 15;
        float a0 = 0.f, a1 = 0.f, a2 = 0.f;
        const float* w0 = xpw + (size_t)(k * 38 + og) * DI;
        const float* w1 = w0 + 16 * DI;
        const float* w2 = w0 + 32 * DI;
        bool has2 = (og < 6);
        for (int i = 0; i < DI; ++i) {
            float uu = u[sl][i];
            a0 += w0[i] * uu;
            a1 += w1[i] * uu;
            if (has2) a2 += w2[i] * uu;
        }
        dbl[sl][og] = a0;
        dbl[sl][og + 16] = a1;
        if (has2) dbl[sl][og + 32] = a2;
    }
    __syncthreads();
    if (tid < DI) {
        int c = tid;
        float w[6];
        #pragma unroll
        for (int r = 0; r < 6; ++r) w[r] = dtw[(k * DI + c) * DTR + r];
        float bias = dtb[k * DI + c];
        float dtl[16], dul[16];
        #pragma unroll
        for (int sl = 0; sl < 16; ++sl) {
            float d = bias;
            #pragma unroll
            for (int r = 0; r < 6; ++r) d += w[r] * dbl[sl][r];
            float sp = fmaxf(d, 0.f) + log1pf(__expf(-fabsf(d)));
            dtl[sl] = sp;
            dul[sl] = sp * u[sl][c];
        }
        size_t base = (size_t)(bk * DI + c) * LL + s0;
        #pragma unroll
        for (int g = 0; g < 4; ++g) {
            *(float4*)(dtb2 + base + g * 4) =
                make_float4(dtl[g*4], dtl[g*4+1], dtl[g*4+2], dtl[g*4+3]);
            *(float4*)(dub2 + base + g * 4) =
                make_float4(dul[g*4], dul[g*4+1], dul[g*4+2], dul[g*4+3]);
        }
    }
    {
        int n = tid >> 4, sl = tid & 15;   // consecutive tid -> consecutive sl
        int j = jarr[sl];
        float w = dsig[(size_t)(b * LL + j) * NST + n];
        float Bo = dbl[sl][6 + n], Co = dbl[sl][22 + n];
        float Bd = dproj[(size_t)(b * LL + j) * 64 + k * 32 + n];
        float Cd = dproj[(size_t)(b * LL + j) * 64 + k * 32 + 16 + n];
        size_t sb = (size_t)(bk * 32 + n) * LL + s0 + sl;
        bscs2[sb] = (1.f - w) * Bo + w * Bd;
        bscs2[sb + (size_t)16 * LL] = (1.f - w) * Co + w * Cd;
    }
}

// ---------------- fused time-parallel selective scan ----------------
// One block per (bk, c): 512 threads = 8 waves; wave w owns states n=w and n=w+8.
// Lane t owns 4 consecutive timesteps of each 256-step chunk; chunk-local
// (a,b) monoid compose in-register, 6-level shfl_up wave scan over lane totals,
// carry kept in-register across the 16 chunks. y = sum_n h*C via LDS reduce.
__global__ __launch_bounds__(512, 4) void scan_fused_kernel(
        const float* __restrict__ dtb2, const float* __restrict__ dub2,
        const float* __restrict__ bscs2, const float* __restrict__ Alog,
        float* __restrict__ y) {
    __shared__ float ypart[8][CT + 4];
    int c = blockIdx.x % DI;
    int bk = blockIdx.x / DI;
    int k = bk & 1;
    int w = threadIdx.x >> 6;
    int t = threadIdx.x & 63;
    float A0 = -__expf(Alog[(k * DI + c) * NST + w]);
    float A1 = -__expf(Alog[(k * DI + c) * NST + w + 8]);
    size_t rowc = (size_t)(bk * DI + c) * LL;
    const float* dtp = dtb2 + rowc;
    const float* dup = dub2 + rowc;
    const float* b0p = bscs2 + (size_t)(bk * 32 + w) * LL;
    const float* c0p = b0p + (size_t)16 * LL;
    const float* b1p = b0p + (size_t)8 * LL;
    const float* c1p = c0p + (size_t)8 * LL;
    float* yrow = y + (size_t)bk * LL * DI + c;
    float Hc0 = 0.f, Hc1 = 0.f;
    int off = t * 4;
    float4 d4 = *(const float4*)(dtp + off);
    float4 u4 = *(const float4*)(dup + off);
    float4 B0 = *(const float4*)(b0p + off);
    float4 C0 = *(const float4*)(c0p + off);
    float4 B1 = *(const float4*)(b1p + off);
    float4 C1 = *(const float4*)(c1p + off);
    for (int ck = 0; ck < NCK; ++ck) {
        int base = ck * CT;
        float4 nd4, nu4, nB0, nC0, nB1, nC1;
        if (ck + 1 < NCK) {
            int noff = base + CT + off;
            nd4 = *(const float4*)(dtp + noff);
            nu4 = *(const float4*)(dup + noff);
            nB0 = *(const float4*)(b0p + noff);
            nC0 = *(const float4*)(c0p + noff);
            nB1 = *(const float4*)(b1p + noff);
            nC1 = *(const float4*)(c1p + noff);
        }
        // local 4-step compose, state n0 and n1
        float la0[4], lb0[4], la1[4], lb1[4];
        float ca0 = 1.f, cb0 = 0.f, ca1 = 1.f, cb1 = 0.f, e;
        e = __expf(d4.x * A0); ca0 *= e; cb0 = cb0 * e + u4.x * B0.x; la0[0] = ca0; lb0[0] = cb0;
        e = __expf(d4.y * A0); ca0 *= e; cb0 = cb0 * e + u4.y * B0.y; la0[1] = ca0; lb0[1] = cb0;
        e = __expf(d4.z * A0); ca0 *= e; cb0 = cb0 * e + u4.z * B0.z; la0[2] = ca0; lb0[2] = cb0;
        e = __expf(d4.w * A0); ca0 *= e; cb0 = cb0 * e + u4.w * B0.w; la0[3] = ca0; lb0[3] = cb0;
        e = __expf(d4.x * A1); ca1 *= e; cb1 = cb1 * e + u4.x * B1.x; la1[0] = ca1; lb1[0] = cb1;
        e = __expf(d4.y * A1); ca1 *= e; cb1 = cb1 * e + u4.y * B1.y; la1[1] = ca1; lb1[1] = cb1;
        e = __expf(d4.z * A1); ca1 *= e; cb1 = cb1 * e + u4.z * B1.z; la1[2] = ca1; lb1[2] = cb1;
        e = __expf(d4.w * A1); ca1 *= e; cb1 = cb1 * e + u4.w * B1.w; la1[3] = ca1; lb1[3] = cb1;
        // wave inclusive scan over lane totals, monoid (a,b): later(x) = a*x+b
        #pragma unroll
        for (int m = 1; m < 64; m <<= 1) {
            float sa0 = __shfl_up(ca0, m), sb0 = __shfl_up(cb0, m);
            float sa1 = __shfl_up(ca1, m), sb1 = __shfl_up(cb1, m);
            if (t >= m) {
                cb0 = sb0 * ca0 + cb0; ca0 *= sa0;
                cb1 = sb1 * ca1 + cb1; ca1 *= sa1;
            }
        }
        // exclusive prefix for this lane
        float ea0 = __shfl_up(ca0, 1), eb0 = __shfl_up(cb0, 1);
        float ea1 = __shfl_up(ca1, 1), eb1 = __shfl_up(cb1, 1);
        if (t == 0) { ea0 = 1.f; eb0 = 0.f; ea1 = 1.f; eb1 = 0.f; }
        float h0in = ea0 * Hc0 + eb0;
        float h1in = ea1 * Hc1 + eb1;
        float h03 = la0[3] * h0in + lb0[3];
        float h13 = la1[3] * h1in + lb1[3];
        float yv0 = (la0[0] * h0in + lb0[0]) * C0.x + (la1[0] * h1in + lb1[0]) * C1.x;
        float yv1 = (la0[1] * h0in + lb0[1]) * C0.y + (la1[1] * h1in + lb1[1]) * C1.y;
        float yv2 = (la0[2] * h0in + lb0[2]) * C0.z + (la1[2] * h1in + lb1[2]) * C1.z;
        float yv3 = h03 * C0.w + h13 * C1.w;
        Hc0 = __shfl(h03, 63);
        Hc1 = __shfl(h13, 63);
        *(float4*)&ypart[w][off] = make_float4(yv0, yv1, yv2, yv3);
        __syncthreads();
        if (threadIdx.x < CT) {
            int t2 = threadIdx.x;
            float s = 0.f;
            #pragma unroll
            for (int r = 0; r < 8; ++r) s += ypart[r][t2];
            yrow[(size_t)(base + t2) * DI] = s;
        }
        __syncthreads();
        d4 = nd4; u4 = nu4; B0 = nB0; C0 = nC0; B1 = nB1; C1 = nC1;
    }
}

// ---------------- gather (inverse perm) + D*u + layernorm + output ------------
__global__ void ln_kernel(const float* __restrict__ y, const float* __restrict__ xpe,
                          const int* __restrict__ inv, const float* __restrict__ Dvec,
                          const float* __restrict__ g, const float* __restrict__ beta,
                          float* __restrict__ out, int X) {
    int w = threadIdx.x >> 6, lane = threadIdx.x & 63;
    int bl = blockIdx.x * 4 + w;
    int b = bl >> 12, l = bl & 4095;
    int s0 = inv[b * LL + l];
    int s1 = LL - 1 - s0;
    const float* y0 = y + ((size_t)(b * 2 + 0) * LL + s0) * DI;
    const float* y1 = y + ((size_t)(b * 2 + 1) * LL + s1) * DI;
    const float* xr = xpe + (size_t)(b * LL + l) * DI;
    float v[3];
    float sum = 0.f, sq = 0.f;
    #pragma unroll
    for (int r = 0; r < 3; ++r) {
        int c = lane + r * 64;
        float t = y0[c] + y1[c] + (Dvec[c] + Dvec[DI + c]) * xr[c];
        v[r] = t; sum += t; sq += t * t;
    }
    #pragma unroll
    for (int m = 1; m < 64; m <<= 1) {
        sum += __shfl_xor(sum, m);
        sq += __shfl_xor(sq, m);
    }
    float mu = sum * (1.f / 192.f);
    float var = sq * (1.f / 192.f) - mu * mu;
    float rs = rsqrtf(var + 1e-5f);
    float* op = out + ((size_t)(X * 2 + b) * LL + l) * DI;
    #pragma unroll
    for (int r = 0; r < 3; ++r) {
        int c = lane + r * 64;
        op[c] = (v[r] - mu) * rs * g[c] + beta[c];
    }
}

extern "C" void kernel_launch(void* const* d_in, const int* in_sizes, int n_in,
                              void* d_out, int out_size, void* d_ws, size_t ws_size,
                              hipStream_t stream) {
    const float* x_T = (const float*)d_in[0];
    const float* x_R = (const float*)d_in[1];
    const float* prox = (const float*)d_in[2];
    const float* fuse_w = (const float*)d_in[3];
    const float* fuse_b = (const float*)d_in[4];
    const float* x_proj_w = (const float*)d_in[5];
    const float* dt_w = (const float*)d_in[6];
    const float* dt_b = (const float*)d_in[7];
    const float* A_log_T = (const float*)d_in[8];
    const float* A_log_R = (const float*)d_in[9];
    const float* D_T = (const float*)d_in[10];
    const float* D_R = (const float*)d_in[11];
    const float* depth_enc_w = (const float*)d_in[12];
    const float* depth_enc_b = (const float*)d_in[13];
    const float* depth_proj_w = (const float*)d_in[14];
    const float* sig_w = (const float*)d_in[15];
    const float* sig_b = (const float*)d_in[16];
    const float* ln_g = (const float*)d_in[17];
    const float* ln_b = (const float*)d_in[18];
    float* out = (float*)d_out;
    char* ws = (char*)d_ws;

    float* pe    = (float*)(ws + 0);         //   49152
    float* pm    = (float*)(ws + 49152);     //   65536
    int*   ord   = (int*)(ws + 114688);      //   65536
    int*   inv   = (int*)(ws + 180224);      //   65536
    float* proxt = (float*)(ws + 245760);    // 6291456 (dead after depth_kernel)
    float* dproj = (float*)(ws + 6537216);   // 2097152
    float* dsig  = (float*)(ws + 8634368);   //  524288
    float* xpe   = (float*)(ws + 9158656);   // 6291456 (reused per branch)
    float* dtb2  = (float*)(ws + 15450112);  // 12582912
    float* dub2  = (float*)(ws + 28033024);  // 12582912
    float* bscs2 = (float*)(ws + 40615936);  // 2097152
    float* ybuf  = (float*)(ws + 42713088);  // 12582912  -> total 55296000
    float* pbuf  = dtb2;                     // fuse partials (dead until project)

    pe_kernel<<<48, 256, 0, stream>>>(pe);
    fusepm_part_kernel<<<dim3(12, 64, 2), 256, 0, stream>>>(x_T, x_R, prox, fuse_w, pbuf);
    fusepm_reduce_kernel<<<64, 256, 0, stream>>>(pbuf, fuse_b, pm);
    sort_kernel<<<4, 1024, 0, stream>>>(pm, ord, inv);
    transpose_pe_kernel<<<dim3(128, 6, 2), dim3(32, 8), 0, stream>>>(prox, proxt, pe, 0);
    depth_kernel<<<512, 256, 0, stream>>>(proxt, depth_enc_w, depth_enc_b, depth_proj_w,
                                          sig_w, sig_b, dproj, dsig);
    for (int X = 0; X < 2; ++X) {
        const float* xin = X ? x_R : x_T;
        const float* Alog = X ? A_log_R : A_log_T;
        const float* Dv = X ? D_R : D_T;
        const int* ordX = ord + X * 2 * LL;
        const int* invX = inv + X * 2 * LL;
        transpose_pe_kernel<<<dim3(128, 6, 2), dim3(32, 8), 0, stream>>>(xin, xpe, pe, 1);
        project_kernel<<<1024, 256, 0, stream>>>(xpe, ordX, x_proj_w, dt_w, dt_b,
                                                 dproj, dsig, dtb2, dub2, bscs2);
        scan_fused_kernel<<<4 * DI, 512, 0, stream>>>(dtb2, dub2, bscs2, Alog, ybuf);
        ln_kernel<<<2048, 256, 0, stream>>>(ybuf, xpe, invX, Dv, ln_g, ln_b, out, X);
    }
}

// Round 5
// 327.299 us; speedup vs baseline: 1.7411x; 1.0104x over previous
//
#include <hip/hip_runtime.h>
#include <hip/hip_bf16.h>
#include <math.h>

// Problem constants
#define BATCH 2
#define DI 192          // D_INNER
#define NST 16          // D_STATE
#define DTR 6           // DT_RANK
#define KK 2
#define LL 4096
#define CT 256          // timesteps per scan chunk (4 per lane)
#define NCK (LL/CT)     // 16 chunk iterations

// ---------------- pe table: pe[col][c], col=l%64 ----------------
__global__ void pe_kernel(float* __restrict__ pe) {
    int i = blockIdx.x * 256 + threadIdx.x;
    if (i >= 64 * DI) return;
    int col = i / DI, c = i % DI;
    float gx = (float)col / 63.f;
    int m = (c < 96) ? c : (c - 96);
    float invf = expf(-(float)m * (logf(10000.f) / 96.f));
    float ang = gx * invf;
    pe[i] = (c < 96) ? sinf(ang) : cosf(ang);
}

// ---------------- fuse conv partials: grid (12 cgroups, 64 rows, 2 b) --------
// pbuf layout: [(cg*4 + X*2 + b)][L]  (X=0:T, X=1:R), raw pre-activation partial
__global__ void fusepm_part_kernel(const float* __restrict__ xT, const float* __restrict__ xR,
                                   const float* __restrict__ prox, const float* __restrict__ fw,
                                   float* __restrict__ pbuf) {
    __shared__ float wl[288];          // 16ch x 9 (x-half) + 16ch x 9 (prox-half)
    __shared__ float red[2][4][64];
    int cg = blockIdx.x;
    int row = blockIdx.y;
    int b = blockIdx.z;
    int tid = threadIdx.x;
    if (tid < 288) {
        int cl = (tid % 144) / 9, tap = tid % 9;
        int half = tid / 144;                    // 0: x-half, 1: prox-half
        wl[tid] = fw[(half * DI + cg * 16 + cl) * 9 + tap];
    }
    __syncthreads();
    int px = tid & 63, g = tid >> 6;
    float aT = 0.f, aR = 0.f, aP = 0.f;
    #pragma unroll
    for (int cc = 0; cc < 4; ++cc) {
        int cl = g * 4 + cc;
        int c = cg * 16 + cl;
        const float* xTb = xT + (size_t)(b * DI + c) * LL;
        const float* xRb = xR + (size_t)(b * DI + c) * LL;
        const float* pb  = prox + (size_t)(b * DI + c) * LL;
        const float* wT = wl + cl * 9;
        const float* wP = wl + 144 + cl * 9;
        #pragma unroll
        for (int ky = 0; ky < 3; ++ky) {
            int yy = row + ky - 1;
            if (yy < 0 || yy > 63) continue;
            #pragma unroll
            for (int kx = 0; kx < 3; ++kx) {
                int xx = px + kx - 1;
                bool in = (xx >= 0 && xx < 64);
                int o = yy * 64 + (in ? xx : 0);
                float mT = in ? xTb[o] : 0.f;
                float mR = in ? xRb[o] : 0.f;
                float mP = in ? pb[o] : 0.f;
                float wTv = wT[ky * 3 + kx], wPv = wP[ky * 3 + kx];
                aT += mT * wTv;
                aR += mR * wTv;
                aP += mP * wPv;
            }
        }
    }
    red[0][g][px] = aT + aP;
    red[1][g][px] = aR + aP;
    __syncthreads();
    if (tid < 128) {
        int X = tid >> 6, x = tid & 63;
        float s = red[X][0][x] + red[X][1][x] + red[X][2][x] + red[X][3][x];
        pbuf[(size_t)(cg * 4 + X * 2 + b) * LL + row * 64 + x] = s;
    }
}

// ---------------- reduce 12 partials -> pm[X*2+b][L] ----------------
__global__ void fusepm_reduce_kernel(const float* __restrict__ pbuf,
                                     const float* __restrict__ fb,
                                     float* __restrict__ pm) {
    int idx = blockIdx.x * 256 + threadIdx.x;   // idx over 4*LL
    int Xb = idx >> 12;                          // X*2+b
    int l = idx & 4095;
    float s = fb[0];
    #pragma unroll
    for (int cg = 0; cg < 12; ++cg)
        s += pbuf[(size_t)(cg * 4 + Xb) * LL + l];
    pm[(size_t)Xb * LL + l] = s;
}

// ---------------- bitonic argsort (stable via index tie-break) ----------------
__global__ void sort_kernel(const float* __restrict__ pm, int* __restrict__ ord,
                            int* __restrict__ inv) {
    __shared__ float key[LL];
    __shared__ int idx[LL];
    int X = blockIdx.x >> 1, b = blockIdx.x & 1;
    const float* z = pm + (X * 2 + b) * LL;
    for (int i = threadIdx.x; i < LL; i += 1024) {
        float v = z[i];
        key[i] = (X == 0) ? -v : v;
        idx[i] = i;
    }
    __syncthreads();
    for (int k = 2; k <= LL; k <<= 1) {
        for (int j = k >> 1; j >= 1; j >>= 1) {
            for (int t = threadIdx.x; t < LL / 2; t += 1024) {
                int i = ((t & ~(j - 1)) << 1) | (t & (j - 1));
                int p = i | j;
                bool asc = ((i & k) == 0);
                float ka = key[i], kb = key[p];
                int ia = idx[i], ib = idx[p];
                bool agt = (ka > kb) || (ka == kb && ia > ib);
                if (agt == asc) { key[i] = kb; key[p] = ka; idx[i] = ib; idx[p] = ia; }
            }
            __syncthreads();
        }
    }
    int* o = ord + (X * 2 + b) * LL;
    int* iv = inv + (X * 2 + b) * LL;
    for (int s = threadIdx.x; s < LL; s += 1024) {
        int j = idx[s];
        o[s] = j;
        iv[j] = s;
    }
}

// ---------------- transpose NCHW (b,c,l) -> (b,l,c), optionally add pe --------
__global__ void transpose_pe_kernel(const float* __restrict__ in, float* __restrict__ out,
                                    const float* __restrict__ pe, int use_pe) {
    __shared__ float tile[32][33];
    int b = blockIdx.z;
    int l0 = blockIdx.x * 32, c0 = blockIdx.y * 32;
    int tx = threadIdx.x, ty = threadIdx.y;
    #pragma unroll
    for (int r = 0; r < 4; ++r) {
        int c = c0 + ty + r * 8;
        tile[ty + r * 8][tx] = in[(size_t)(b * DI + c) * LL + l0 + tx];
    }
    __syncthreads();
    #pragma unroll
    for (int r = 0; r < 4; ++r) {
        int l = l0 + ty + r * 8;
        int c = c0 + tx;
        float v = tile[tx][ty + r * 8];
        if (use_pe) v += pe[(l & 63) * DI + c];
        out[(size_t)(b * LL + l) * DI + c] = v;
    }
}

// ---------------- depth path: df = leaky(Wde@pv+b); dproj = dpw@df; dsig ------
__global__ void depth_kernel(const float* __restrict__ proxt, const float* __restrict__ wde,
                             const float* __restrict__ bde, const float* __restrict__ dpw,
                             const float* __restrict__ sgw, const float* __restrict__ sgb,
                             float* __restrict__ dproj, float* __restrict__ dsig) {
    __shared__ float pvs[16][DI];
    __shared__ float dfs[16][DI];
    int bl0 = blockIdx.x * 16;
    int tid = threadIdx.x;
    for (int t = tid; t < 16 * DI; t += 256)
        pvs[t / DI][t % DI] = proxt[(size_t)bl0 * DI + t];
    __syncthreads();
    if (tid < DI) {
        float acc[16];
        #pragma unroll
        for (int l = 0; l < 16; ++l) acc[l] = 0.f;
        for (int i = 0; i < DI; ++i) {
            float w = wde[tid * DI + i];
            #pragma unroll
            for (int l = 0; l < 16; ++l) acc[l] += w * pvs[l][i];
        }
        float bias = bde[tid];
        #pragma unroll
        for (int l = 0; l < 16; ++l) {
            float v = acc[l] + bias;
            dfs[l][tid] = (v > 0.f) ? v : 0.2f * v;
        }
    }
    __syncthreads();
    if (tid < 80) {
        float acc[16];
        #pragma unroll
        for (int l = 0; l < 16; ++l) acc[l] = 0.f;
        const float* wrow = (tid < 64) ? (dpw + tid * DI) : (sgw + (tid - 64) * DI);
        for (int i = 0; i < DI; ++i) {
            float w = wrow[i];
            #pragma unroll
            for (int l = 0; l < 16; ++l) acc[l] += w * dfs[l][i];
        }
        if (tid < 64) {
            #pragma unroll
            for (int l = 0; l < 16; ++l) dproj[(size_t)(bl0 + l) * 64 + tid] = acc[l];
        } else {
            float bias = sgb[tid - 64];
            #pragma unroll
            for (int l = 0; l < 16; ++l) {
                float v = acc[l] + bias;
                v = (v > 0.f) ? v : 0.2f * v;
                dsig[(size_t)(bl0 + l) * NST + (tid - 64)] = 1.f / (1.f + __expf(-v));
            }
        }
    }
}

// ---------------- per-(b,k,s): x_dbl proj, delta, Bs/Cs -> s-minor buffers ----
// dtb2/dub2: [bk][c][s] ; bscs2: [bk][n][s] (B rows 0..15, C rows 16..31)
__global__ void project_kernel(const float* __restrict__ xpe, const int* __restrict__ ord,
                               const float* __restrict__ xpw, const float* __restrict__ dtw,
                               const float* __restrict__ dtb, const float* __restrict__ dproj,
                               const float* __restrict__ dsig, float* __restrict__ dtb2,
                               float* __restrict__ dub2, float* __restrict__ bscs2) {
    __shared__ float u[16][193];
    __shared__ float dbl[16][40];
    __shared__ int jarr[16];
    int chunk = blockIdx.x & 255;
    int k = (blockIdx.x >> 8) & 1;
    int b = blockIdx.x >> 9;
    int bk = b * 2 + k;
    int s0 = chunk * 16;
    int tid = threadIdx.x;
    if (tid < 16) {
        int s = s0 + tid;
        jarr[tid] = ord[b * LL + ((k == 0) ? s : (LL - 1 - s))];
    }
    __syncthreads();
    for (int t = tid; t < 16 * DI; t += 256) {
        int l = t / DI, i = t - l * DI;
        u[l][i] = xpe[(size_t)(b * LL + jarr[l]) * DI + i];
    }
    __syncthreads();
    {
        int og = tid >> 4, sl = tid & 15;
        float a0 = 0.f, a1 = 0.f, a2 = 0.f;
        const float* w0 = xpw + (size_t)(k * 38 + og) * DI;
        const float* w1 = w0 + 16 * DI;
        const float* w2 = w0 + 32 * DI;
        bool has2 = (og < 6);
        for (int i = 0; i < DI; ++i) {
            float uu = u[sl][i];
            a0 += w0[i] * uu;
            a1 += w1[i] * uu;
            if (has2) a2 += w2[i] * uu;
        }
        dbl[sl][og] = a0;
        dbl[sl][og + 16] = a1;
        if (has2) dbl[sl][og + 32] = a2;
    }
    __syncthreads();
    if (tid < DI) {
        int c = tid;
        float w[6];
        #pragma unroll
        for (int r = 0; r < 6; ++r) w[r] = dtw[(k * DI + c) * DTR + r];
        float bias = dtb[k * DI + c];
        float dtl[16], dul[16];
        #pragma unroll
        for (int sl = 0; sl < 16; ++sl) {
            float d = bias;
            #pragma unroll
            for (int r = 0; r < 6; ++r) d += w[r] * dbl[sl][r];
            float sp = fmaxf(d, 0.f) + log1pf(__expf(-fabsf(d)));
            dtl[sl] = sp;
            dul[sl] = sp * u[sl][c];
        }
        size_t base = (size_t)(bk * DI + c) * LL + s0;
        #pragma unroll
        for (int g = 0; g < 4; ++g) {
            *(float4*)(dtb2 + base + g * 4) =
                make_float4(dtl[g*4], dtl[g*4+1], dtl[g*4+2], dtl[g*4+3]);
            *(float4*)(dub2 + base + g * 4) =
                make_float4(dul[g*4], dul[g*4+1], dul[g*4+2], dul[g*4+3]);
        }
    }
    {
        int n = tid >> 4, sl = tid & 15;   // consecutive tid -> consecutive sl
        int j = jarr[sl];
        float w = dsig[(size_t)(b * LL + j) * NST + n];
        float Bo = dbl[sl][6 + n], Co = dbl[sl][22 + n];
        float Bd = dproj[(size_t)(b * LL + j) * 64 + k * 32 + n];
        float Cd = dproj[(size_t)(b * LL + j) * 64 + k * 32 + 16 + n];
        size_t sb = (size_t)(bk * 32 + n) * LL + s0 + sl;
        bscs2[sb] = (1.f - w) * Bo + w * Bd;
        bscs2[sb + (size_t)16 * LL] = (1.f - w) * Co + w * Cd;
    }
}

// ---------------- fused time-parallel selective scan ----------------
// One block per (bk, c): 512 threads = 8 waves; wave w owns states n=w and n=w+8.
// Lane t owns 4 consecutive timesteps of each 256-step chunk; chunk-local
// (a,b) monoid compose in-register, 6-level shfl_up wave scan over lane totals,
// carry kept in-register across the 16 chunks. y = sum_n h*C via LDS reduce.
// Output layout: y[bk][c][s]  (contiguous stores; ln_kernel transposes via LDS)
__global__ __launch_bounds__(512, 4) void scan_fused_kernel(
        const float* __restrict__ dtb2, const float* __restrict__ dub2,
        const float* __restrict__ bscs2, const float* __restrict__ Alog,
        float* __restrict__ y) {
    __shared__ float ypart[2][8][CT + 4];
    int c = blockIdx.x % DI;
    int bk = blockIdx.x / DI;
    int k = bk & 1;
    int w = threadIdx.x >> 6;
    int t = threadIdx.x & 63;
    float A0 = -__expf(Alog[(k * DI + c) * NST + w]);
    float A1 = -__expf(Alog[(k * DI + c) * NST + w + 8]);
    size_t rowc = (size_t)(bk * DI + c) * LL;
    const float* dtp = dtb2 + rowc;
    const float* dup = dub2 + rowc;
    const float* b0p = bscs2 + (size_t)(bk * 32 + w) * LL;
    const float* c0p = b0p + (size_t)16 * LL;
    const float* b1p = b0p + (size_t)8 * LL;
    const float* c1p = c0p + (size_t)8 * LL;
    float* yrow = y + rowc;
    float Hc0 = 0.f, Hc1 = 0.f;
    int off = t * 4;
    float4 d4 = *(const float4*)(dtp + off);
    float4 u4 = *(const float4*)(dup + off);
    float4 B0 = *(const float4*)(b0p + off);
    float4 C0 = *(const float4*)(c0p + off);
    float4 B1 = *(const float4*)(b1p + off);
    float4 C1 = *(const float4*)(c1p + off);
    for (int ck = 0; ck < NCK; ++ck) {
        int base = ck * CT;
        float4 nd4, nu4, nB0, nC0, nB1, nC1;
        if (ck + 1 < NCK) {
            int noff = base + CT + off;
            nd4 = *(const float4*)(dtp + noff);
            nu4 = *(const float4*)(dup + noff);
            nB0 = *(const float4*)(b0p + noff);
            nC0 = *(const float4*)(c0p + noff);
            nB1 = *(const float4*)(b1p + noff);
            nC1 = *(const float4*)(c1p + noff);
        }
        // local 4-step compose, state n0 and n1
        float la0[4], lb0[4], la1[4], lb1[4];
        float ca0 = 1.f, cb0 = 0.f, ca1 = 1.f, cb1 = 0.f, e;
        e = __expf(d4.x * A0); ca0 *= e; cb0 = cb0 * e + u4.x * B0.x; la0[0] = ca0; lb0[0] = cb0;
        e = __expf(d4.y * A0); ca0 *= e; cb0 = cb0 * e + u4.y * B0.y; la0[1] = ca0; lb0[1] = cb0;
        e = __expf(d4.z * A0); ca0 *= e; cb0 = cb0 * e + u4.z * B0.z; la0[2] = ca0; lb0[2] = cb0;
        e = __expf(d4.w * A0); ca0 *= e; cb0 = cb0 * e + u4.w * B0.w; la0[3] = ca0; lb0[3] = cb0;
        e = __expf(d4.x * A1); ca1 *= e; cb1 = cb1 * e + u4.x * B1.x; la1[0] = ca1; lb1[0] = cb1;
        e = __expf(d4.y * A1); ca1 *= e; cb1 = cb1 * e + u4.y * B1.y; la1[1] = ca1; lb1[1] = cb1;
        e = __expf(d4.z * A1); ca1 *= e; cb1 = cb1 * e + u4.z * B1.z; la1[2] = ca1; lb1[2] = cb1;
        e = __expf(d4.w * A1); ca1 *= e; cb1 = cb1 * e + u4.w * B1.w; la1[3] = ca1; lb1[3] = cb1;
        // wave inclusive scan over lane totals, monoid (a,b): later(x) = a*x+b
        #pragma unroll
        for (int m = 1; m < 64; m <<= 1) {
            float sa0 = __shfl_up(ca0, m), sb0 = __shfl_up(cb0, m);
            float sa1 = __shfl_up(ca1, m), sb1 = __shfl_up(cb1, m);
            if (t >= m) {
                cb0 = sb0 * ca0 + cb0; ca0 *= sa0;
                cb1 = sb1 * ca1 + cb1; ca1 *= sa1;
            }
        }
        // exclusive prefix for this lane
        float ea0 = __shfl_up(ca0, 1), eb0 = __shfl_up(cb0, 1);
        float ea1 = __shfl_up(ca1, 1), eb1 = __shfl_up(cb1, 1);
        if (t == 0) { ea0 = 1.f; eb0 = 0.f; ea1 = 1.f; eb1 = 0.f; }
        float h0in = ea0 * Hc0 + eb0;
        float h1in = ea1 * Hc1 + eb1;
        float h03 = la0[3] * h0in + lb0[3];
        float h13 = la1[3] * h1in + lb1[3];
        float yv0 = (la0[0] * h0in + lb0[0]) * C0.x + (la1[0] * h1in + lb1[0]) * C1.x;
        float yv1 = (la0[1] * h0in + lb0[1]) * C0.y + (la1[1] * h1in + lb1[1]) * C1.y;
        float yv2 = (la0[2] * h0in + lb0[2]) * C0.z + (la1[2] * h1in + lb1[2]) * C1.z;
        float yv3 = h03 * C0.w + h13 * C1.w;
        Hc0 = __shfl(h03, 63);
        Hc1 = __shfl(h13, 63);
        *(float4*)&ypart[ck & 1][w][off] = make_float4(yv0, yv1, yv2, yv3);
        __syncthreads();
        if (threadIdx.x < CT) {
            int t2 = threadIdx.x;
            float s = 0.f;
            #pragma unroll
            for (int r = 0; r < 8; ++r) s += ypart[ck & 1][r][t2];
            yrow[base + t2] = s;          // contiguous: coalesced 1KB store/block
        }
        // no second barrier: next iter writes ypart[(ck+1)&1], disjoint buffer
        d4 = nd4; u4 = nu4; B0 = nB0; C0 = nC0; B1 = nB1; C1 = nC1;
    }
}

// ---------------- s-order gather + D*u + layernorm + output ------------------
// y layout [bk][c][s]; block stages a 16-column tile of y0/y1 through LDS
// (transpose), iterates s ascending: l = ord[s], out row l.
__global__ __launch_bounds__(256) void ln_kernel(const float* __restrict__ y,
                          const float* __restrict__ xpe,
                          const int* __restrict__ ord, const float* __restrict__ Dvec,
                          const float* __restrict__ g, const float* __restrict__ beta,
                          float* __restrict__ out, int X) {
    __shared__ float y0t[DI][17];
    __shared__ float y1t[DI][17];
    int b = blockIdx.x >> 8;
    int s0 = (blockIdx.x & 255) * 16;
    int tid = threadIdx.x;
    for (int idx = tid; idx < DI * 16; idx += 256) {
        int c = idx >> 4, j = idx & 15;
        y0t[c][j] = y[((size_t)(b * 2 + 0) * DI + c) * LL + s0 + j];
        y1t[c][j] = y[((size_t)(b * 2 + 1) * DI + c) * LL + (LL - 1 - s0 - j)];
    }
    __syncthreads();
    int w = tid >> 6, lane = tid & 63;
    #pragma unroll
    for (int it = 0; it < 4; ++it) {
        int j = it * 4 + w;
        int l = ord[b * LL + s0 + j];
        const float* xr = xpe + (size_t)(b * LL + l) * DI;
        float v[3];
        float sum = 0.f, sq = 0.f;
        #pragma unroll
        for (int r = 0; r < 3; ++r) {
            int c = lane + r * 64;
            float t = y0t[c][j] + y1t[c][j] + (Dvec[c] + Dvec[DI + c]) * xr[c];
            v[r] = t; sum += t; sq += t * t;
        }
        #pragma unroll
        for (int m = 1; m < 64; m <<= 1) {
            sum += __shfl_xor(sum, m);
            sq += __shfl_xor(sq, m);
        }
        float mu = sum * (1.f / 192.f);
        float var = sq * (1.f / 192.f) - mu * mu;
        float rs = rsqrtf(var + 1e-5f);
        float* op = out + ((size_t)(X * 2 + b) * LL + l) * DI;
        #pragma unroll
        for (int r = 0; r < 3; ++r) {
            int c = lane + r * 64;
            op[c] = (v[r] - mu) * rs * g[c] + beta[c];
        }
    }
}

extern "C" void kernel_launch(void* const* d_in, const int* in_sizes, int n_in,
                              void* d_out, int out_size, void* d_ws, size_t ws_size,
                              hipStream_t stream) {
    const float* x_T = (const float*)d_in[0];
    const float* x_R = (const float*)d_in[1];
    const float* prox = (const float*)d_in[2];
    const float* fuse_w = (const float*)d_in[3];
    const float* fuse_b = (const float*)d_in[4];
    const float* x_proj_w = (const float*)d_in[5];
    const float* dt_w = (const float*)d_in[6];
    const float* dt_b = (const float*)d_in[7];
    const float* A_log_T = (const float*)d_in[8];
    const float* A_log_R = (const float*)d_in[9];
    const float* D_T = (const float*)d_in[10];
    const float* D_R = (const float*)d_in[11];
    const float* depth_enc_w = (const float*)d_in[12];
    const float* depth_enc_b = (const float*)d_in[13];
    const float* depth_proj_w = (const float*)d_in[14];
    const float* sig_w = (const float*)d_in[15];
    const float* sig_b = (const float*)d_in[16];
    const float* ln_g = (const float*)d_in[17];
    const float* ln_b = (const float*)d_in[18];
    float* out = (float*)d_out;
    char* ws = (char*)d_ws;

    float* pe    = (float*)(ws + 0);         //   49152
    float* pm    = (float*)(ws + 49152);     //   65536
    int*   ord   = (int*)(ws + 114688);      //   65536
    int*   inv   = (int*)(ws + 180224);      //   65536
    float* proxt = (float*)(ws + 245760);    // 6291456 (dead after depth_kernel)
    float* dproj = (float*)(ws + 6537216);   // 2097152
    float* dsig  = (float*)(ws + 8634368);   //  524288
    float* xpe   = (float*)(ws + 9158656);   // 6291456 (reused per branch)
    float* dtb2  = (float*)(ws + 15450112);  // 12582912
    float* dub2  = (float*)(ws + 28033024);  // 12582912
    float* bscs2 = (float*)(ws + 40615936);  // 2097152
    float* ybuf  = (float*)(ws + 42713088);  // 12582912, layout [bk][c][s]
    float* pbuf  = dtb2;                     // fuse partials (dead until project)

    pe_kernel<<<48, 256, 0, stream>>>(pe);
    fusepm_part_kernel<<<dim3(12, 64, 2), 256, 0, stream>>>(x_T, x_R, prox, fuse_w, pbuf);
    fusepm_reduce_kernel<<<64, 256, 0, stream>>>(pbuf, fuse_b, pm);
    sort_kernel<<<4, 1024, 0, stream>>>(pm, ord, inv);
    transpose_pe_kernel<<<dim3(128, 6, 2), dim3(32, 8), 0, stream>>>(prox, proxt, pe, 0);
    depth_kernel<<<512, 256, 0, stream>>>(proxt, depth_enc_w, depth_enc_b, depth_proj_w,
                                          sig_w, sig_b, dproj, dsig);
    for (int X = 0; X < 2; ++X) {
        const float* xin = X ? x_R : x_T;
        const float* Alog = X ? A_log_R : A_log_T;
        const float* Dv = X ? D_R : D_T;
        const int* ordX = ord + X * 2 * LL;
        transpose_pe_kernel<<<dim3(128, 6, 2), dim3(32, 8), 0, stream>>>(xin, xpe, pe, 1);
        project_kernel<<<1024, 256, 0, stream>>>(xpe, ordX, x_proj_w, dt_w, dt_b,
                                                 dproj, dsig, dtb2, dub2, bscs2);
        scan_fused_kernel<<<4 * DI, 512, 0, stream>>>(dtb2, dub2, bscs2, Alog, ybuf);
        ln_kernel<<<512, 256, 0, stream>>>(ybuf, xpe, ordX, Dv, ln_g, ln_b, out, X);
    }
}

// Round 6
// 317.056 us; speedup vs baseline: 1.7974x; 1.0323x over previous
//
#include <hip/hip_runtime.h>
#include <hip/hip_bf16.h>
#include <math.h>

// Problem constants
#define BATCH 2
#define DI 192          // D_INNER
#define NST 16          // D_STATE
#define DTR 6           // DT_RANK
#define KK 2
#define LL 4096
#define CT 256          // timesteps per scan chunk (4 per lane)
#define NCK (LL/CT)     // 16 chunk iterations

// ---------------- pe table: pe[col][c], col=l%64 ----------------
__global__ void pe_kernel(float* __restrict__ pe) {
    int i = blockIdx.x * 256 + threadIdx.x;
    if (i >= 64 * DI) return;
    int col = i / DI, c = i % DI;
    float gx = (float)col / 63.f;
    int m = (c < 96) ? c : (c - 96);
    float invf = expf(-(float)m * (logf(10000.f) / 96.f));
    float ang = gx * invf;
    pe[i] = (c < 96) ? sinf(ang) : cosf(ang);
}

// ---------------- fuse conv partials: grid (12 cgroups, 64 rows, 2 b) --------
__global__ void fusepm_part_kernel(const float* __restrict__ xT, const float* __restrict__ xR,
                                   const float* __restrict__ prox, const float* __restrict__ fw,
                                   float* __restrict__ pbuf) {
    __shared__ float wl[288];
    __shared__ float red[2][4][64];
    int cg = blockIdx.x;
    int row = blockIdx.y;
    int b = blockIdx.z;
    int tid = threadIdx.x;
    if (tid < 288) {
        int cl = (tid % 144) / 9, tap = tid % 9;
        int half = tid / 144;
        wl[tid] = fw[(half * DI + cg * 16 + cl) * 9 + tap];
    }
    __syncthreads();
    int px = tid & 63, g = tid >> 6;
    float aT = 0.f, aR = 0.f, aP = 0.f;
    #pragma unroll
    for (int cc = 0; cc < 4; ++cc) {
        int cl = g * 4 + cc;
        int c = cg * 16 + cl;
        const float* xTb = xT + (size_t)(b * DI + c) * LL;
        const float* xRb = xR + (size_t)(b * DI + c) * LL;
        const float* pb  = prox + (size_t)(b * DI + c) * LL;
        const float* wT = wl + cl * 9;
        const float* wP = wl + 144 + cl * 9;
        #pragma unroll
        for (int ky = 0; ky < 3; ++ky) {
            int yy = row + ky - 1;
            if (yy < 0 || yy > 63) continue;
            #pragma unroll
            for (int kx = 0; kx < 3; ++kx) {
                int xx = px + kx - 1;
                bool in = (xx >= 0 && xx < 64);
                int o = yy * 64 + (in ? xx : 0);
                float mT = in ? xTb[o] : 0.f;
                float mR = in ? xRb[o] : 0.f;
                float mP = in ? pb[o] : 0.f;
                float wTv = wT[ky * 3 + kx], wPv = wP[ky * 3 + kx];
                aT += mT * wTv;
                aR += mR * wTv;
                aP += mP * wPv;
            }
        }
    }
    red[0][g][px] = aT + aP;
    red[1][g][px] = aR + aP;
    __syncthreads();
    if (tid < 128) {
        int X = tid >> 6, x = tid & 63;
        float s = red[X][0][x] + red[X][1][x] + red[X][2][x] + red[X][3][x];
        pbuf[(size_t)(cg * 4 + X * 2 + b) * LL + row * 64 + x] = s;
    }
}

// ---------------- reduce 12 partials -> pm[X*2+b][L] ----------------
__global__ void fusepm_reduce_kernel(const float* __restrict__ pbuf,
                                     const float* __restrict__ fb,
                                     float* __restrict__ pm) {
    int idx = blockIdx.x * 256 + threadIdx.x;
    int Xb = idx >> 12;
    int l = idx & 4095;
    float s = fb[0];
    #pragma unroll
    for (int cg = 0; cg < 12; ++cg)
        s += pbuf[(size_t)(cg * 4 + Xb) * LL + l];
    pm[(size_t)Xb * LL + l] = s;
}

// ---------------- bitonic argsort (stable via index tie-break) ----------------
__global__ void sort_kernel(const float* __restrict__ pm, int* __restrict__ ord,
                            int* __restrict__ inv) {
    __shared__ float key[LL];
    __shared__ int idx[LL];
    int X = blockIdx.x >> 1, b = blockIdx.x & 1;
    const float* z = pm + (X * 2 + b) * LL;
    for (int i = threadIdx.x; i < LL; i += 1024) {
        float v = z[i];
        key[i] = (X == 0) ? -v : v;
        idx[i] = i;
    }
    __syncthreads();
    for (int k = 2; k <= LL; k <<= 1) {
        for (int j = k >> 1; j >= 1; j >>= 1) {
            for (int t = threadIdx.x; t < LL / 2; t += 1024) {
                int i = ((t & ~(j - 1)) << 1) | (t & (j - 1));
                int p = i | j;
                bool asc = ((i & k) == 0);
                float ka = key[i], kb = key[p];
                int ia = idx[i], ib = idx[p];
                bool agt = (ka > kb) || (ka == kb && ia > ib);
                if (agt == asc) { key[i] = kb; key[p] = ka; idx[i] = ib; idx[p] = ia; }
            }
            __syncthreads();
        }
    }
    int* o = ord + (X * 2 + b) * LL;
    int* iv = inv + (X * 2 + b) * LL;
    for (int s = threadIdx.x; s < LL; s += 1024) {
        int j = idx[s];
        o[s] = j;
        iv[j] = s;
    }
}

// ---------------- weight transposes (coalesced-read layouts) ------------------
// wtT[i][j], i<192, j<272: j<192 -> wde[j][i]; j<256 -> dpw[j-192][i]; else sgw[j-256][i]
// xpwT[(k*192+i)*38 + j] = xpw[(k*38+j)*192 + i]
__global__ void wt_transpose_kernel(const float* __restrict__ wde, const float* __restrict__ dpw,
                                    const float* __restrict__ sgw, const float* __restrict__ xpw,
                                    float* __restrict__ wtT, float* __restrict__ xpwT) {
    int idx = blockIdx.x * 256 + threadIdx.x;
    if (idx < 192 * 272) {
        int i = idx / 272, j = idx % 272;
        float v;
        if (j < 192) v = wde[j * DI + i];
        else if (j < 256) v = dpw[(j - 192) * DI + i];
        else v = sgw[(j - 256) * DI + i];
        wtT[idx] = v;
    } else if (idx < 192 * 272 + 2 * 192 * 38) {
        int t = idx - 192 * 272;
        int j = t % 38;
        int ki = t / 38;
        int i = ki % 192, k = ki / 192;
        xpwT[t] = xpw[((size_t)k * 38 + j) * DI + i];
    }
}

// ---------------- transpose NCHW (b,c,l) -> (b,l,c), optionally add pe --------
__global__ void transpose_pe_kernel(const float* __restrict__ in, float* __restrict__ out,
                                    const float* __restrict__ pe, int use_pe) {
    __shared__ float tile[32][33];
    int b = blockIdx.z;
    int l0 = blockIdx.x * 32, c0 = blockIdx.y * 32;
    int tx = threadIdx.x, ty = threadIdx.y;
    #pragma unroll
    for (int r = 0; r < 4; ++r) {
        int c = c0 + ty + r * 8;
        tile[ty + r * 8][tx] = in[(size_t)(b * DI + c) * LL + l0 + tx];
    }
    __syncthreads();
    #pragma unroll
    for (int r = 0; r < 4; ++r) {
        int l = l0 + ty + r * 8;
        int c = c0 + tx;
        float v = tile[tx][ty + r * 8];
        if (use_pe) v += pe[(l & 63) * DI + c];
        out[(size_t)(b * LL + l) * DI + c] = v;
    }
}

// ---------------- depth path: 8 positions/block, transposed weights ----------
// phase1 (tid<192): df[p][tid] = leaky(sum_i wtT[i][tid]*pv[p][i] + b)
// phase2 (tid<160): o=tid>>1 (64 dproj + 16 dsig), 4 positions per thread
__global__ __launch_bounds__(256) void depth_kernel(
        const float* __restrict__ proxt, const float* __restrict__ wtT,
        const float* __restrict__ bde, const float* __restrict__ sgb,
        float* __restrict__ dproj, float* __restrict__ dsig) {
    __shared__ float pvs[8][DI];
    __shared__ float dfs[8][DI];
    int bl0 = blockIdx.x * 8;
    int tid = threadIdx.x;
    for (int t = tid; t < 8 * DI; t += 256)
        pvs[t / DI][t % DI] = proxt[(size_t)bl0 * DI + t];
    __syncthreads();
    if (tid < DI) {
        float acc[8];
        #pragma unroll
        for (int l = 0; l < 8; ++l) acc[l] = 0.f;
        const float* wp = wtT + tid;
        for (int i = 0; i < DI; ++i) {
            float w = wp[i * 272];
            #pragma unroll
            for (int l = 0; l < 8; ++l) acc[l] += w * pvs[l][i];
        }
        float bias = bde[tid];
        #pragma unroll
        for (int l = 0; l < 8; ++l) {
            float v = acc[l] + bias;
            dfs[l][tid] = (v > 0.f) ? v : 0.2f * v;
        }
    }
    __syncthreads();
    if (tid < 160) {
        int o = tid >> 1;
        int ph = (tid & 1) * 4;
        float acc[4] = {0.f, 0.f, 0.f, 0.f};
        const float* wp = wtT + 192 + o;
        for (int i = 0; i < DI; ++i) {
            float w = wp[i * 272];
            #pragma unroll
            for (int p = 0; p < 4; ++p) acc[p] += w * dfs[ph + p][i];
        }
        if (o < 64) {
            #pragma unroll
            for (int p = 0; p < 4; ++p)
                dproj[(size_t)(bl0 + ph + p) * 64 + o] = acc[p];
        } else {
            float bias = sgb[o - 64];
            #pragma unroll
            for (int p = 0; p < 4; ++p) {
                float v = acc[p] + bias;
                v = (v > 0.f) ? v : 0.2f * v;
                dsig[(size_t)(bl0 + ph + p) * NST + (o - 64)] = 1.f / (1.f + __expf(-v));
            }
        }
    }
}

// ---------------- per-(b,k,s): x_dbl proj, delta, Bs/Cs -> s-minor buffers ----
// dtb2/dub2: [bk][c][s] ; bscs2: [bk][n][s] (B rows 0..15, C rows 16..31)
__global__ void project_kernel(const float* __restrict__ xpe, const int* __restrict__ ord,
                               const float* __restrict__ xpwT, const float* __restrict__ dtw,
                               const float* __restrict__ dtb, const float* __restrict__ dproj,
                               const float* __restrict__ dsig, float* __restrict__ dtb2,
                               float* __restrict__ dub2, float* __restrict__ bscs2) {
    __shared__ float u[16][193];
    __shared__ float dbl[16][40];
    __shared__ int jarr[16];
    int chunk = blockIdx.x & 255;
    int k = (blockIdx.x >> 8) & 1;
    int b = blockIdx.x >> 9;
    int bk = b * 2 + k;
    int s0 = chunk * 16;
    int tid = threadIdx.x;
    if (tid < 16) {
        int s = s0 + tid;
        jarr[tid] = ord[b * LL + ((k == 0) ? s : (LL - 1 - s))];
    }
    __syncthreads();
    for (int t = tid; t < 16 * DI; t += 256) {
        int l = t / DI, i = t - l * DI;
        u[l][i] = xpe[(size_t)(b * LL + jarr[l]) * DI + i];
    }
    __syncthreads();
    {
        int og = tid >> 4, sl = tid & 15;
        float a0 = 0.f, a1 = 0.f, a2 = 0.f;
        bool has2 = (og < 6);
        const float* xw = xpwT + (size_t)k * DI * 38 + og;
        for (int i = 0; i < DI; ++i) {
            float uu = u[sl][i];
            const float* r = xw + i * 38;
            a0 += r[0] * uu;
            a1 += r[16] * uu;
            if (has2) a2 += r[32] * uu;
        }
        dbl[sl][og] = a0;
        dbl[sl][og + 16] = a1;
        if (has2) dbl[sl][og + 32] = a2;
    }
    __syncthreads();
    if (tid < DI) {
        int c = tid;
        float w[6];
        #pragma unroll
        for (int r = 0; r < 6; ++r) w[r] = dtw[(k * DI + c) * DTR + r];
        float bias = dtb[k * DI + c];
        float dtl[16], dul[16];
        #pragma unroll
        for (int sl = 0; sl < 16; ++sl) {
            float d = bias;
            #pragma unroll
            for (int r = 0; r < 6; ++r) d += w[r] * dbl[sl][r];
            float sp = fmaxf(d, 0.f) + log1pf(__expf(-fabsf(d)));
            dtl[sl] = sp;
            dul[sl] = sp * u[sl][c];
        }
        size_t base = (size_t)(bk * DI + c) * LL + s0;
        #pragma unroll
        for (int g = 0; g < 4; ++g) {
            *(float4*)(dtb2 + base + g * 4) =
                make_float4(dtl[g*4], dtl[g*4+1], dtl[g*4+2], dtl[g*4+3]);
            *(float4*)(dub2 + base + g * 4) =
                make_float4(dul[g*4], dul[g*4+1], dul[g*4+2], dul[g*4+3]);
        }
    }
    {
        int n = tid >> 4, sl = tid & 15;
        int j = jarr[sl];
        float w = dsig[(size_t)(b * LL + j) * NST + n];
        float Bo = dbl[sl][6 + n], Co = dbl[sl][22 + n];
        float Bd = dproj[(size_t)(b * LL + j) * 64 + k * 32 + n];
        float Cd = dproj[(size_t)(b * LL + j) * 64 + k * 32 + 16 + n];
        size_t sb = (size_t)(bk * 32 + n) * LL + s0 + sl;
        bscs2[sb] = (1.f - w) * Bo + w * Bd;
        bscs2[sb + (size_t)16 * LL] = (1.f - w) * Co + w * Cd;
    }
}

// ---------------- fused time-parallel selective scan ----------------
__global__ __launch_bounds__(512, 4) void scan_fused_kernel(
        const float* __restrict__ dtb2, const float* __restrict__ dub2,
        const float* __restrict__ bscs2, const float* __restrict__ Alog,
        float* __restrict__ y) {
    __shared__ float ypart[2][8][CT + 4];
    int c = blockIdx.x % DI;
    int bk = blockIdx.x / DI;
    int k = bk & 1;
    int w = threadIdx.x >> 6;
    int t = threadIdx.x & 63;
    float A0 = -__expf(Alog[(k * DI + c) * NST + w]);
    float A1 = -__expf(Alog[(k * DI + c) * NST + w + 8]);
    size_t rowc = (size_t)(bk * DI + c) * LL;
    const float* dtp = dtb2 + rowc;
    const float* dup = dub2 + rowc;
    const float* b0p = bscs2 + (size_t)(bk * 32 + w) * LL;
    const float* c0p = b0p + (size_t)16 * LL;
    const float* b1p = b0p + (size_t)8 * LL;
    const float* c1p = c0p + (size_t)8 * LL;
    float* yrow = y + rowc;
    float Hc0 = 0.f, Hc1 = 0.f;
    int off = t * 4;
    float4 d4 = *(const float4*)(dtp + off);
    float4 u4 = *(const float4*)(dup + off);
    float4 B0 = *(const float4*)(b0p + off);
    float4 C0 = *(const float4*)(c0p + off);
    float4 B1 = *(const float4*)(b1p + off);
    float4 C1 = *(const float4*)(c1p + off);
    for (int ck = 0; ck < NCK; ++ck) {
        int base = ck * CT;
        float4 nd4, nu4, nB0, nC0, nB1, nC1;
        if (ck + 1 < NCK) {
            int noff = base + CT + off;
            nd4 = *(const float4*)(dtp + noff);
            nu4 = *(const float4*)(dup + noff);
            nB0 = *(const float4*)(b0p + noff);
            nC0 = *(const float4*)(c0p + noff);
            nB1 = *(const float4*)(b1p + noff);
            nC1 = *(const float4*)(c1p + noff);
        }
        float la0[4], lb0[4], la1[4], lb1[4];
        float ca0 = 1.f, cb0 = 0.f, ca1 = 1.f, cb1 = 0.f, e;
        e = __expf(d4.x * A0); ca0 *= e; cb0 = cb0 * e + u4.x * B0.x; la0[0] = ca0; lb0[0] = cb0;
        e = __expf(d4.y * A0); ca0 *= e; cb0 = cb0 * e + u4.y * B0.y; la0[1] = ca0; lb0[1] = cb0;
        e = __expf(d4.z * A0); ca0 *= e; cb0 = cb0 * e + u4.z * B0.z; la0[2] = ca0; lb0[2] = cb0;
        e = __expf(d4.w * A0); ca0 *= e; cb0 = cb0 * e + u4.w * B0.w; la0[3] = ca0; lb0[3] = cb0;
        e = __expf(d4.x * A1); ca1 *= e; cb1 = cb1 * e + u4.x * B1.x; la1[0] = ca1; lb1[0] = cb1;
        e = __expf(d4.y * A1); ca1 *= e; cb1 = cb1 * e + u4.y * B1.y; la1[1] = ca1; lb1[1] = cb1;
        e = __expf(d4.z * A1); ca1 *= e; cb1 = cb1 * e + u4.z * B1.z; la1[2] = ca1; lb1[2] = cb1;
        e = __expf(d4.w * A1); ca1 *= e; cb1 = cb1 * e + u4.w * B1.w; la1[3] = ca1; lb1[3] = cb1;
        #pragma unroll
        for (int m = 1; m < 64; m <<= 1) {
            float sa0 = __shfl_up(ca0, m), sb0 = __shfl_up(cb0, m);
            float sa1 = __shfl_up(ca1, m), sb1 = __shfl_up(cb1, m);
            if (t >= m) {
                cb0 = sb0 * ca0 + cb0; ca0 *= sa0;
                cb1 = sb1 * ca1 + cb1; ca1 *= sa1;
            }
        }
        float ea0 = __shfl_up(ca0, 1), eb0 = __shfl_up(cb0, 1);
        float ea1 = __shfl_up(ca1, 1), eb1 = __shfl_up(cb1, 1);
        if (t == 0) { ea0 = 1.f; eb0 = 0.f; ea1 = 1.f; eb1 = 0.f; }
        float h0in = ea0 * Hc0 + eb0;
        float h1in = ea1 * Hc1 + eb1;
        float h03 = la0[3] * h0in + lb0[3];
        float h13 = la1[3] * h1in + lb1[3];
        float yv0 = (la0[0] * h0in + lb0[0]) * C0.x + (la1[0] * h1in + lb1[0]) * C1.x;
        float yv1 = (la0[1] * h0in + lb0[1]) * C0.y + (la1[1] * h1in + lb1[1]) * C1.y;
        float yv2 = (la0[2] * h0in + lb0[2]) * C0.z + (la1[2] * h1in + lb1[2]) * C1.z;
        float yv3 = h03 * C0.w + h13 * C1.w;
        Hc0 = __shfl(h03, 63);
        Hc1 = __shfl(h13, 63);
        *(float4*)&ypart[ck & 1][w][off] = make_float4(yv0, yv1, yv2, yv3);
        __syncthreads();
        if (threadIdx.x < CT) {
            int t2 = threadIdx.x;
            float s = 0.f;
            #pragma unroll
            for (int r = 0; r < 8; ++r) s += ypart[ck & 1][r][t2];
            yrow[base + t2] = s;
        }
        d4 = nd4; u4 = nu4; B0 = nB0; C0 = nC0; B1 = nB1; C1 = nC1;
    }
}

// ---------------- s-order gather + D*u + layernorm + output ------------------
__global__ __launch_bounds__(256) void ln_kernel(const float* __restrict__ y,
                          const float* __restrict__ xpe,
                          const int* __restrict__ ord, const float* __restrict__ Dvec,
                          const float* __restrict__ g, const float* __restrict__ beta,
                          float* __restrict__ out, int X) {
    __shared__ float y0t[DI][17];
    __shared__ float y1t[DI][17];
    int b = blockIdx.x >> 8;
    int s0 = (blockIdx.x & 255) * 16;
    int tid = threadIdx.x;
    for (int idx = tid; idx < DI * 16; idx += 256) {
        int c = idx >> 4, j = idx & 15;
        y0t[c][j] = y[((size_t)(b * 2 + 0) * DI + c) * LL + s0 + j];
        y1t[c][j] = y[((size_t)(b * 2 + 1) * DI + c) * LL + (LL - 1 - s0 - j)];
    }
    __syncthreads();
    int w = tid >> 6, lane = tid & 63;
    #pragma unroll
    for (int it = 0; it < 4; ++it) {
        int j = it * 4 + w;
        int l = ord[b * LL + s0 + j];
        const float* xr = xpe + (size_t)(b * LL + l) * DI;
        float v[3];
        float sum = 0.f, sq = 0.f;
        #pragma unroll
        for (int r = 0; r < 3; ++r) {
            int c = lane + r * 64;
            float t = y0t[c][j] + y1t[c][j] + (Dvec[c] + Dvec[DI + c]) * xr[c];
            v[r] = t; sum += t; sq += t * t;
        }
        #pragma unroll
        for (int m = 1; m < 64; m <<= 1) {
            sum += __shfl_xor(sum, m);
            sq += __shfl_xor(sq, m);
        }
        float mu = sum * (1.f / 192.f);
        float var = sq * (1.f / 192.f) - mu * mu;
        float rs = rsqrtf(var + 1e-5f);
        float* op = out + ((size_t)(X * 2 + b) * LL + l) * DI;
        #pragma unroll
        for (int r = 0; r < 3; ++r) {
            int c = lane + r * 64;
            op[c] = (v[r] - mu) * rs * g[c] + beta[c];
        }
    }
}

extern "C" void kernel_launch(void* const* d_in, const int* in_sizes, int n_in,
                              void* d_out, int out_size, void* d_ws, size_t ws_size,
                              hipStream_t stream) {
    const float* x_T = (const float*)d_in[0];
    const float* x_R = (const float*)d_in[1];
    const float* prox = (const float*)d_in[2];
    const float* fuse_w = (const float*)d_in[3];
    const float* fuse_b = (const float*)d_in[4];
    const float* x_proj_w = (const float*)d_in[5];
    const float* dt_w = (const float*)d_in[6];
    const float* dt_b = (const float*)d_in[7];
    const float* A_log_T = (const float*)d_in[8];
    const float* A_log_R = (const float*)d_in[9];
    const float* D_T = (const float*)d_in[10];
    const float* D_R = (const float*)d_in[11];
    const float* depth_enc_w = (const float*)d_in[12];
    const float* depth_enc_b = (const float*)d_in[13];
    const float* depth_proj_w = (const float*)d_in[14];
    const float* sig_w = (const float*)d_in[15];
    const float* sig_b = (const float*)d_in[16];
    const float* ln_g = (const float*)d_in[17];
    const float* ln_b = (const float*)d_in[18];
    float* out = (float*)d_out;
    char* ws = (char*)d_ws;

    float* pe    = (float*)(ws + 0);         //   49152
    float* pm    = (float*)(ws + 49152);     //   65536 (dead after sort -> xpwT)
    int*   ord   = (int*)(ws + 114688);      //   65536
    int*   inv   = (int*)(ws + 180224);      //   65536
    float* proxt = (float*)(ws + 245760);    // 6291456
    float* dproj = (float*)(ws + 6537216);   // 2097152
    float* dsig  = (float*)(ws + 8634368);   //  524288
    float* xpe   = (float*)(ws + 9158656);   // 6291456 (reused per branch)
    float* dtb2  = (float*)(ws + 15450112);  // 12582912
    float* dub2  = (float*)(ws + 28033024);  // 12582912
    float* bscs2 = (float*)(ws + 40615936);  // 2097152
    float* ybuf  = (float*)(ws + 42713088);  // 12582912, layout [bk][c][s]
    float* pbuf  = dtb2;                     // fuse partials (dead until project)
    float* wtT   = bscs2;                    // 209 KB, dead once project writes bscs2
    float* xpwT  = pm;                       // 58 KB, pm dead after sort

    pe_kernel<<<48, 256, 0, stream>>>(pe);
    fusepm_part_kernel<<<dim3(12, 64, 2), 256, 0, stream>>>(x_T, x_R, prox, fuse_w, pbuf);
    fusepm_reduce_kernel<<<64, 256, 0, stream>>>(pbuf, fuse_b, pm);
    sort_kernel<<<4, 1024, 0, stream>>>(pm, ord, inv);
    wt_transpose_kernel<<<261, 256, 0, stream>>>(depth_enc_w, depth_proj_w, sig_w,
                                                 x_proj_w, wtT, xpwT);
    transpose_pe_kernel<<<dim3(128, 6, 2), dim3(32, 8), 0, stream>>>(prox, proxt, pe, 0);
    depth_kernel<<<1024, 256, 0, stream>>>(proxt, wtT, depth_enc_b, sig_b, dproj, dsig);
    for (int X = 0; X < 2; ++X) {
        const float* xin = X ? x_R : x_T;
        const float* Alog = X ? A_log_R : A_log_T;
        const float* Dv = X ? D_R : D_T;
        const int* ordX = ord + X * 2 * LL;
        transpose_pe_kernel<<<dim3(128, 6, 2), dim3(32, 8), 0, stream>>>(xin, xpe, pe, 1);
        project_kernel<<<1024, 256, 0, stream>>>(xpe, ordX, xpwT, dt_w, dt_b,
                                                 dproj, dsig, dtb2, dub2, bscs2);
        scan_fused_kernel<<<4 * DI, 512, 0, stream>>>(dtb2, dub2, bscs2, Alog, ybuf);
        ln_kernel<<<512, 256, 0, stream>>>(ybuf, xpe, ordX, Dv, ln_g, ln_b, out, X);
    }
}

// Round 7
// 290.094 us; speedup vs baseline: 1.9644x; 1.0929x over previous
//
#include <hip/hip_runtime.h>
#include <hip/hip_bf16.h>
#include <math.h>

// Problem constants
#define BATCH 2
#define DI 192          // D_INNER
#define NST 16          // D_STATE
#define DTR 6           // DT_RANK
#define KK 2
#define LL 4096
#define CT 512          // timesteps per scan chunk (8 per lane)
#define NCK (LL/CT)     // 8 chunk iterations

// ---------------- pe table: pe[col][c], col=l%64 ----------------
__global__ void pe_kernel(float* __restrict__ pe) {
    int i = blockIdx.x * 256 + threadIdx.x;
    if (i >= 64 * DI) return;
    int col = i / DI, c = i % DI;
    float gx = (float)col / 63.f;
    int m = (c < 96) ? c : (c - 96);
    float invf = expf(-(float)m * (logf(10000.f) / 96.f));
    float ang = gx * invf;
    pe[i] = (c < 96) ? sinf(ang) : cosf(ang);
}

// ---------------- fuse conv partials: grid (12 cgroups, 64 rows, 2 b) --------
__global__ void fusepm_part_kernel(const float* __restrict__ xT, const float* __restrict__ xR,
                                   const float* __restrict__ prox, const float* __restrict__ fw,
                                   float* __restrict__ pbuf) {
    __shared__ float wl[288];
    __shared__ float red[2][4][64];
    int cg = blockIdx.x;
    int row = blockIdx.y;
    int b = blockIdx.z;
    int tid = threadIdx.x;
    if (tid < 288) {
        int cl = (tid % 144) / 9, tap = tid % 9;
        int half = tid / 144;
        wl[tid] = fw[(half * DI + cg * 16 + cl) * 9 + tap];
    }
    __syncthreads();
    int px = tid & 63, g = tid >> 6;
    float aT = 0.f, aR = 0.f, aP = 0.f;
    #pragma unroll
    for (int cc = 0; cc < 4; ++cc) {
        int cl = g * 4 + cc;
        int c = cg * 16 + cl;
        const float* xTb = xT + (size_t)(b * DI + c) * LL;
        const float* xRb = xR + (size_t)(b * DI + c) * LL;
        const float* pb  = prox + (size_t)(b * DI + c) * LL;
        const float* wT = wl + cl * 9;
        const float* wP = wl + 144 + cl * 9;
        #pragma unroll
        for (int ky = 0; ky < 3; ++ky) {
            int yy = row + ky - 1;
            if (yy < 0 || yy > 63) continue;
            #pragma unroll
            for (int kx = 0; kx < 3; ++kx) {
                int xx = px + kx - 1;
                bool in = (xx >= 0 && xx < 64);
                int o = yy * 64 + (in ? xx : 0);
                float mT = in ? xTb[o] : 0.f;
                float mR = in ? xRb[o] : 0.f;
                float mP = in ? pb[o] : 0.f;
                float wTv = wT[ky * 3 + kx], wPv = wP[ky * 3 + kx];
                aT += mT * wTv;
                aR += mR * wTv;
                aP += mP * wPv;
            }
        }
    }
    red[0][g][px] = aT + aP;
    red[1][g][px] = aR + aP;
    __syncthreads();
    if (tid < 128) {
        int X = tid >> 6, x = tid & 63;
        float s = red[X][0][x] + red[X][1][x] + red[X][2][x] + red[X][3][x];
        pbuf[(size_t)(cg * 4 + X * 2 + b) * LL + row * 64 + x] = s;
    }
}

// ---------------- reduce 12 partials -> pm[X*2+b][L] ----------------
__global__ void fusepm_reduce_kernel(const float* __restrict__ pbuf,
                                     const float* __restrict__ fb,
                                     float* __restrict__ pm) {
    int idx = blockIdx.x * 256 + threadIdx.x;
    int Xb = idx >> 12;
    int l = idx & 4095;
    float s = fb[0];
    #pragma unroll
    for (int cg = 0; cg < 12; ++cg)
        s += pbuf[(size_t)(cg * 4 + Xb) * LL + l];
    pm[(size_t)Xb * LL + l] = s;
}

// ---------------- bitonic argsort (stable via index tie-break) ----------------
__global__ void sort_kernel(const float* __restrict__ pm, int* __restrict__ ord,
                            int* __restrict__ inv) {
    __shared__ float key[LL];
    __shared__ int idx[LL];
    int X = blockIdx.x >> 1, b = blockIdx.x & 1;
    const float* z = pm + (X * 2 + b) * LL;
    for (int i = threadIdx.x; i < LL; i += 1024) {
        float v = z[i];
        key[i] = (X == 0) ? -v : v;
        idx[i] = i;
    }
    __syncthreads();
    for (int k = 2; k <= LL; k <<= 1) {
        for (int j = k >> 1; j >= 1; j >>= 1) {
            for (int t = threadIdx.x; t < LL / 2; t += 1024) {
                int i = ((t & ~(j - 1)) << 1) | (t & (j - 1));
                int p = i | j;
                bool asc = ((i & k) == 0);
                float ka = key[i], kb = key[p];
                int ia = idx[i], ib = idx[p];
                bool agt = (ka > kb) || (ka == kb && ia > ib);
                if (agt == asc) { key[i] = kb; key[p] = ka; idx[i] = ib; idx[p] = ia; }
            }
            __syncthreads();
        }
    }
    int* o = ord + (X * 2 + b) * LL;
    int* iv = inv + (X * 2 + b) * LL;
    for (int s = threadIdx.x; s < LL; s += 1024) {
        int j = idx[s];
        o[s] = j;
        iv[j] = s;
    }
}

// ---------------- depth weight transpose: wtT[i][j] ----------------
// j<192 -> wde[j][i]; j<256 -> dpw[j-192][i]; else sgw[j-256][i]
__global__ void wt_transpose_kernel(const float* __restrict__ wde, const float* __restrict__ dpw,
                                    const float* __restrict__ sgw, float* __restrict__ wtT) {
    int idx = blockIdx.x * 256 + threadIdx.x;
    if (idx < 192 * 272) {
        int i = idx / 272, j = idx % 272;
        float v;
        if (j < 192) v = wde[j * DI + i];
        else if (j < 256) v = dpw[(j - 192) * DI + i];
        else v = sgw[(j - 256) * DI + i];
        wtT[idx] = v;
    }
}

// ---------------- transpose NCHW (b,c,l) -> (b,l,c), optionally add pe --------
__global__ void transpose_pe_kernel(const float* __restrict__ in, float* __restrict__ out,
                                    const float* __restrict__ pe, int use_pe) {
    __shared__ float tile[32][33];
    int b = blockIdx.z;
    int l0 = blockIdx.x * 32, c0 = blockIdx.y * 32;
    int tx = threadIdx.x, ty = threadIdx.y;
    #pragma unroll
    for (int r = 0; r < 4; ++r) {
        int c = c0 + ty + r * 8;
        tile[ty + r * 8][tx] = in[(size_t)(b * DI + c) * LL + l0 + tx];
    }
    __syncthreads();
    #pragma unroll
    for (int r = 0; r < 4; ++r) {
        int l = l0 + ty + r * 8;
        int c = c0 + tx;
        float v = tile[tx][ty + r * 8];
        if (use_pe) v += pe[(l & 63) * DI + c];
        out[(size_t)(b * LL + l) * DI + c] = v;
    }
}

// ---------------- depth path: 8 positions/block, transposed weights ----------
__global__ __launch_bounds__(256) void depth_kernel(
        const float* __restrict__ proxt, const float* __restrict__ wtT,
        const float* __restrict__ bde, const float* __restrict__ sgb,
        float* __restrict__ dproj, float* __restrict__ dsig) {
    __shared__ float pvs[8][DI];
    __shared__ float dfs[8][DI];
    int bl0 = blockIdx.x * 8;
    int tid = threadIdx.x;
    for (int t = tid; t < 8 * DI; t += 256)
        pvs[t / DI][t % DI] = proxt[(size_t)bl0 * DI + t];
    __syncthreads();
    if (tid < DI) {
        float acc[8];
        #pragma unroll
        for (int l = 0; l < 8; ++l) acc[l] = 0.f;
        const float* wp = wtT + tid;
        for (int i = 0; i < DI; ++i) {
            float w = wp[i * 272];
            #pragma unroll
            for (int l = 0; l < 8; ++l) acc[l] += w * pvs[l][i];
        }
        float bias = bde[tid];
        #pragma unroll
        for (int l = 0; l < 8; ++l) {
            float v = acc[l] + bias;
            dfs[l][tid] = (v > 0.f) ? v : 0.2f * v;
        }
    }
    __syncthreads();
    if (tid < 160) {
        int o = tid >> 1;
        int ph = (tid & 1) * 4;
        float acc[4] = {0.f, 0.f, 0.f, 0.f};
        const float* wp = wtT + 192 + o;
        for (int i = 0; i < DI; ++i) {
            float w = wp[i * 272];
            #pragma unroll
            for (int p = 0; p < 4; ++p) acc[p] += w * dfs[ph + p][i];
        }
        if (o < 64) {
            #pragma unroll
            for (int p = 0; p < 4; ++p)
                dproj[(size_t)(bl0 + ph + p) * 64 + o] = acc[p];
        } else {
            float bias = sgb[o - 64];
            #pragma unroll
            for (int p = 0; p < 4; ++p) {
                float v = acc[p] + bias;
                v = (v > 0.f) ? v : 0.2f * v;
                dsig[(size_t)(bl0 + ph + p) * NST + (o - 64)] = 1.f / (1.f + __expf(-v));
            }
        }
    }
}

// ---------------- per-(b,k,s): x_dbl proj, delta, Bs/Cs -> s-minor buffers ----
// Row-major x_proj_w: K-loop vectorized float4 (rows contiguous in K).
__global__ void project_kernel(const float* __restrict__ xpe, const int* __restrict__ ord,
                               const float* __restrict__ xpw, const float* __restrict__ dtw,
                               const float* __restrict__ dtb, const float* __restrict__ dproj,
                               const float* __restrict__ dsig, float* __restrict__ dtb2,
                               float* __restrict__ dub2, float* __restrict__ bscs2) {
    __shared__ float u[16][196];        // row stride 784B (16B aligned)
    __shared__ float dbl[16][40];
    __shared__ int jarr[16];
    int chunk = blockIdx.x & 255;
    int k = (blockIdx.x >> 8) & 1;
    int b = blockIdx.x >> 9;
    int bk = b * 2 + k;
    int s0 = chunk * 16;
    int tid = threadIdx.x;
    if (tid < 16) {
        int s = s0 + tid;
        jarr[tid] = ord[b * LL + ((k == 0) ? s : (LL - 1 - s))];
    }
    __syncthreads();
    for (int t = tid; t < 16 * 48; t += 256) {
        int l = t / 48, i4 = t % 48;
        *(float4*)&u[l][i4 * 4] =
            *(const float4*)(xpe + (size_t)(b * LL + jarr[l]) * DI + i4 * 4);
    }
    __syncthreads();
    {
        int og = tid >> 4, sl = tid & 15;
        const float* w0 = xpw + (size_t)(k * 38 + og) * DI;
        const float* w1 = w0 + 16 * DI;
        const float* w2 = w0 + 32 * DI;
        bool has2 = (og < 6);
        float a0 = 0.f, a1 = 0.f, a2 = 0.f;
        for (int i4 = 0; i4 < 48; ++i4) {
            float4 u4 = *(const float4*)&u[sl][i4 * 4];
            float4 x0 = *(const float4*)(w0 + i4 * 4);
            float4 x1 = *(const float4*)(w1 + i4 * 4);
            a0 += x0.x * u4.x + x0.y * u4.y + x0.z * u4.z + x0.w * u4.w;
            a1 += x1.x * u4.x + x1.y * u4.y + x1.z * u4.z + x1.w * u4.w;
            if (has2) {
                float4 x2 = *(const float4*)(w2 + i4 * 4);
                a2 += x2.x * u4.x + x2.y * u4.y + x2.z * u4.z + x2.w * u4.w;
            }
        }
        dbl[sl][og] = a0;
        dbl[sl][og + 16] = a1;
        if (has2) dbl[sl][og + 32] = a2;
    }
    __syncthreads();
    if (tid < DI) {
        int c = tid;
        float w[6];
        #pragma unroll
        for (int r = 0; r < 6; ++r) w[r] = dtw[(k * DI + c) * DTR + r];
        float bias = dtb[k * DI + c];
        float dtl[16], dul[16];
        #pragma unroll
        for (int sl = 0; sl < 16; ++sl) {
            float d = bias;
            #pragma unroll
            for (int r = 0; r < 6; ++r) d += w[r] * dbl[sl][r];
            float sp = fmaxf(d, 0.f) + log1pf(__expf(-fabsf(d)));
            dtl[sl] = sp;
            dul[sl] = sp * u[sl][c];
        }
        size_t base = (size_t)(bk * DI + c) * LL + s0;
        #pragma unroll
        for (int g = 0; g < 4; ++g) {
            *(float4*)(dtb2 + base + g * 4) =
                make_float4(dtl[g*4], dtl[g*4+1], dtl[g*4+2], dtl[g*4+3]);
            *(float4*)(dub2 + base + g * 4) =
                make_float4(dul[g*4], dul[g*4+1], dul[g*4+2], dul[g*4+3]);
        }
    }
    {
        int n = tid >> 4, sl = tid & 15;
        int j = jarr[sl];
        float w = dsig[(size_t)(b * LL + j) * NST + n];
        float Bo = dbl[sl][6 + n], Co = dbl[sl][22 + n];
        float Bd = dproj[(size_t)(b * LL + j) * 64 + k * 32 + n];
        float Cd = dproj[(size_t)(b * LL + j) * 64 + k * 32 + 16 + n];
        size_t sb = (size_t)(bk * 32 + n) * LL + s0 + sl;
        bscs2[sb] = (1.f - w) * Bo + w * Bd;
        bscs2[sb + (size_t)16 * LL] = (1.f - w) * Co + w * Cd;
    }
}

// ---------------- fused time-parallel selective scan (8 steps/lane) ----------
__global__ __launch_bounds__(512, 2) void scan_fused_kernel(
        const float* __restrict__ dtb2, const float* __restrict__ dub2,
        const float* __restrict__ bscs2, const float* __restrict__ Alog,
        float* __restrict__ y) {
    __shared__ float ypart[2][8][CT + 4];
    int c = blockIdx.x % DI;
    int bk = blockIdx.x / DI;
    int k = bk & 1;
    int w = threadIdx.x >> 6;
    int t = threadIdx.x & 63;
    float A0 = -__expf(Alog[(k * DI + c) * NST + w]);
    float A1 = -__expf(Alog[(k * DI + c) * NST + w + 8]);
    size_t rowc = (size_t)(bk * DI + c) * LL;
    const float* dtp = dtb2 + rowc;
    const float* dup = dub2 + rowc;
    const float* b0p = bscs2 + (size_t)(bk * 32 + w) * LL;
    const float* c0p = b0p + (size_t)16 * LL;
    const float* b1p = b0p + (size_t)8 * LL;
    const float* c1p = c0p + (size_t)8 * LL;
    float* yrow = y + rowc;
    float Hc0 = 0.f, Hc1 = 0.f;
    int off = t * 8;
    float4 dA = *(const float4*)(dtp + off), dB = *(const float4*)(dtp + off + 4);
    float4 uA = *(const float4*)(dup + off), uB = *(const float4*)(dup + off + 4);
    float4 B0a = *(const float4*)(b0p + off), B0b = *(const float4*)(b0p + off + 4);
    float4 C0a = *(const float4*)(c0p + off), C0b = *(const float4*)(c0p + off + 4);
    float4 B1a = *(const float4*)(b1p + off), B1b = *(const float4*)(b1p + off + 4);
    float4 C1a = *(const float4*)(c1p + off), C1b = *(const float4*)(c1p + off + 4);
    for (int ck = 0; ck < NCK; ++ck) {
        int base = ck * CT;
        float4 ndA, ndB, nuA, nuB, nB0a, nB0b, nC0a, nC0b, nB1a, nB1b, nC1a, nC1b;
        if (ck + 1 < NCK) {
            int no = base + CT + off;
            ndA = *(const float4*)(dtp + no); ndB = *(const float4*)(dtp + no + 4);
            nuA = *(const float4*)(dup + no); nuB = *(const float4*)(dup + no + 4);
            nB0a = *(const float4*)(b0p + no); nB0b = *(const float4*)(b0p + no + 4);
            nC0a = *(const float4*)(c0p + no); nC0b = *(const float4*)(c0p + no + 4);
            nB1a = *(const float4*)(b1p + no); nB1b = *(const float4*)(b1p + no + 4);
            nC1a = *(const float4*)(c1p + no); nC1b = *(const float4*)(c1p + no + 4);
        }
        float d[8]  = {dA.x, dA.y, dA.z, dA.w, dB.x, dB.y, dB.z, dB.w};
        float uu[8] = {uA.x, uA.y, uA.z, uA.w, uB.x, uB.y, uB.z, uB.w};
        float Bb0[8] = {B0a.x, B0a.y, B0a.z, B0a.w, B0b.x, B0b.y, B0b.z, B0b.w};
        float Cc0[8] = {C0a.x, C0a.y, C0a.z, C0a.w, C0b.x, C0b.y, C0b.z, C0b.w};
        float Bb1[8] = {B1a.x, B1a.y, B1a.z, B1a.w, B1b.x, B1b.y, B1b.z, B1b.w};
        float Cc1[8] = {C1a.x, C1a.y, C1a.z, C1a.w, C1b.x, C1b.y, C1b.z, C1b.w};
        float la0[8], lb0[8], la1[8], lb1[8];
        float ca0 = 1.f, cb0 = 0.f, ca1 = 1.f, cb1 = 0.f;
        #pragma unroll
        for (int j = 0; j < 8; ++j) {
            float e0 = __expf(d[j] * A0);
            ca0 *= e0; cb0 = cb0 * e0 + uu[j] * Bb0[j];
            la0[j] = ca0; lb0[j] = cb0;
            float e1 = __expf(d[j] * A1);
            ca1 *= e1; cb1 = cb1 * e1 + uu[j] * Bb1[j];
            la1[j] = ca1; lb1[j] = cb1;
        }
        // wave inclusive scan over lane totals, monoid (a,b): later(x) = a*x+b
        #pragma unroll
        for (int m = 1; m < 64; m <<= 1) {
            float sa0 = __shfl_up(ca0, m), sb0 = __shfl_up(cb0, m);
            float sa1 = __shfl_up(ca1, m), sb1 = __shfl_up(cb1, m);
            if (t >= m) {
                cb0 = sb0 * ca0 + cb0; ca0 *= sa0;
                cb1 = sb1 * ca1 + cb1; ca1 *= sa1;
            }
        }
        float ea0 = __shfl_up(ca0, 1), eb0 = __shfl_up(cb0, 1);
        float ea1 = __shfl_up(ca1, 1), eb1 = __shfl_up(cb1, 1);
        if (t == 0) { ea0 = 1.f; eb0 = 0.f; ea1 = 1.f; eb1 = 0.f; }
        float h0in = ea0 * Hc0 + eb0;
        float h1in = ea1 * Hc1 + eb1;
        float yv[8];
        #pragma unroll
        for (int j = 0; j < 8; ++j)
            yv[j] = (la0[j] * h0in + lb0[j]) * Cc0[j] + (la1[j] * h1in + lb1[j]) * Cc1[j];
        Hc0 = __shfl(la0[7] * h0in + lb0[7], 63);
        Hc1 = __shfl(la1[7] * h1in + lb1[7], 63);
        *(float4*)&ypart[ck & 1][w][off] = make_float4(yv[0], yv[1], yv[2], yv[3]);
        *(float4*)&ypart[ck & 1][w][off + 4] = make_float4(yv[4], yv[5], yv[6], yv[7]);
        __syncthreads();
        {
            int t2 = threadIdx.x;
            float s = 0.f;
            #pragma unroll
            for (int r = 0; r < 8; ++r) s += ypart[ck & 1][r][t2];
            yrow[base + t2] = s;
        }
        dA = ndA; dB = ndB; uA = nuA; uB = nuB;
        B0a = nB0a; B0b = nB0b; C0a = nC0a; C0b = nC0b;
        B1a = nB1a; B1b = nB1b; C1a = nC1a; C1b = nC1b;
    }
}

// ---------------- s-order gather + D*u + layernorm + output ------------------
__global__ __launch_bounds__(256) void ln_kernel(const float* __restrict__ y,
                          const float* __restrict__ xpe,
                          const int* __restrict__ ord, const float* __restrict__ Dvec,
                          const float* __restrict__ g, const float* __restrict__ beta,
                          float* __restrict__ out, int X) {
    __shared__ float y0t[DI][17];
    __shared__ float y1t[DI][17];
    int b = blockIdx.x >> 8;
    int s0 = (blockIdx.x & 255) * 16;
    int tid = threadIdx.x;
    for (int idx = tid; idx < DI * 16; idx += 256) {
        int c = idx >> 4, j = idx & 15;
        y0t[c][j] = y[((size_t)(b * 2 + 0) * DI + c) * LL + s0 + j];
        y1t[c][j] = y[((size_t)(b * 2 + 1) * DI + c) * LL + (LL - 1 - s0 - j)];
    }
    __syncthreads();
    int w = tid >> 6, lane = tid & 63;
    #pragma unroll
    for (int it = 0; it < 4; ++it) {
        int j = it * 4 + w;
        int l = ord[b * LL + s0 + j];
        const float* xr = xpe + (size_t)(b * LL + l) * DI;
        float v[3];
        float sum = 0.f, sq = 0.f;
        #pragma unroll
        for (int r = 0; r < 3; ++r) {
            int c = lane + r * 64;
            float t = y0t[c][j] + y1t[c][j] + (Dvec[c] + Dvec[DI + c]) * xr[c];
            v[r] = t; sum += t; sq += t * t;
        }
        #pragma unroll
        for (int m = 1; m < 64; m <<= 1) {
            sum += __shfl_xor(sum, m);
            sq += __shfl_xor(sq, m);
        }
        float mu = sum * (1.f / 192.f);
        float var = sq * (1.f / 192.f) - mu * mu;
        float rs = rsqrtf(var + 1e-5f);
        float* op = out + ((size_t)(X * 2 + b) * LL + l) * DI;
        #pragma unroll
        for (int r = 0; r < 3; ++r) {
            int c = lane + r * 64;
            op[c] = (v[r] - mu) * rs * g[c] + beta[c];
        }
    }
}

extern "C" void kernel_launch(void* const* d_in, const int* in_sizes, int n_in,
                              void* d_out, int out_size, void* d_ws, size_t ws_size,
                              hipStream_t stream) {
    const float* x_T = (const float*)d_in[0];
    const float* x_R = (const float*)d_in[1];
    const float* prox = (const float*)d_in[2];
    const float* fuse_w = (const float*)d_in[3];
    const float* fuse_b = (const float*)d_in[4];
    const float* x_proj_w = (const float*)d_in[5];
    const float* dt_w = (const float*)d_in[6];
    const float* dt_b = (const float*)d_in[7];
    const float* A_log_T = (const float*)d_in[8];
    const float* A_log_R = (const float*)d_in[9];
    const float* D_T = (const float*)d_in[10];
    const float* D_R = (const float*)d_in[11];
    const float* depth_enc_w = (const float*)d_in[12];
    const float* depth_enc_b = (const float*)d_in[13];
    const float* depth_proj_w = (const float*)d_in[14];
    const float* sig_w = (const float*)d_in[15];
    const float* sig_b = (const float*)d_in[16];
    const float* ln_g = (const float*)d_in[17];
    const float* ln_b = (const float*)d_in[18];
    float* out = (float*)d_out;
    char* ws = (char*)d_ws;

    float* pe    = (float*)(ws + 0);         //   49152
    float* pm    = (float*)(ws + 49152);     //   65536
    int*   ord   = (int*)(ws + 114688);      //   65536
    int*   inv   = (int*)(ws + 180224);      //   65536
    float* proxt = (float*)(ws + 245760);    // 6291456
    float* dproj = (float*)(ws + 6537216);   // 2097152
    float* dsig  = (float*)(ws + 8634368);   //  524288
    float* xpe   = (float*)(ws + 9158656);   // 6291456 (reused per branch)
    float* dtb2  = (float*)(ws + 15450112);  // 12582912
    float* dub2  = (float*)(ws + 28033024);  // 12582912
    float* bscs2 = (float*)(ws + 40615936);  // 2097152
    float* ybuf  = (float*)(ws + 42713088);  // 12582912, layout [bk][c][s]
    float* pbuf  = dtb2;                     // fuse partials (dead until project)
    float* wtT   = bscs2;                    // 209 KB, dead once project writes bscs2

    pe_kernel<<<48, 256, 0, stream>>>(pe);
    fusepm_part_kernel<<<dim3(12, 64, 2), 256, 0, stream>>>(x_T, x_R, prox, fuse_w, pbuf);
    fusepm_reduce_kernel<<<64, 256, 0, stream>>>(pbuf, fuse_b, pm);
    sort_kernel<<<4, 1024, 0, stream>>>(pm, ord, inv);
    wt_transpose_kernel<<<204, 256, 0, stream>>>(depth_enc_w, depth_proj_w, sig_w, wtT);
    transpose_pe_kernel<<<dim3(128, 6, 2), dim3(32, 8), 0, stream>>>(prox, proxt, pe, 0);
    depth_kernel<<<1024, 256, 0, stream>>>(proxt, wtT, depth_enc_b, sig_b, dproj, dsig);
    for (int X = 0; X < 2; ++X) {
        const float* xin = X ? x_R : x_T;
        const float* Alog = X ? A_log_R : A_log_T;
        const float* Dv = X ? D_R : D_T;
        const int* ordX = ord + X * 2 * LL;
        transpose_pe_kernel<<<dim3(128, 6, 2), dim3(32, 8), 0, stream>>>(xin, xpe, pe, 1);
        project_kernel<<<1024, 256, 0, stream>>>(xpe, ordX, x_proj_w, dt_w, dt_b,
                                                 dproj, dsig, dtb2, dub2, bscs2);
        scan_fused_kernel<<<4 * DI, 512, 0, stream>>>(dtb2, dub2, bscs2, Alog, ybuf);
        ln_kernel<<<512, 256, 0, stream>>>(ybuf, xpe, ordX, Dv, ln_g, ln_b, out, X);
    }
}

// Round 8
// 263.603 us; speedup vs baseline: 2.1619x; 1.1005x over previous
//
#include <hip/hip_runtime.h>
#include <hip/hip_bf16.h>
#include <math.h>

// Problem constants
#define BATCH 2
#define DI 192          // D_INNER
#define NST 16          // D_STATE
#define DTR 6           // DT_RANK
#define KK 2
#define LL 4096
#define CT 512          // timesteps per scan chunk (8 per lane)
#define NCK (LL/CT)     // 8 chunk iterations

// ---------------- pe table: pe[col][c], col=l%64 ----------------
__global__ void pe_kernel(float* __restrict__ pe) {
    int i = blockIdx.x * 256 + threadIdx.x;
    if (i >= 64 * DI) return;
    int col = i / DI, c = i % DI;
    float gx = (float)col / 63.f;
    int m = (c < 96) ? c : (c - 96);
    float invf = expf(-(float)m * (logf(10000.f) / 96.f));
    float ang = gx * invf;
    pe[i] = (c < 96) ? sinf(ang) : cosf(ang);
}

// ---------------- fuse conv partials: grid (12 cgroups, 64 rows, 2 b) --------
__global__ void fusepm_part_kernel(const float* __restrict__ xT, const float* __restrict__ xR,
                                   const float* __restrict__ prox, const float* __restrict__ fw,
                                   float* __restrict__ pbuf) {
    __shared__ float wl[288];
    __shared__ float red[2][4][64];
    int cg = blockIdx.x;
    int row = blockIdx.y;
    int b = blockIdx.z;
    int tid = threadIdx.x;
    if (tid < 288) {
        int cl = (tid % 144) / 9, tap = tid % 9;
        int half = tid / 144;
        wl[tid] = fw[(half * DI + cg * 16 + cl) * 9 + tap];
    }
    __syncthreads();
    int px = tid & 63, g = tid >> 6;
    float aT = 0.f, aR = 0.f, aP = 0.f;
    #pragma unroll
    for (int cc = 0; cc < 4; ++cc) {
        int cl = g * 4 + cc;
        int c = cg * 16 + cl;
        const float* xTb = xT + (size_t)(b * DI + c) * LL;
        const float* xRb = xR + (size_t)(b * DI + c) * LL;
        const float* pb  = prox + (size_t)(b * DI + c) * LL;
        const float* wT = wl + cl * 9;
        const float* wP = wl + 144 + cl * 9;
        #pragma unroll
        for (int ky = 0; ky < 3; ++ky) {
            int yy = row + ky - 1;
            if (yy < 0 || yy > 63) continue;
            #pragma unroll
            for (int kx = 0; kx < 3; ++kx) {
                int xx = px + kx - 1;
                bool in = (xx >= 0 && xx < 64);
                int o = yy * 64 + (in ? xx : 0);
                float mT = in ? xTb[o] : 0.f;
                float mR = in ? xRb[o] : 0.f;
                float mP = in ? pb[o] : 0.f;
                float wTv = wT[ky * 3 + kx], wPv = wP[ky * 3 + kx];
                aT += mT * wTv;
                aR += mR * wTv;
                aP += mP * wPv;
            }
        }
    }
    red[0][g][px] = aT + aP;
    red[1][g][px] = aR + aP;
    __syncthreads();
    if (tid < 128) {
        int X = tid >> 6, x = tid & 63;
        float s = red[X][0][x] + red[X][1][x] + red[X][2][x] + red[X][3][x];
        pbuf[(size_t)(cg * 4 + X * 2 + b) * LL + row * 64 + x] = s;
    }
}

// ---------------- reduce 12 partials -> pm[X*2+b][L] ----------------
__global__ void fusepm_reduce_kernel(const float* __restrict__ pbuf,
                                     const float* __restrict__ fb,
                                     float* __restrict__ pm) {
    int idx = blockIdx.x * 256 + threadIdx.x;
    int Xb = idx >> 12;
    int l = idx & 4095;
    float s = fb[0];
    #pragma unroll
    for (int cg = 0; cg < 12; ++cg)
        s += pbuf[(size_t)(cg * 4 + Xb) * LL + l];
    pm[(size_t)Xb * LL + l] = s;
}

// ---------------- bitonic argsort (stable via index tie-break) ----------------
__global__ void sort_kernel(const float* __restrict__ pm, int* __restrict__ ord,
                            int* __restrict__ inv) {
    __shared__ float key[LL];
    __shared__ int idx[LL];
    int X = blockIdx.x >> 1, b = blockIdx.x & 1;
    const float* z = pm + (X * 2 + b) * LL;
    for (int i = threadIdx.x; i < LL; i += 1024) {
        float v = z[i];
        key[i] = (X == 0) ? -v : v;
        idx[i] = i;
    }
    __syncthreads();
    for (int k = 2; k <= LL; k <<= 1) {
        for (int j = k >> 1; j >= 1; j >>= 1) {
            for (int t = threadIdx.x; t < LL / 2; t += 1024) {
                int i = ((t & ~(j - 1)) << 1) | (t & (j - 1));
                int p = i | j;
                bool asc = ((i & k) == 0);
                float ka = key[i], kb = key[p];
                int ia = idx[i], ib = idx[p];
                bool agt = (ka > kb) || (ka == kb && ia > ib);
                if (agt == asc) { key[i] = kb; key[p] = ka; idx[i] = ib; idx[p] = ia; }
            }
            __syncthreads();
        }
    }
    int* o = ord + (X * 2 + b) * LL;
    int* iv = inv + (X * 2 + b) * LL;
    for (int s = threadIdx.x; s < LL; s += 1024) {
        int j = idx[s];
        o[s] = j;
        iv[j] = s;
    }
}

// ---------------- depth weight transpose: wtT[i][j] ----------------
__global__ void wt_transpose_kernel(const float* __restrict__ wde, const float* __restrict__ dpw,
                                    const float* __restrict__ sgw, float* __restrict__ wtT) {
    int idx = blockIdx.x * 256 + threadIdx.x;
    if (idx < 192 * 272) {
        int i = idx / 272, j = idx % 272;
        float v;
        if (j < 192) v = wde[j * DI + i];
        else if (j < 256) v = dpw[(j - 192) * DI + i];
        else v = sgw[(j - 256) * DI + i];
        wtT[idx] = v;
    }
}

// ---------------- transpose NCHW (b,c,l) -> (b,l,c), optionally add pe --------
__global__ void transpose_pe_kernel(const float* __restrict__ in, float* __restrict__ out,
                                    const float* __restrict__ pe, int use_pe) {
    __shared__ float tile[32][33];
    int b = blockIdx.z;
    int l0 = blockIdx.x * 32, c0 = blockIdx.y * 32;
    int tx = threadIdx.x, ty = threadIdx.y;
    #pragma unroll
    for (int r = 0; r < 4; ++r) {
        int c = c0 + ty + r * 8;
        tile[ty + r * 8][tx] = in[(size_t)(b * DI + c) * LL + l0 + tx];
    }
    __syncthreads();
    #pragma unroll
    for (int r = 0; r < 4; ++r) {
        int l = l0 + ty + r * 8;
        int c = c0 + tx;
        float v = tile[tx][ty + r * 8];
        if (use_pe) v += pe[(l & 63) * DI + c];
        out[(size_t)(b * LL + l) * DI + c] = v;
    }
}

// ---------------- depth path: 8 positions/block, transposed weights ----------
__global__ __launch_bounds__(256) void depth_kernel(
        const float* __restrict__ proxt, const float* __restrict__ wtT,
        const float* __restrict__ bde, const float* __restrict__ sgb,
        float* __restrict__ dproj, float* __restrict__ dsig) {
    __shared__ float pvs[8][DI];
    __shared__ float dfs[8][DI];
    int bl0 = blockIdx.x * 8;
    int tid = threadIdx.x;
    for (int t = tid; t < 8 * DI; t += 256)
        pvs[t / DI][t % DI] = proxt[(size_t)bl0 * DI + t];
    __syncthreads();
    if (tid < DI) {
        float acc[8];
        #pragma unroll
        for (int l = 0; l < 8; ++l) acc[l] = 0.f;
        const float* wp = wtT + tid;
        for (int i = 0; i < DI; ++i) {
            float w = wp[i * 272];
            #pragma unroll
            for (int l = 0; l < 8; ++l) acc[l] += w * pvs[l][i];
        }
        float bias = bde[tid];
        #pragma unroll
        for (int l = 0; l < 8; ++l) {
            float v = acc[l] + bias;
            dfs[l][tid] = (v > 0.f) ? v : 0.2f * v;
        }
    }
    __syncthreads();
    if (tid < 160) {
        int o = tid >> 1;
        int ph = (tid & 1) * 4;
        float acc[4] = {0.f, 0.f, 0.f, 0.f};
        const float* wp = wtT + 192 + o;
        for (int i = 0; i < DI; ++i) {
            float w = wp[i * 272];
            #pragma unroll
            for (int p = 0; p < 4; ++p) acc[p] += w * dfs[ph + p][i];
        }
        if (o < 64) {
            #pragma unroll
            for (int p = 0; p < 4; ++p)
                dproj[(size_t)(bl0 + ph + p) * 64 + o] = acc[p];
        } else {
            float bias = sgb[o - 64];
            #pragma unroll
            for (int p = 0; p < 4; ++p) {
                float v = acc[p] + bias;
                v = (v > 0.f) ? v : 0.2f * v;
                dsig[(size_t)(bl0 + ph + p) * NST + (o - 64)] = 1.f / (1.f + __expf(-v));
            }
        }
    }
}

// ---------------- per-(b,k,s): x_dbl proj, delta, Bs/Cs -> s-minor buffers ----
__global__ void project_kernel(const float* __restrict__ xpe, const int* __restrict__ ord,
                               const float* __restrict__ xpw, const float* __restrict__ dtw,
                               const float* __restrict__ dtb, const float* __restrict__ dproj,
                               const float* __restrict__ dsig, float* __restrict__ dtb2,
                               float* __restrict__ dub2, float* __restrict__ bscs2) {
    __shared__ float u[16][196];        // row stride 784B (16B aligned)
    __shared__ float dbl[16][40];
    __shared__ int jarr[16];
    int chunk = blockIdx.x & 255;
    int k = (blockIdx.x >> 8) & 1;
    int b = blockIdx.x >> 9;
    int bk = b * 2 + k;
    int s0 = chunk * 16;
    int tid = threadIdx.x;
    if (tid < 16) {
        int s = s0 + tid;
        jarr[tid] = ord[b * LL + ((k == 0) ? s : (LL - 1 - s))];
    }
    __syncthreads();
    for (int t = tid; t < 16 * 48; t += 256) {
        int l = t / 48, i4 = t % 48;
        *(float4*)&u[l][i4 * 4] =
            *(const float4*)(xpe + (size_t)(b * LL + jarr[l]) * DI + i4 * 4);
    }
    __syncthreads();
    {
        int og = tid >> 4, sl = tid & 15;
        const float* w0 = xpw + (size_t)(k * 38 + og) * DI;
        const float* w1 = w0 + 16 * DI;
        const float* w2 = w0 + 32 * DI;
        bool has2 = (og < 6);
        float a0 = 0.f, a1 = 0.f, a2 = 0.f;
        for (int i4 = 0; i4 < 48; ++i4) {
            float4 u4 = *(const float4*)&u[sl][i4 * 4];
            float4 x0 = *(const float4*)(w0 + i4 * 4);
            float4 x1 = *(const float4*)(w1 + i4 * 4);
            a0 += x0.x * u4.x + x0.y * u4.y + x0.z * u4.z + x0.w * u4.w;
            a1 += x1.x * u4.x + x1.y * u4.y + x1.z * u4.z + x1.w * u4.w;
            if (has2) {
                float4 x2 = *(const float4*)(w2 + i4 * 4);
                a2 += x2.x * u4.x + x2.y * u4.y + x2.z * u4.z + x2.w * u4.w;
            }
        }
        dbl[sl][og] = a0;
        dbl[sl][og + 16] = a1;
        if (has2) dbl[sl][og + 32] = a2;
    }
    __syncthreads();
    if (tid < DI) {
        int c = tid;
        float w[6];
        #pragma unroll
        for (int r = 0; r < 6; ++r) w[r] = dtw[(k * DI + c) * DTR + r];
        float bias = dtb[k * DI + c];
        float dtl[16], dul[16];
        #pragma unroll
        for (int sl = 0; sl < 16; ++sl) {
            float d = bias;
            #pragma unroll
            for (int r = 0; r < 6; ++r) d += w[r] * dbl[sl][r];
            float sp = fmaxf(d, 0.f) + log1pf(__expf(-fabsf(d)));
            dtl[sl] = sp;
            dul[sl] = sp * u[sl][c];
        }
        size_t base = (size_t)(bk * DI + c) * LL + s0;
        #pragma unroll
        for (int g = 0; g < 4; ++g) {
            *(float4*)(dtb2 + base + g * 4) =
                make_float4(dtl[g*4], dtl[g*4+1], dtl[g*4+2], dtl[g*4+3]);
            *(float4*)(dub2 + base + g * 4) =
                make_float4(dul[g*4], dul[g*4+1], dul[g*4+2], dul[g*4+3]);
        }
    }
    {
        int n = tid >> 4, sl = tid & 15;
        int j = jarr[sl];
        float w = dsig[(size_t)(b * LL + j) * NST + n];
        float Bo = dbl[sl][6 + n], Co = dbl[sl][22 + n];
        float Bd = dproj[(size_t)(b * LL + j) * 64 + k * 32 + n];
        float Cd = dproj[(size_t)(b * LL + j) * 64 + k * 32 + 16 + n];
        size_t sb = (size_t)(bk * 32 + n) * LL + s0 + sl;
        bscs2[sb] = (1.f - w) * Bo + w * Bd;
        bscs2[sb + (size_t)16 * LL] = (1.f - w) * Co + w * Cd;
    }
}

// ---------------- fused time-parallel selective scan (8 steps/lane) ----------
// Monoid scan carried as (S=sum dt, cb) per state; a == exp(A*S) recomputed on
// the trans pipe (shares the S word across both states: 3 bpermutes/level not 4).
// y via sequential replay with kept e0/e1 (no la/lb arrays). VGPR<=85 so three
// 8-wave blocks co-reside per CU -> 768-block grid runs in exactly one round.
__global__ __launch_bounds__(512, 6) void scan_fused_kernel(
        const float* __restrict__ dtb2, const float* __restrict__ dub2,
        const float* __restrict__ bscs2, const float* __restrict__ Alog,
        float* __restrict__ y) {
    __shared__ float ypart[2][8][CT + 4];
    int c = blockIdx.x % DI;
    int bk = blockIdx.x / DI;
    int k = bk & 1;
    int w = threadIdx.x >> 6;
    int t = threadIdx.x & 63;
    float A0 = -__expf(Alog[(k * DI + c) * NST + w]);
    float A1 = -__expf(Alog[(k * DI + c) * NST + w + 8]);
    size_t rowc = (size_t)(bk * DI + c) * LL;
    const float* dtp = dtb2 + rowc;
    const float* dup = dub2 + rowc;
    const float* b0p = bscs2 + (size_t)(bk * 32 + w) * LL;
    const float* c0p = b0p + (size_t)16 * LL;
    const float* b1p = b0p + (size_t)8 * LL;
    const float* c1p = c0p + (size_t)8 * LL;
    float* yrow = y + rowc;
    float Hc0 = 0.f, Hc1 = 0.f;
    int off = t * 8;
    for (int ck = 0; ck < NCK; ++ck) {
        int base = ck * CT;
        int o = base + off;
        float4 dA = *(const float4*)(dtp + o), dB = *(const float4*)(dtp + o + 4);
        float4 uA = *(const float4*)(dup + o), uB = *(const float4*)(dup + o + 4);
        float4 B0a = *(const float4*)(b0p + o), B0b = *(const float4*)(b0p + o + 4);
        float4 B1a = *(const float4*)(b1p + o), B1b = *(const float4*)(b1p + o + 4);
        float d[8]  = {dA.x, dA.y, dA.z, dA.w, dB.x, dB.y, dB.z, dB.w};
        float uu[8] = {uA.x, uA.y, uA.z, uA.w, uB.x, uB.y, uB.z, uB.w};
        float Bb0[8] = {B0a.x, B0a.y, B0a.z, B0a.w, B0b.x, B0b.y, B0b.z, B0b.w};
        float Bb1[8] = {B1a.x, B1a.y, B1a.z, B1a.w, B1b.x, B1b.y, B1b.z, B1b.w};
        float e0[8], e1[8], z0[8], z1[8];
        float S = 0.f, cb0 = 0.f, cb1 = 0.f;
        #pragma unroll
        for (int j = 0; j < 8; ++j) {
            e0[j] = __expf(d[j] * A0);
            e1[j] = __expf(d[j] * A1);
            z0[j] = uu[j] * Bb0[j];
            z1[j] = uu[j] * Bb1[j];
            S += d[j];
            cb0 = cb0 * e0[j] + z0[j];
            cb1 = cb1 * e1[j] + z1[j];
        }
        // wave inclusive scan; segment decay = exp(A*S)
        #pragma unroll
        for (int m = 1; m < 64; m <<= 1) {
            float sS = __shfl_up(S, m);
            float s0 = __shfl_up(cb0, m);
            float s1 = __shfl_up(cb1, m);
            if (t >= m) {
                cb0 += __expf(A0 * S) * s0;
                cb1 += __expf(A1 * S) * s1;
                S += sS;
            }
        }
        // chunk totals (lane 63 inclusive)
        float Sf  = __shfl(S, 63);
        float b0f = __shfl(cb0, 63);
        float b1f = __shfl(cb1, 63);
        // exclusive prefix
        float Se  = __shfl_up(S, 1);
        float b0e = __shfl_up(cb0, 1);
        float b1e = __shfl_up(cb1, 1);
        if (t == 0) { Se = 0.f; b0e = 0.f; b1e = 0.f; }
        float h0 = __expf(A0 * Se) * Hc0 + b0e;
        float h1 = __expf(A1 * Se) * Hc1 + b1e;
        float nHc0 = __expf(A0 * Sf) * Hc0 + b0f;
        float nHc1 = __expf(A1 * Sf) * Hc1 + b1f;
        Hc0 = nHc0; Hc1 = nHc1;
        float4 C0a = *(const float4*)(c0p + o), C0b = *(const float4*)(c0p + o + 4);
        float4 C1a = *(const float4*)(c1p + o), C1b = *(const float4*)(c1p + o + 4);
        float Cc0[8] = {C0a.x, C0a.y, C0a.z, C0a.w, C0b.x, C0b.y, C0b.z, C0b.w};
        float Cc1[8] = {C1a.x, C1a.y, C1a.z, C1a.w, C1b.x, C1b.y, C1b.z, C1b.w};
        float yv[8];
        #pragma unroll
        for (int j = 0; j < 8; ++j) {
            h0 = h0 * e0[j] + z0[j];
            h1 = h1 * e1[j] + z1[j];
            yv[j] = h0 * Cc0[j] + h1 * Cc1[j];
        }
        *(float4*)&ypart[ck & 1][w][off] = make_float4(yv[0], yv[1], yv[2], yv[3]);
        *(float4*)&ypart[ck & 1][w][off + 4] = make_float4(yv[4], yv[5], yv[6], yv[7]);
        __syncthreads();
        if (threadIdx.x < 128) {
            int t4 = threadIdx.x * 4;
            float4 s = *(const float4*)&ypart[ck & 1][0][t4];
            #pragma unroll
            for (int r = 1; r < 8; ++r) {
                float4 v = *(const float4*)&ypart[ck & 1][r][t4];
                s.x += v.x; s.y += v.y; s.z += v.z; s.w += v.w;
            }
            *(float4*)(yrow + base + t4) = s;
        }
        // no second barrier: next iter writes ypart[(ck+1)&1], disjoint buffer
    }
}

// ---------------- s-order gather + D*u + layernorm + output ------------------
__global__ __launch_bounds__(256) void ln_kernel(const float* __restrict__ y,
                          const float* __restrict__ xpe,
                          const int* __restrict__ ord, const float* __restrict__ Dvec,
                          const float* __restrict__ g, const float* __restrict__ beta,
                          float* __restrict__ out, int X) {
    __shared__ float y0t[DI][17];
    __shared__ float y1t[DI][17];
    int b = blockIdx.x >> 8;
    int s0 = (blockIdx.x & 255) * 16;
    int tid = threadIdx.x;
    for (int idx = tid; idx < DI * 16; idx += 256) {
        int c = idx >> 4, j = idx & 15;
        y0t[c][j] = y[((size_t)(b * 2 + 0) * DI + c) * LL + s0 + j];
        y1t[c][j] = y[((size_t)(b * 2 + 1) * DI + c) * LL + (LL - 1 - s0 - j)];
    }
    __syncthreads();
    int w = tid >> 6, lane = tid & 63;
    #pragma unroll
    for (int it = 0; it < 4; ++it) {
        int j = it * 4 + w;
        int l = ord[b * LL + s0 + j];
        const float* xr = xpe + (size_t)(b * LL + l) * DI;
        float v[3];
        float sum = 0.f, sq = 0.f;
        #pragma unroll
        for (int r = 0; r < 3; ++r) {
            int c = lane + r * 64;
            float t = y0t[c][j] + y1t[c][j] + (Dvec[c] + Dvec[DI + c]) * xr[c];
            v[r] = t; sum += t; sq += t * t;
        }
        #pragma unroll
        for (int m = 1; m < 64; m <<= 1) {
            sum += __shfl_xor(sum, m);
            sq += __shfl_xor(sq, m);
        }
        float mu = sum * (1.f / 192.f);
        float var = sq * (1.f / 192.f) - mu * mu;
        float rs = rsqrtf(var + 1e-5f);
        float* op = out + ((size_t)(X * 2 + b) * LL + l) * DI;
        #pragma unroll
        for (int r = 0; r < 3; ++r) {
            int c = lane + r * 64;
            op[c] = (v[r] - mu) * rs * g[c] + beta[c];
        }
    }
}

extern "C" void kernel_launch(void* const* d_in, const int* in_sizes, int n_in,
                              void* d_out, int out_size, void* d_ws, size_t ws_size,
                              hipStream_t stream) {
    const float* x_T = (const float*)d_in[0];
    const float* x_R = (const float*)d_in[1];
    const float* prox = (const float*)d_in[2];
    const float* fuse_w = (const float*)d_in[3];
    const float* fuse_b = (const float*)d_in[4];
    const float* x_proj_w = (const float*)d_in[5];
    const float* dt_w = (const float*)d_in[6];
    const float* dt_b = (const float*)d_in[7];
    const float* A_log_T = (const float*)d_in[8];
    const float* A_log_R = (const float*)d_in[9];
    const float* D_T = (const float*)d_in[10];
    const float* D_R = (const float*)d_in[11];
    const float* depth_enc_w = (const float*)d_in[12];
    const float* depth_enc_b = (const float*)d_in[13];
    const float* depth_proj_w = (const float*)d_in[14];
    const float* sig_w = (const float*)d_in[15];
    const float* sig_b = (const float*)d_in[16];
    const float* ln_g = (const float*)d_in[17];
    const float* ln_b = (const float*)d_in[18];
    float* out = (float*)d_out;
    char* ws = (char*)d_ws;

    float* pe    = (float*)(ws + 0);         //   49152
    float* pm    = (float*)(ws + 49152);     //   65536
    int*   ord   = (int*)(ws + 114688);      //   65536
    int*   inv   = (int*)(ws + 180224);      //   65536
    float* proxt = (float*)(ws + 245760);    // 6291456
    float* dproj = (float*)(ws + 6537216);   // 2097152
    float* dsig  = (float*)(ws + 8634368);   //  524288
    float* xpe   = (float*)(ws + 9158656);   // 6291456 (reused per branch)
    float* dtb2  = (float*)(ws + 15450112);  // 12582912
    float* dub2  = (float*)(ws + 28033024);  // 12582912
    float* bscs2 = (float*)(ws + 40615936);  // 2097152
    float* ybuf  = (float*)(ws + 42713088);  // 12582912, layout [bk][c][s]
    float* pbuf  = dtb2;                     // fuse partials (dead until project)
    float* wtT   = bscs2;                    // 209 KB, dead once project writes bscs2

    pe_kernel<<<48, 256, 0, stream>>>(pe);
    fusepm_part_kernel<<<dim3(12, 64, 2), 256, 0, stream>>>(x_T, x_R, prox, fuse_w, pbuf);
    fusepm_reduce_kernel<<<64, 256, 0, stream>>>(pbuf, fuse_b, pm);
    sort_kernel<<<4, 1024, 0, stream>>>(pm, ord, inv);
    wt_transpose_kernel<<<204, 256, 0, stream>>>(depth_enc_w, depth_proj_w, sig_w, wtT);
    transpose_pe_kernel<<<dim3(128, 6, 2), dim3(32, 8), 0, stream>>>(prox, proxt, pe, 0);
    depth_kernel<<<1024, 256, 0, stream>>>(proxt, wtT, depth_enc_b, sig_b, dproj, dsig);
    for (int X = 0; X < 2; ++X) {
        const float* xin = X ? x_R : x_T;
        const float* Alog = X ? A_log_R : A_log_T;
        const float* Dv = X ? D_R : D_T;
        const int* ordX = ord + X * 2 * LL;
        transpose_pe_kernel<<<dim3(128, 6, 2), dim3(32, 8), 0, stream>>>(xin, xpe, pe, 1);
        project_kernel<<<1024, 256, 0, stream>>>(xpe, ordX, x_proj_w, dt_w, dt_b,
                                                 dproj, dsig, dtb2, dub2, bscs2);
        scan_fused_kernel<<<4 * DI, 512, 0, stream>>>(dtb2, dub2, bscs2, Alog, ybuf);
        ln_kernel<<<512, 256, 0, stream>>>(ybuf, xpe, ordX, Dv, ln_g, ln_b, out, X);
    }
}

// Round 9
// 244.503 us; speedup vs baseline: 2.3307x; 1.0781x over previous
//
#include <hip/hip_runtime.h>
#include <hip/hip_bf16.h>
#include <math.h>

// Problem constants
#define BATCH 2
#define DI 192          // D_INNER
#define NST 16          // D_STATE
#define DTR 6           // DT_RANK
#define KK 2
#define LL 4096
#define CT 512          // timesteps per scan chunk (8 per lane)
#define NCK (LL/CT)     // 8 chunk iterations

// ---------------- pe table: pe[col][c], col=l%64 ----------------
__global__ void pe_kernel(float* __restrict__ pe) {
    int i = blockIdx.x * 256 + threadIdx.x;
    if (i >= 64 * DI) return;
    int col = i / DI, c = i % DI;
    float gx = (float)col / 63.f;
    int m = (c < 96) ? c : (c - 96);
    float invf = expf(-(float)m * (logf(10000.f) / 96.f));
    float ang = gx * invf;
    pe[i] = (c < 96) ? sinf(ang) : cosf(ang);
}

// ---------------- fuse conv partials: grid (12 cgroups, 64 rows, 2 b) --------
__global__ void fusepm_part_kernel(const float* __restrict__ xT, const float* __restrict__ xR,
                                   const float* __restrict__ prox, const float* __restrict__ fw,
                                   float* __restrict__ pbuf) {
    __shared__ float wl[288];
    __shared__ float red[2][4][64];
    int cg = blockIdx.x;
    int row = blockIdx.y;
    int b = blockIdx.z;
    int tid = threadIdx.x;
    if (tid < 288) {
        int cl = (tid % 144) / 9, tap = tid % 9;
        int half = tid / 144;
        wl[tid] = fw[(half * DI + cg * 16 + cl) * 9 + tap];
    }
    __syncthreads();
    int px = tid & 63, g = tid >> 6;
    float aT = 0.f, aR = 0.f, aP = 0.f;
    #pragma unroll
    for (int cc = 0; cc < 4; ++cc) {
        int cl = g * 4 + cc;
        int c = cg * 16 + cl;
        const float* xTb = xT + (size_t)(b * DI + c) * LL;
        const float* xRb = xR + (size_t)(b * DI + c) * LL;
        const float* pb  = prox + (size_t)(b * DI + c) * LL;
        const float* wT = wl + cl * 9;
        const float* wP = wl + 144 + cl * 9;
        #pragma unroll
        for (int ky = 0; ky < 3; ++ky) {
            int yy = row + ky - 1;
            if (yy < 0 || yy > 63) continue;
            #pragma unroll
            for (int kx = 0; kx < 3; ++kx) {
                int xx = px + kx - 1;
                bool in = (xx >= 0 && xx < 64);
                int o = yy * 64 + (in ? xx : 0);
                float mT = in ? xTb[o] : 0.f;
                float mR = in ? xRb[o] : 0.f;
                float mP = in ? pb[o] : 0.f;
                float wTv = wT[ky * 3 + kx], wPv = wP[ky * 3 + kx];
                aT += mT * wTv;
                aR += mR * wTv;
                aP += mP * wPv;
            }
        }
    }
    red[0][g][px] = aT + aP;
    red[1][g][px] = aR + aP;
    __syncthreads();
    if (tid < 128) {
        int X = tid >> 6, x = tid & 63;
        float s = red[X][0][x] + red[X][1][x] + red[X][2][x] + red[X][3][x];
        pbuf[(size_t)(cg * 4 + X * 2 + b) * LL + row * 64 + x] = s;
    }
}

// ---------------- reduce 12 partials -> pm[X*2+b][L] ----------------
__global__ void fusepm_reduce_kernel(const float* __restrict__ pbuf,
                                     const float* __restrict__ fb,
                                     float* __restrict__ pm) {
    int idx = blockIdx.x * 256 + threadIdx.x;
    int Xb = idx >> 12;
    int l = idx & 4095;
    float s = fb[0];
    #pragma unroll
    for (int cg = 0; cg < 12; ++cg)
        s += pbuf[(size_t)(cg * 4 + Xb) * LL + l];
    pm[(size_t)Xb * LL + l] = s;
}

// ---------------- rank-count argsort (stable, index tie-break) ----------------
// grid (64, 4): blockIdx.y = X*2+b; block handles 64 elements, 4 threads each
// scan a quarter of the 4096 keys staged in LDS (sortable-uint transform;
// broadcast reads, conflict-free). rank = #{j : k[j]<k[i] or (== and j<i)}.
__global__ __launch_bounds__(256) void rank_sort_kernel(const float* __restrict__ pm,
                                                        int* __restrict__ ord,
                                                        int* __restrict__ inv) {
    __shared__ unsigned int keys[LL];
    __shared__ int cnts[4][64];
    int Xb = blockIdx.y;
    int X = Xb >> 1;
    const float* z = pm + (size_t)Xb * LL;
    int tid = threadIdx.x;
    for (int i = tid; i < LL; i += 256) {
        float v = z[i];
        if (X == 0) v = -v;                  // T branch: descending pm
        int bits = __float_as_int(v);
        keys[i] = (bits < 0) ? ~(unsigned)bits : ((unsigned)bits | 0x80000000u);
    }
    __syncthreads();
    int el = tid & 63;
    int q = tid >> 6;
    int e = blockIdx.x * 64 + el;
    unsigned ui = keys[e];
    int count = 0;
    int j0 = q * (LL / 4);
    #pragma unroll 4
    for (int j = j0; j < j0 + LL / 4; ++j) {
        unsigned uj = keys[j];
        count += (uj < ui) || (uj == ui && j < e);
    }
    cnts[q][el] = count;
    __syncthreads();
    if (tid < 64) {
        int rank = cnts[0][tid] + cnts[1][tid] + cnts[2][tid] + cnts[3][tid];
        int i = blockIdx.x * 64 + tid;
        ord[(size_t)Xb * LL + rank] = i;
        inv[(size_t)Xb * LL + i] = rank;
    }
}

// ---------------- depth weight transpose: wtT[i][j] ----------------
__global__ void wt_transpose_kernel(const float* __restrict__ wde, const float* __restrict__ dpw,
                                    const float* __restrict__ sgw, float* __restrict__ wtT) {
    int idx = blockIdx.x * 256 + threadIdx.x;
    if (idx < 192 * 272) {
        int i = idx / 272, j = idx % 272;
        float v;
        if (j < 192) v = wde[j * DI + i];
        else if (j < 256) v = dpw[(j - 192) * DI + i];
        else v = sgw[(j - 256) * DI + i];
        wtT[idx] = v;
    }
}

// ---------------- transpose NCHW (b,c,l) -> (b,l,c), optionally add pe --------
__global__ void transpose_pe_kernel(const float* __restrict__ in, float* __restrict__ out,
                                    const float* __restrict__ pe, int use_pe) {
    __shared__ float tile[32][33];
    int b = blockIdx.z;
    int l0 = blockIdx.x * 32, c0 = blockIdx.y * 32;
    int tx = threadIdx.x, ty = threadIdx.y;
    #pragma unroll
    for (int r = 0; r < 4; ++r) {
        int c = c0 + ty + r * 8;
        tile[ty + r * 8][tx] = in[(size_t)(b * DI + c) * LL + l0 + tx];
    }
    __syncthreads();
    #pragma unroll
    for (int r = 0; r < 4; ++r) {
        int l = l0 + ty + r * 8;
        int c = c0 + tx;
        float v = tile[tx][ty + r * 8];
        if (use_pe) v += pe[(l & 63) * DI + c];
        out[(size_t)(b * LL + l) * DI + c] = v;
    }
}

// ---------------- depth path: 8 positions/block, transposed weights ----------
__global__ __launch_bounds__(256) void depth_kernel(
        const float* __restrict__ proxt, const float* __restrict__ wtT,
        const float* __restrict__ bde, const float* __restrict__ sgb,
        float* __restrict__ dproj, float* __restrict__ dsig) {
    __shared__ float pvs[8][DI];
    __shared__ float dfs[8][DI];
    int bl0 = blockIdx.x * 8;
    int tid = threadIdx.x;
    for (int t = tid; t < 8 * DI; t += 256)
        pvs[t / DI][t % DI] = proxt[(size_t)bl0 * DI + t];
    __syncthreads();
    if (tid < DI) {
        float acc[8];
        #pragma unroll
        for (int l = 0; l < 8; ++l) acc[l] = 0.f;
        const float* wp = wtT + tid;
        for (int i = 0; i < DI; ++i) {
            float w = wp[i * 272];
            #pragma unroll
            for (int l = 0; l < 8; ++l) acc[l] += w * pvs[l][i];
        }
        float bias = bde[tid];
        #pragma unroll
        for (int l = 0; l < 8; ++l) {
            float v = acc[l] + bias;
            dfs[l][tid] = (v > 0.f) ? v : 0.2f * v;
        }
    }
    __syncthreads();
    if (tid < 160) {
        int o = tid >> 1;
        int ph = (tid & 1) * 4;
        float acc[4] = {0.f, 0.f, 0.f, 0.f};
        const float* wp = wtT + 192 + o;
        for (int i = 0; i < DI; ++i) {
            float w = wp[i * 272];
            #pragma unroll
            for (int p = 0; p < 4; ++p) acc[p] += w * dfs[ph + p][i];
        }
        if (o < 64) {
            #pragma unroll
            for (int p = 0; p < 4; ++p)
                dproj[(size_t)(bl0 + ph + p) * 64 + o] = acc[p];
        } else {
            float bias = sgb[o - 64];
            #pragma unroll
            for (int p = 0; p < 4; ++p) {
                float v = acc[p] + bias;
                v = (v > 0.f) ? v : 0.2f * v;
                dsig[(size_t)(bl0 + ph + p) * NST + (o - 64)] = 1.f / (1.f + __expf(-v));
            }
        }
    }
}

// ---------------- per-(b,k,s): x_dbl proj, delta, Bs/Cs -> s-minor buffers ----
__global__ void project_kernel(const float* __restrict__ xpe, const int* __restrict__ ord,
                               const float* __restrict__ xpw, const float* __restrict__ dtw,
                               const float* __restrict__ dtb, const float* __restrict__ dproj,
                               const float* __restrict__ dsig, float* __restrict__ dtb2,
                               float* __restrict__ dub2, float* __restrict__ bscs2) {
    __shared__ float u[16][196];        // row stride 784B (16B aligned)
    __shared__ float dbl[16][40];
    __shared__ int jarr[16];
    int chunk = blockIdx.x & 255;
    int k = (blockIdx.x >> 8) & 1;
    int b = blockIdx.x >> 9;
    int bk = b * 2 + k;
    int s0 = chunk * 16;
    int tid = threadIdx.x;
    if (tid < 16) {
        int s = s0 + tid;
        jarr[tid] = ord[b * LL + ((k == 0) ? s : (LL - 1 - s))];
    }
    __syncthreads();
    for (int t = tid; t < 16 * 48; t += 256) {
        int l = t / 48, i4 = t % 48;
        *(float4*)&u[l][i4 * 4] =
            *(const float4*)(xpe + (size_t)(b * LL + jarr[l]) * DI + i4 * 4);
    }
    __syncthreads();
    {
        int og = tid >> 4, sl = tid & 15;
        const float* w0 = xpw + (size_t)(k * 38 + og) * DI;
        const float* w1 = w0 + 16 * DI;
        const float* w2 = w0 + 32 * DI;
        bool has2 = (og < 6);
        float a0 = 0.f, a1 = 0.f, a2 = 0.f;
        for (int i4 = 0; i4 < 48; ++i4) {
            float4 u4 = *(const float4*)&u[sl][i4 * 4];
            float4 x0 = *(const float4*)(w0 + i4 * 4);
            float4 x1 = *(const float4*)(w1 + i4 * 4);
            a0 += x0.x * u4.x + x0.y * u4.y + x0.z * u4.z + x0.w * u4.w;
            a1 += x1.x * u4.x + x1.y * u4.y + x1.z * u4.z + x1.w * u4.w;
            if (has2) {
                float4 x2 = *(const float4*)(w2 + i4 * 4);
                a2 += x2.x * u4.x + x2.y * u4.y + x2.z * u4.z + x2.w * u4.w;
            }
        }
        dbl[sl][og] = a0;
        dbl[sl][og + 16] = a1;
        if (has2) dbl[sl][og + 32] = a2;
    }
    __syncthreads();
    if (tid < DI) {
        int c = tid;
        float w[6];
        #pragma unroll
        for (int r = 0; r < 6; ++r) w[r] = dtw[(k * DI + c) * DTR + r];
        float bias = dtb[k * DI + c];
        float dtl[16], dul[16];
        #pragma unroll
        for (int sl = 0; sl < 16; ++sl) {
            float d = bias;
            #pragma unroll
            for (int r = 0; r < 6; ++r) d += w[r] * dbl[sl][r];
            float sp = fmaxf(d, 0.f) + log1pf(__expf(-fabsf(d)));
            dtl[sl] = sp;
            dul[sl] = sp * u[sl][c];
        }
        size_t base = (size_t)(bk * DI + c) * LL + s0;
        #pragma unroll
        for (int g = 0; g < 4; ++g) {
            *(float4*)(dtb2 + base + g * 4) =
                make_float4(dtl[g*4], dtl[g*4+1], dtl[g*4+2], dtl[g*4+3]);
            *(float4*)(dub2 + base + g * 4) =
                make_float4(dul[g*4], dul[g*4+1], dul[g*4+2], dul[g*4+3]);
        }
    }
    {
        int n = tid >> 4, sl = tid & 15;
        int j = jarr[sl];
        float w = dsig[(size_t)(b * LL + j) * NST + n];
        float Bo = dbl[sl][6 + n], Co = dbl[sl][22 + n];
        float Bd = dproj[(size_t)(b * LL + j) * 64 + k * 32 + n];
        float Cd = dproj[(size_t)(b * LL + j) * 64 + k * 32 + 16 + n];
        size_t sb = (size_t)(bk * 32 + n) * LL + s0 + sl;
        bscs2[sb] = (1.f - w) * Bo + w * Bd;
        bscs2[sb + (size_t)16 * LL] = (1.f - w) * Co + w * Cd;
    }
}

// ---------------- fused time-parallel selective scan (8 steps/lane) ----------
__global__ __launch_bounds__(512, 6) void scan_fused_kernel(
        const float* __restrict__ dtb2, const float* __restrict__ dub2,
        const float* __restrict__ bscs2, const float* __restrict__ Alog,
        float* __restrict__ y) {
    __shared__ float ypart[2][8][CT + 4];
    int c = blockIdx.x % DI;
    int bk = blockIdx.x / DI;
    int k = bk & 1;
    int w = threadIdx.x >> 6;
    int t = threadIdx.x & 63;
    float A0 = -__expf(Alog[(k * DI + c) * NST + w]);
    float A1 = -__expf(Alog[(k * DI + c) * NST + w + 8]);
    size_t rowc = (size_t)(bk * DI + c) * LL;
    const float* dtp = dtb2 + rowc;
    const float* dup = dub2 + rowc;
    const float* b0p = bscs2 + (size_t)(bk * 32 + w) * LL;
    const float* c0p = b0p + (size_t)16 * LL;
    const float* b1p = b0p + (size_t)8 * LL;
    const float* c1p = c0p + (size_t)8 * LL;
    float* yrow = y + rowc;
    float Hc0 = 0.f, Hc1 = 0.f;
    int off = t * 8;
    for (int ck = 0; ck < NCK; ++ck) {
        int base = ck * CT;
        int o = base + off;
        float4 dA = *(const float4*)(dtp + o), dB = *(const float4*)(dtp + o + 4);
        float4 uA = *(const float4*)(dup + o), uB = *(const float4*)(dup + o + 4);
        float4 B0a = *(const float4*)(b0p + o), B0b = *(const float4*)(b0p + o + 4);
        float4 B1a = *(const float4*)(b1p + o), B1b = *(const float4*)(b1p + o + 4);
        float d[8]  = {dA.x, dA.y, dA.z, dA.w, dB.x, dB.y, dB.z, dB.w};
        float uu[8] = {uA.x, uA.y, uA.z, uA.w, uB.x, uB.y, uB.z, uB.w};
        float Bb0[8] = {B0a.x, B0a.y, B0a.z, B0a.w, B0b.x, B0b.y, B0b.z, B0b.w};
        float Bb1[8] = {B1a.x, B1a.y, B1a.z, B1a.w, B1b.x, B1b.y, B1b.z, B1b.w};
        float e0[8], e1[8], z0[8], z1[8];
        float S = 0.f, cb0 = 0.f, cb1 = 0.f;
        #pragma unroll
        for (int j = 0; j < 8; ++j) {
            e0[j] = __expf(d[j] * A0);
            e1[j] = __expf(d[j] * A1);
            z0[j] = uu[j] * Bb0[j];
            z1[j] = uu[j] * Bb1[j];
            S += d[j];
            cb0 = cb0 * e0[j] + z0[j];
            cb1 = cb1 * e1[j] + z1[j];
        }
        #pragma unroll
        for (int m = 1; m < 64; m <<= 1) {
            float sS = __shfl_up(S, m);
            float s0 = __shfl_up(cb0, m);
            float s1 = __shfl_up(cb1, m);
            if (t >= m) {
                cb0 += __expf(A0 * S) * s0;
                cb1 += __expf(A1 * S) * s1;
                S += sS;
            }
        }
        float Sf  = __shfl(S, 63);
        float b0f = __shfl(cb0, 63);
        float b1f = __shfl(cb1, 63);
        float Se  = __shfl_up(S, 1);
        float b0e = __shfl_up(cb0, 1);
        float b1e = __shfl_up(cb1, 1);
        if (t == 0) { Se = 0.f; b0e = 0.f; b1e = 0.f; }
        float h0 = __expf(A0 * Se) * Hc0 + b0e;
        float h1 = __expf(A1 * Se) * Hc1 + b1e;
        float nHc0 = __expf(A0 * Sf) * Hc0 + b0f;
        float nHc1 = __expf(A1 * Sf) * Hc1 + b1f;
        Hc0 = nHc0; Hc1 = nHc1;
        float4 C0a = *(const float4*)(c0p + o), C0b = *(const float4*)(c0p + o + 4);
        float4 C1a = *(const float4*)(c1p + o), C1b = *(const float4*)(c1p + o + 4);
        float Cc0[8] = {C0a.x, C0a.y, C0a.z, C0a.w, C0b.x, C0b.y, C0b.z, C0b.w};
        float Cc1[8] = {C1a.x, C1a.y, C1a.z, C1a.w, C1b.x, C1b.y, C1b.z, C1b.w};
        float yv[8];
        #pragma unroll
        for (int j = 0; j < 8; ++j) {
            h0 = h0 * e0[j] + z0[j];
            h1 = h1 * e1[j] + z1[j];
            yv[j] = h0 * Cc0[j] + h1 * Cc1[j];
        }
        *(float4*)&ypart[ck & 1][w][off] = make_float4(yv[0], yv[1], yv[2], yv[3]);
        *(float4*)&ypart[ck & 1][w][off + 4] = make_float4(yv[4], yv[5], yv[6], yv[7]);
        __syncthreads();
        if (threadIdx.x < 128) {
            int t4 = threadIdx.x * 4;
            float4 s = *(const float4*)&ypart[ck & 1][0][t4];
            #pragma unroll
            for (int r = 1; r < 8; ++r) {
                float4 v = *(const float4*)&ypart[ck & 1][r][t4];
                s.x += v.x; s.y += v.y; s.z += v.z; s.w += v.w;
            }
            *(float4*)(yrow + base + t4) = s;
        }
    }
}

// ---------------- s-order gather + D*u + layernorm + output ------------------
__global__ __launch_bounds__(256) void ln_kernel(const float* __restrict__ y,
                          const float* __restrict__ xpe,
                          const int* __restrict__ ord, const float* __restrict__ Dvec,
                          const float* __restrict__ g, const float* __restrict__ beta,
                          float* __restrict__ out, int X) {
    __shared__ float y0t[DI][17];
    __shared__ float y1t[DI][17];
    int b = blockIdx.x >> 8;
    int s0 = (blockIdx.x & 255) * 16;
    int tid = threadIdx.x;
    for (int idx = tid; idx < DI * 16; idx += 256) {
        int c = idx >> 4, j = idx & 15;
        y0t[c][j] = y[((size_t)(b * 2 + 0) * DI + c) * LL + s0 + j];
        y1t[c][j] = y[((size_t)(b * 2 + 1) * DI + c) * LL + (LL - 1 - s0 - j)];
    }
    __syncthreads();
    int w = tid >> 6, lane = tid & 63;
    #pragma unroll
    for (int it = 0; it < 4; ++it) {
        int j = it * 4 + w;
        int l = ord[b * LL + s0 + j];
        const float* xr = xpe + (size_t)(b * LL + l) * DI;
        float v[3];
        float sum = 0.f, sq = 0.f;
        #pragma unroll
        for (int r = 0; r < 3; ++r) {
            int c = lane + r * 64;
            float t = y0t[c][j] + y1t[c][j] + (Dvec[c] + Dvec[DI + c]) * xr[c];
            v[r] = t; sum += t; sq += t * t;
        }
        #pragma unroll
        for (int m = 1; m < 64; m <<= 1) {
            sum += __shfl_xor(sum, m);
            sq += __shfl_xor(sq, m);
        }
        float mu = sum * (1.f / 192.f);
        float var = sq * (1.f / 192.f) - mu * mu;
        float rs = rsqrtf(var + 1e-5f);
        float* op = out + ((size_t)(X * 2 + b) * LL + l) * DI;
        #pragma unroll
        for (int r = 0; r < 3; ++r) {
            int c = lane + r * 64;
            op[c] = (v[r] - mu) * rs * g[c] + beta[c];
        }
    }
}

extern "C" void kernel_launch(void* const* d_in, const int* in_sizes, int n_in,
                              void* d_out, int out_size, void* d_ws, size_t ws_size,
                              hipStream_t stream) {
    const float* x_T = (const float*)d_in[0];
    const float* x_R = (const float*)d_in[1];
    const float* prox = (const float*)d_in[2];
    const float* fuse_w = (const float*)d_in[3];
    const float* fuse_b = (const float*)d_in[4];
    const float* x_proj_w = (const float*)d_in[5];
    const float* dt_w = (const float*)d_in[6];
    const float* dt_b = (const float*)d_in[7];
    const float* A_log_T = (const float*)d_in[8];
    const float* A_log_R = (const float*)d_in[9];
    const float* D_T = (const float*)d_in[10];
    const float* D_R = (const float*)d_in[11];
    const float* depth_enc_w = (const float*)d_in[12];
    const float* depth_enc_b = (const float*)d_in[13];
    const float* depth_proj_w = (const float*)d_in[14];
    const float* sig_w = (const float*)d_in[15];
    const float* sig_b = (const float*)d_in[16];
    const float* ln_g = (const float*)d_in[17];
    const float* ln_b = (const float*)d_in[18];
    float* out = (float*)d_out;
    char* ws = (char*)d_ws;

    float* pe    = (float*)(ws + 0);         //   49152
    float* pm    = (float*)(ws + 49152);     //   65536
    int*   ord   = (int*)(ws + 114688);      //   65536
    int*   inv   = (int*)(ws + 180224);      //   65536
    float* proxt = (float*)(ws + 245760);    // 6291456
    float* dproj = (float*)(ws + 6537216);   // 2097152
    float* dsig  = (float*)(ws + 8634368);   //  524288
    float* xpe   = (float*)(ws + 9158656);   // 6291456 (reused per branch)
    float* dtb2  = (float*)(ws + 15450112);  // 12582912
    float* dub2  = (float*)(ws + 28033024);  // 12582912
    float* bscs2 = (float*)(ws + 40615936);  // 2097152
    float* ybuf  = (float*)(ws + 42713088);  // 12582912, layout [bk][c][s]
    float* pbuf  = dtb2;                     // fuse partials (dead until project)
    float* wtT   = bscs2;                    // 209 KB, dead once project writes bscs2

    pe_kernel<<<48, 256, 0, stream>>>(pe);
    fusepm_part_kernel<<<dim3(12, 64, 2), 256, 0, stream>>>(x_T, x_R, prox, fuse_w, pbuf);
    fusepm_reduce_kernel<<<64, 256, 0, stream>>>(pbuf, fuse_b, pm);
    rank_sort_kernel<<<dim3(64, 4), 256, 0, stream>>>(pm, ord, inv);
    wt_transpose_kernel<<<204, 256, 0, stream>>>(depth_enc_w, depth_proj_w, sig_w, wtT);
    transpose_pe_kernel<<<dim3(128, 6, 2), dim3(32, 8), 0, stream>>>(prox, proxt, pe, 0);
    depth_kernel<<<1024, 256, 0, stream>>>(proxt, wtT, depth_enc_b, sig_b, dproj, dsig);
    for (int X = 0; X < 2; ++X) {
        const float* xin = X ? x_R : x_T;
        const float* Alog = X ? A_log_R : A_log_T;
        const float* Dv = X ? D_R : D_T;
        const int* ordX = ord + X * 2 * LL;
        transpose_pe_kernel<<<dim3(128, 6, 2), dim3(32, 8), 0, stream>>>(xin, xpe, pe, 1);
        project_kernel<<<1024, 256, 0, stream>>>(xpe, ordX, x_proj_w, dt_w, dt_b,
                                                 dproj, dsig, dtb2, dub2, bscs2);
        scan_fused_kernel<<<4 * DI, 512, 0, stream>>>(dtb2, dub2, bscs2, Alog, ybuf);
        ln_kernel<<<512, 256, 0, stream>>>(ybuf, xpe, ordX, Dv, ln_g, ln_b, out, X);
    }
}